// Round 5
// baseline (986.817 us; speedup 1.0000x reference)
//
#include <hip/hip_runtime.h>
#include <math.h>

#define N_NODES 50000
#define IN_DIM  256
#define LATENT  128
#define FINALD  64
#define NGRAPH  2
#define NEDGE   1000000
#define BATCHSZ 16384

#define VN      (2 * N_NODES)          // virtual dst ids (graph-major)
#define NBUCK   ((VN + 255) >> 8)      // 391 buckets of 256 dsts
#define E2      (2 * NEDGE)
#define NPB     256                    // partition blocks
#define PCH     ((E2 + NPB - 1) / NPB) // edges per partition block
#define NRANGE  8                      // src ranges for L2-resident gather
#define RSZ     ((N_NODES + NRANGE - 1) / NRANGE)   // 6250

typedef __attribute__((ext_vector_type(8))) short bf16x8;
typedef __attribute__((ext_vector_type(4))) float f32x4;
typedef __attribute__((ext_vector_type(8))) unsigned short u16x8;
typedef __attribute__((ext_vector_type(4))) unsigned short u16x4;

__device__ inline unsigned short f2bf(float x) {
    unsigned int u = __float_as_uint(x);
    u = (u + 0x7fffu + ((u >> 16) & 1u)) >> 16;
    return (unsigned short)u;
}
__device__ inline float bf2f(unsigned short h) {
    return __uint_as_float(((unsigned int)h) << 16);
}

// ---------------------------------------------------------------------------
// Split-precision bf16 MFMA GEMM (Ah@Bh + Ah@Bl + Al@Bh), 64x64 tile, BK=64.
// ---------------------------------------------------------------------------
#define GBM 64
#define GBK 64

__device__ inline int swz(int r, int k) {
    return r * GBK + ((((k >> 3) ^ (r & 7)) << 3) | (k & 7));
}

__global__ __launch_bounds__(256)
void gemm_mfma(const float* __restrict__ A1, const float* __restrict__ B1, int K1,
               const float* __restrict__ A2, const float* __restrict__ B2, int K2,
               const float* __restrict__ bias, const float* __restrict__ addm,
               void* __restrict__ Cout, int M, int Ncols, int act, int out_bf16)
{
    __shared__ unsigned short AhS[GBM * GBK];
    __shared__ unsigned short AlS[GBM * GBK];
    __shared__ unsigned short BhS[GBM * GBK];
    __shared__ unsigned short BlS[GBM * GBK];

    const int tid = threadIdx.x;
    const int rowBase = blockIdx.x * GBM;
    const int colBase = blockIdx.y * GBM;
    const int wave = tid >> 6, lane = tid & 63;
    const int wr = wave >> 1, wc = wave & 1;
    const int sl = lane & 15, lg = lane >> 4;

    f32x4 acc[2][2] = {};

    const float* Ap = A1;
    const float* Bp = B1;
    int K = K1;

    for (int pass = 0; pass < 2; ++pass) {
        if (pass == 1) { if (!A2) break; Ap = A2; Bp = B2; K = K2; }
        for (int k0 = 0; k0 < K; k0 += GBK) {
            __syncthreads();
            #pragma unroll
            for (int p = 0; p < 4; ++p) {
                int q = p * 256 + tid;
                int row = q >> 4;
                int kq = (q & 15) << 2;
                int grow = rowBase + row;
                float4 v = make_float4(0.f, 0.f, 0.f, 0.f);
                if (grow < M) v = *(const float4*)(Ap + (size_t)grow * K + k0 + kq);
                unsigned short h0 = f2bf(v.x), h1 = f2bf(v.y), h2 = f2bf(v.z), h3 = f2bf(v.w);
                u16x4 hv = {h0, h1, h2, h3};
                u16x4 lv = {f2bf(v.x - bf2f(h0)), f2bf(v.y - bf2f(h1)),
                            f2bf(v.z - bf2f(h2)), f2bf(v.w - bf2f(h3))};
                int off = swz(row, kq);
                *(u16x4*)&AhS[off] = hv;
                *(u16x4*)&AlS[off] = lv;
            }
            {
                int n = tid & 63;
                int kq = (tid >> 6) << 4;
                #pragma unroll
                for (int c = 0; c < 2; ++c) {
                    u16x8 hv, lv;
                    #pragma unroll
                    for (int j = 0; j < 8; ++j) {
                        float x = Bp[(size_t)(k0 + kq + c * 8 + j) * Ncols + colBase + n];
                        unsigned short h = f2bf(x);
                        hv[j] = h;
                        lv[j] = f2bf(x - bf2f(h));
                    }
                    int off = swz(n, kq + c * 8);
                    *(u16x8*)&BhS[off] = hv;
                    *(u16x8*)&BlS[off] = lv;
                }
            }
            __syncthreads();
            #pragma unroll
            for (int ks = 0; ks < 2; ++ks) {
                int kof = ks * 32 + lg * 8;
                bf16x8 ah[2], al[2], bh[2], bl[2];
                #pragma unroll
                for (int f = 0; f < 2; ++f) {
                    int m = wr * 32 + f * 16 + sl;
                    int oa = swz(m, kof);
                    ah[f] = *(const bf16x8*)&AhS[oa];
                    al[f] = *(const bf16x8*)&AlS[oa];
                    int n = wc * 32 + f * 16 + sl;
                    int ob = swz(n, kof);
                    bh[f] = *(const bf16x8*)&BhS[ob];
                    bl[f] = *(const bf16x8*)&BlS[ob];
                }
                #pragma unroll
                for (int fm = 0; fm < 2; ++fm)
                    #pragma unroll
                    for (int fn = 0; fn < 2; ++fn) {
                        acc[fm][fn] = __builtin_amdgcn_mfma_f32_16x16x32_bf16(ah[fm], bh[fn], acc[fm][fn], 0, 0, 0);
                        acc[fm][fn] = __builtin_amdgcn_mfma_f32_16x16x32_bf16(ah[fm], bl[fn], acc[fm][fn], 0, 0, 0);
                        acc[fm][fn] = __builtin_amdgcn_mfma_f32_16x16x32_bf16(al[fm], bh[fn], acc[fm][fn], 0, 0, 0);
                    }
            }
        }
    }

    #pragma unroll
    for (int fm = 0; fm < 2; ++fm)
        #pragma unroll
        for (int r = 0; r < 4; ++r) {
            int row = rowBase + wr * 32 + fm * 16 + lg * 4 + r;
            if (row >= M) continue;
            #pragma unroll
            for (int fn = 0; fn < 2; ++fn) {
                int col = colBase + wc * 32 + fn * 16 + sl;
                float v = acc[fm][fn][r];
                if (bias) v += bias[col];
                if (act) v = v > 0.f ? v : (__expf(v) - 1.f);
                if (addm) v += addm[(size_t)row * Ncols + col];
                if (out_bf16)
                    ((unsigned short*)Cout)[(size_t)row * Ncols + col] = f2bf(v);
                else
                    ((float*)Cout)[(size_t)row * Ncols + col] = v;
            }
        }
}

// ---------------------------------------------------------------------------
// alpha_self / alpha_nb from bf16 H1. Wave per row.
// ---------------------------------------------------------------------------
__global__ __launch_bounds__(256)
void rowdots(const unsigned short* __restrict__ H1b, const float* __restrict__ a1,
             const float* __restrict__ a2,
             float* __restrict__ o1, float* __restrict__ o2, int n)
{
    int lane = threadIdx.x & 63, wid = threadIdx.x >> 6;
    int row = blockIdx.x * 4 + wid;
    if (row >= n) return;
    unsigned int hv = *(const unsigned int*)(H1b + (size_t)row * LATENT + lane * 2);
    float h0 = bf2f((unsigned short)(hv & 0xffffu));
    float h1 = bf2f((unsigned short)(hv >> 16));
    float2 x = *(const float2*)(a1 + lane * 2);
    float2 y = *(const float2*)(a2 + lane * 2);
    float d1 = h0 * x.x + h1 * x.y;
    float d2 = h0 * y.x + h1 * y.y;
    #pragma unroll
    for (int o = 32; o; o >>= 1) {
        d1 += __shfl_xor(d1, o);
        d2 += __shfl_xor(d2, o);
    }
    if (lane == 0) { o1[row] = d1; o2[row] = d2; }
}

// ---------------------------------------------------------------------------
// Atomic-free bucketed counting sort by virtual dst (vd = g*N + dst).
// pcnt/pbase layout: [NBUCK][NPB] (bucket-major).
// ---------------------------------------------------------------------------
__global__ __launch_bounds__(256)
void part_count(const int* __restrict__ edg, int* __restrict__ pcnt)
{
    __shared__ int h[NBUCK];
    int tid = threadIdx.x;
    for (int i = tid; i < NBUCK; i += 256) h[i] = 0;
    __syncthreads();
    int start = blockIdx.x * PCH;
    int stop  = min(start + PCH, E2);
    for (int i = start + tid; i < stop; i += 256) {
        int g = i >= NEDGE;
        int idx = i - (g ? NEDGE : 0);
        int dst = edg[(size_t)g * E2 + NEDGE + idx];
        atomicAdd(&h[(g * N_NODES + dst) >> 8], 1);
    }
    __syncthreads();
    for (int i = tid; i < NBUCK; i += 256)
        pcnt[i * NPB + blockIdx.x] = h[i];
}

__global__ __launch_bounds__(1024)
void part_scan(const int* __restrict__ pcnt, int* __restrict__ pbase,
               int* __restrict__ bbase, int* __restrict__ offs)
{
    __shared__ int btot[NBUCK];
    int tid = threadIdx.x;
    int lane = tid & 63, w = tid >> 6;           // 16 waves
    for (int b = w; b < NBUCK; b += 16) {
        int4 v = *(const int4*)&pcnt[b * NPB + lane * 4];
        int s = v.x + v.y + v.z + v.w;
        int x = s;
        #pragma unroll
        for (int o = 1; o < 64; o <<= 1) {
            int y = __shfl_up(x, o);
            if (lane >= o) x += y;
        }
        int ex = x - s;                           // exclusive within bucket
        int* pb = &pbase[b * NPB + lane * 4];
        pb[0] = ex;
        pb[1] = ex + v.x;
        pb[2] = ex + v.x + v.y;
        pb[3] = ex + v.x + v.y + v.z;
        if (lane == 63) btot[b] = x;
    }
    __syncthreads();
    if (tid == 0) {
        int a = 0;
        for (int b = 0; b < NBUCK; ++b) { bbase[b] = a; a += btot[b]; }
        bbase[NBUCK] = a;
        offs[VN] = E2;
    }
}

__global__ __launch_bounds__(256)
void part_fill(const int* __restrict__ edg, const int* __restrict__ pbase,
               const int* __restrict__ bbase, int* __restrict__ ebuf)
{
    __shared__ int lbase[NBUCK];
    __shared__ int lcur[NBUCK];
    int tid = threadIdx.x;
    for (int i = tid; i < NBUCK; i += 256) {
        lbase[i] = bbase[i] + pbase[i * NPB + blockIdx.x];
        lcur[i] = 0;
    }
    __syncthreads();
    int start = blockIdx.x * PCH;
    int stop  = min(start + PCH, E2);
    for (int i = start + tid; i < stop; i += 256) {
        int g = i >= NEDGE;
        int idx = i - (g ? NEDGE : 0);
        int src = edg[(size_t)g * E2 + idx];
        int dst = edg[(size_t)g * E2 + NEDGE + idx];
        int vd = g * N_NODES + dst;
        int b = vd >> 8;
        int p = lbase[b] + atomicAdd(&lcur[b], 1);
        ebuf[p] = ((vd & 255) << 16) | src;
    }
}

__global__ __launch_bounds__(256)
void bucket_csr(const int* __restrict__ ebuf, const int* __restrict__ bbase,
                int* __restrict__ offs, unsigned short* __restrict__ csr)
{
    __shared__ int cnt[256];
    __shared__ int excl[256];
    __shared__ int cur[256];
    __shared__ int wsum[4];
    int tid = threadIdx.x;
    int b = blockIdx.x;
    int lo = bbase[b], hi = bbase[b + 1];

    cnt[tid] = 0; cur[tid] = 0;
    __syncthreads();
    for (int i = lo + tid; i < hi; i += 256)
        atomicAdd(&cnt[ebuf[i] >> 16], 1);
    __syncthreads();

    int lane = tid & 63, w = tid >> 6;
    int v = cnt[tid];
    int x = v;
    #pragma unroll
    for (int o = 1; o < 64; o <<= 1) {
        int y = __shfl_up(x, o);
        if (lane >= o) x += y;
    }
    if (lane == 63) wsum[w] = x;
    __syncthreads();
    int wb = 0;
    for (int i = 0; i < w; ++i) wb += wsum[i];
    int ex = wb + x - v;
    excl[tid] = ex;
    int vd = b * 256 + tid;
    if (vd < VN) offs[vd] = lo + ex;
    __syncthreads();

    for (int i = lo + tid; i < hi; i += 256) {
        int e = ebuf[i];
        int dl = e >> 16;
        int p = excl[dl] + atomicAdd(&cur[dl], 1);
        csr[lo + p] = (unsigned short)(e & 0xFFFF);
    }
}

// ---------------------------------------------------------------------------
// Phase 1: per-edge softmax weights. Wave per virtual dst segment.
// ---------------------------------------------------------------------------
__global__ __launch_bounds__(256)
void gat_weights(const float* __restrict__ asf, const float* __restrict__ anb,
                 const int* __restrict__ offs, const unsigned short* __restrict__ csr,
                 const float* __restrict__ omega, float* __restrict__ wbuf)
{
    int lane = threadIdx.x & 63, wid = threadIdx.x >> 6;
    int vd = blockIdx.x * 4 + wid;
    if (vd >= VN) return;
    int g = vd >= N_NODES;
    int d = vd - (g ? N_NODES : 0);
    int beg = offs[vd], end = offs[vd + 1];
    if (beg == end) return;
    float ad = asf[d];
    float om = omega[g];

    float m = -INFINITY;
    for (int e = beg + lane; e < end; e += 64) {
        float sc = ad + anb[csr[e]];
        sc = sc > 0.f ? sc : 0.2f * sc;
        m = fmaxf(m, sc);
    }
    #pragma unroll
    for (int o = 32; o; o >>= 1) m = fmaxf(m, __shfl_xor(m, o));

    float ss = 0.f;
    for (int e = beg + lane; e < end; e += 64) {
        float sc = ad + anb[csr[e]];
        sc = sc > 0.f ? sc : 0.2f * sc;
        ss += __expf(sc - m);
    }
    #pragma unroll
    for (int o = 32; o; o >>= 1) ss += __shfl_xor(ss, o);
    float wsc = om / (ss + 1e-16f);

    for (int e = beg + lane; e < end; e += 64) {
        float sc = ad + anb[csr[e]];
        sc = sc > 0.f ? sc : 0.2f * sc;
        wbuf[e] = __expf(sc - m) * wsc;
    }
}

// ---------------------------------------------------------------------------
// Phase 2: gather-accumulate, src-range blocked for L2 residency.
// Wave per dst; acc stays in registers across the 8 range passes.
// ---------------------------------------------------------------------------
__global__ __launch_bounds__(256)
void gat_gather(const unsigned short* __restrict__ H1b,
                const int* __restrict__ offs, const unsigned short* __restrict__ csr,
                const float* __restrict__ wbuf,
                float* __restrict__ H2, int n)
{
    int lane = threadIdx.x & 63, wid = threadIdx.x >> 6;
    int d = blockIdx.x * 4 + wid;
    if (d >= n) return;
    int sub = lane >> 4, sl = lane & 15;
    float acc[8] = {};

    int beg0 = offs[d],     end0 = offs[d + 1];
    int beg1 = offs[n + d], end1 = offs[n + d + 1];

    for (int r = 0; r < NRANGE; ++r) {
        int lo = r * RSZ, hi = lo + RSZ;
        #pragma unroll
        for (int g = 0; g < NGRAPH; ++g) {
            int beg = g ? beg1 : beg0;
            int end = g ? end1 : end0;
            for (int e = beg + sub; e < end; e += 4) {
                int s = csr[e];
                if (s >= lo && s < hi) {
                    float wv = wbuf[e];
                    u16x8 h = *(const u16x8*)(H1b + (size_t)s * LATENT + (sl << 3));
                    #pragma unroll
                    for (int j = 0; j < 8; ++j) acc[j] += wv * bf2f(h[j]);
                }
            }
        }
    }

    #pragma unroll
    for (int j = 0; j < 8; ++j) {
        acc[j] += __shfl_xor(acc[j], 32);
        acc[j] += __shfl_xor(acc[j], 16);
    }
    if (sub == 0) {
        float* dp = H2 + (size_t)d * LATENT + sl * 8;
        *(float4*)dp       = make_float4(acc[0], acc[1], acc[2], acc[3]);
        *(float4*)(dp + 4) = make_float4(acc[4], acc[5], acc[6], acc[7]);
    }
}

// ---------------------------------------------------------------------------
__global__ __launch_bounds__(256)
void predict(const int* __restrict__ uid, const int* __restrict__ iid,
             const float* __restrict__ U, const float* __restrict__ B,
             const float* __restrict__ bu, const float* __restrict__ bb,
             const float* __restrict__ bx, float* __restrict__ out, int batch)
{
    int lane = threadIdx.x & 63, wid = threadIdx.x >> 6;
    int b = blockIdx.x * 4 + wid;
    if (b >= batch) return;
    int u = uid[b], it = iid[b];
    float p = U[(size_t)u * FINALD + lane] * B[(size_t)it * FINALD + lane];
    #pragma unroll
    for (int o = 32; o; o >>= 1) p += __shfl_xor(p, o);
    if (lane == 0) {
        float raw = p + bu[u] + bb[it] + bx[0];
        out[b] = 4.f * (1.f / (1.f + __expf(-raw))) + 1.f;
    }
}

// ---------------------------------------------------------------------------
extern "C" void kernel_launch(void* const* d_in, const int* in_sizes, int n_in,
                              void* d_out, int out_size, void* d_ws, size_t ws_size,
                              hipStream_t stream)
{
    const int N = N_NODES;

    float* ws = (float*)d_ws;
    float* bufA  = ws;                        // H1b (bf16) then H3 (f32): 6.4e6 f
    float* H2    = ws + 6400000;              // 6.4e6 f  (ebuf overlays this)
    float* U_all = ws + 12800000;             // 3.2e6 f
    float* B_all = ws + 16000000;             // 3.2e6 f  (wbuf overlays this)
    float* asf   = ws + 19200000;             // 5e4
    float* anb   = asf + N;                   // 5e4
    int*   offs  = (int*)(anb + N);           // VN+1
    int*   pcnt  = offs + VN + 1;             // NBUCK*NPB
    int*   pbase = pcnt + NBUCK * NPB;        // NBUCK*NPB
    int*   bbase = pbase + NBUCK * NPB;       // NBUCK+1
    unsigned short* csr = (unsigned short*)(bbase + NBUCK + 1);  // E2 ushorts
    int*   ebuf  = (int*)H2;                  // E2 ints, dead before gat writes H2
    float* wbuf  = B_all;                     // E2 floats, dead before final gemm (side1)

    unsigned short* H1b = (unsigned short*)bufA;
    float* H3 = bufA;

    dim3 gL(782, 2);
    dim3 gF(782, 1);

    for (int side = 0; side < 2; ++side) {
        const float* S   = (const float*)d_in[side == 0 ? 2 : 3];
        const int*   edg = (const int*)  d_in[side == 0 ? 4 : 5];
        const float* W1  = (const float*)d_in[side == 0 ? 6 : 10];
        const float* avs = (const float*)d_in[side == 0 ? 7 : 11];
        const float* avn = (const float*)d_in[side == 0 ? 8 : 12];
        const float* om  = (const float*)d_in[side == 0 ? 9 : 13];
        const float* W2a = (const float*)d_in[side == 0 ? 14 : 17];
        const float* W2s = (const float*)d_in[side == 0 ? 15 : 18];
        const float* b2  = (const float*)d_in[side == 0 ? 16 : 19];
        const float* W3  = (const float*)d_in[side == 0 ? 20 : 21];
        const float* H4  = (const float*)d_in[side == 0 ? 22 : 23];
        float* OUT = side == 0 ? U_all : B_all;

        // H1b = bf16( S @ W1 )
        gemm_mfma<<<gL, 256, 0, stream>>>(
            S, W1, IN_DIM, nullptr, nullptr, 0, nullptr, nullptr,
            H1b, N, LATENT, 0, 1);

        rowdots<<<N / 4, 256, 0, stream>>>(H1b, avs, avn, asf, anb, N);

        // atomic-free bucketed CSR build (both graphs)
        part_count<<<NPB, 256, 0, stream>>>(edg, pcnt);
        part_scan<<<1, 1024, 0, stream>>>(pcnt, pbase, bbase, offs);
        part_fill<<<NPB, 256, 0, stream>>>(edg, pbase, bbase, ebuf);
        bucket_csr<<<NBUCK, 256, 0, stream>>>(ebuf, bbase, offs, csr);

        // per-edge softmax weights, then L2-range-blocked gather
        gat_weights<<<(VN + 3) / 4, 256, 0, stream>>>(asf, anb, offs, csr, om, wbuf);
        gat_gather<<<N / 4, 256, 0, stream>>>(H1b, offs, csr, wbuf, H2, N);

        // H3 = elu(H2@W2a + S@W2s + b2)
        gemm_mfma<<<gL, 256, 0, stream>>>(
            H2, W2a, LATENT, S, W2s, IN_DIM, b2, nullptr,
            H3, N, LATENT, 1, 0);

        // OUT = elu(H3@W3) + H4
        gemm_mfma<<<gF, 256, 0, stream>>>(
            H3, W3, LATENT, nullptr, nullptr, 0, nullptr, H4,
            OUT, N, FINALD, 1, 0);
    }

    predict<<<BATCHSZ / 4, 256, 0, stream>>>(
        (const int*)d_in[0], (const int*)d_in[1], U_all, B_all,
        (const float*)d_in[24], (const float*)d_in[25], (const float*)d_in[26],
        (float*)d_out, BATCHSZ);
}

// Round 6
// 540.589 us; speedup vs baseline: 1.8254x; 1.8254x over previous
//
#include <hip/hip_runtime.h>
#include <math.h>

#define N_NODES 50000
#define IN_DIM  256
#define LATENT  128
#define FINALD  64
#define NGRAPH  2
#define NEDGE   1000000
#define BATCHSZ 16384

#define VN      (2 * N_NODES)          // virtual dst ids (graph-major)
#define NBUCK   ((VN + 255) >> 8)      // 391 buckets of 256 dsts
#define E2      (2 * NEDGE)
#define NPB     256                    // partition blocks
#define PCH     ((E2 + NPB - 1) / NPB) // edges per partition block

typedef __attribute__((ext_vector_type(8))) short bf16x8;
typedef __attribute__((ext_vector_type(4))) float f32x4;
typedef __attribute__((ext_vector_type(8))) unsigned short u16x8;
typedef __attribute__((ext_vector_type(4))) unsigned short u16x4;

__device__ inline unsigned short f2bf(float x) {
    unsigned int u = __float_as_uint(x);
    u = (u + 0x7fffu + ((u >> 16) & 1u)) >> 16;
    return (unsigned short)u;
}
__device__ inline float bf2f(unsigned short h) {
    return __uint_as_float(((unsigned int)h) << 16);
}

// ---------------------------------------------------------------------------
// Split-precision bf16 MFMA GEMM (Ah@Bh + Ah@Bl + Al@Bh), 64x64 tile, BK=64.
// ---------------------------------------------------------------------------
#define GBM 64
#define GBK 64

__device__ inline int swz(int r, int k) {
    return r * GBK + ((((k >> 3) ^ (r & 7)) << 3) | (k & 7));
}

__global__ __launch_bounds__(256)
void gemm_mfma(const float* __restrict__ A1, const float* __restrict__ B1, int K1,
               const float* __restrict__ A2, const float* __restrict__ B2, int K2,
               const float* __restrict__ bias, const float* __restrict__ addm,
               void* __restrict__ Cout, int M, int Ncols, int act, int out_bf16)
{
    __shared__ unsigned short AhS[GBM * GBK];
    __shared__ unsigned short AlS[GBM * GBK];
    __shared__ unsigned short BhS[GBM * GBK];
    __shared__ unsigned short BlS[GBM * GBK];

    const int tid = threadIdx.x;
    const int rowBase = blockIdx.x * GBM;
    const int colBase = blockIdx.y * GBM;
    const int wave = tid >> 6, lane = tid & 63;
    const int wr = wave >> 1, wc = wave & 1;
    const int sl = lane & 15, lg = lane >> 4;

    f32x4 acc[2][2] = {};

    const float* Ap = A1;
    const float* Bp = B1;
    int K = K1;

    for (int pass = 0; pass < 2; ++pass) {
        if (pass == 1) { if (!A2) break; Ap = A2; Bp = B2; K = K2; }
        for (int k0 = 0; k0 < K; k0 += GBK) {
            __syncthreads();
            #pragma unroll
            for (int p = 0; p < 4; ++p) {
                int q = p * 256 + tid;
                int row = q >> 4;
                int kq = (q & 15) << 2;
                int grow = rowBase + row;
                float4 v = make_float4(0.f, 0.f, 0.f, 0.f);
                if (grow < M) v = *(const float4*)(Ap + (size_t)grow * K + k0 + kq);
                unsigned short h0 = f2bf(v.x), h1 = f2bf(v.y), h2 = f2bf(v.z), h3 = f2bf(v.w);
                u16x4 hv = {h0, h1, h2, h3};
                u16x4 lv = {f2bf(v.x - bf2f(h0)), f2bf(v.y - bf2f(h1)),
                            f2bf(v.z - bf2f(h2)), f2bf(v.w - bf2f(h3))};
                int off = swz(row, kq);
                *(u16x4*)&AhS[off] = hv;
                *(u16x4*)&AlS[off] = lv;
            }
            {
                int n = tid & 63;
                int kq = (tid >> 6) << 4;
                #pragma unroll
                for (int c = 0; c < 2; ++c) {
                    u16x8 hv, lv;
                    #pragma unroll
                    for (int j = 0; j < 8; ++j) {
                        float x = Bp[(size_t)(k0 + kq + c * 8 + j) * Ncols + colBase + n];
                        unsigned short h = f2bf(x);
                        hv[j] = h;
                        lv[j] = f2bf(x - bf2f(h));
                    }
                    int off = swz(n, kq + c * 8);
                    *(u16x8*)&BhS[off] = hv;
                    *(u16x8*)&BlS[off] = lv;
                }
            }
            __syncthreads();
            #pragma unroll
            for (int ks = 0; ks < 2; ++ks) {
                int kof = ks * 32 + lg * 8;
                bf16x8 ah[2], al[2], bh[2], bl[2];
                #pragma unroll
                for (int f = 0; f < 2; ++f) {
                    int m = wr * 32 + f * 16 + sl;
                    int oa = swz(m, kof);
                    ah[f] = *(const bf16x8*)&AhS[oa];
                    al[f] = *(const bf16x8*)&AlS[oa];
                    int n = wc * 32 + f * 16 + sl;
                    int ob = swz(n, kof);
                    bh[f] = *(const bf16x8*)&BhS[ob];
                    bl[f] = *(const bf16x8*)&BlS[ob];
                }
                #pragma unroll
                for (int fm = 0; fm < 2; ++fm)
                    #pragma unroll
                    for (int fn = 0; fn < 2; ++fn) {
                        acc[fm][fn] = __builtin_amdgcn_mfma_f32_16x16x32_bf16(ah[fm], bh[fn], acc[fm][fn], 0, 0, 0);
                        acc[fm][fn] = __builtin_amdgcn_mfma_f32_16x16x32_bf16(ah[fm], bl[fn], acc[fm][fn], 0, 0, 0);
                        acc[fm][fn] = __builtin_amdgcn_mfma_f32_16x16x32_bf16(al[fm], bh[fn], acc[fm][fn], 0, 0, 0);
                    }
            }
        }
    }

    #pragma unroll
    for (int fm = 0; fm < 2; ++fm)
        #pragma unroll
        for (int r = 0; r < 4; ++r) {
            int row = rowBase + wr * 32 + fm * 16 + lg * 4 + r;
            if (row >= M) continue;
            #pragma unroll
            for (int fn = 0; fn < 2; ++fn) {
                int col = colBase + wc * 32 + fn * 16 + sl;
                float v = acc[fm][fn][r];
                if (bias) v += bias[col];
                if (act) v = v > 0.f ? v : (__expf(v) - 1.f);
                if (addm) v += addm[(size_t)row * Ncols + col];
                if (out_bf16)
                    ((unsigned short*)Cout)[(size_t)row * Ncols + col] = f2bf(v);
                else
                    ((float*)Cout)[(size_t)row * Ncols + col] = v;
            }
        }
}

// ---------------------------------------------------------------------------
// alpha_self / alpha_nb from bf16 H1. Wave per row.
// ---------------------------------------------------------------------------
__global__ __launch_bounds__(256)
void rowdots(const unsigned short* __restrict__ H1b, const float* __restrict__ a1,
             const float* __restrict__ a2,
             float* __restrict__ o1, float* __restrict__ o2, int n)
{
    int lane = threadIdx.x & 63, wid = threadIdx.x >> 6;
    int row = blockIdx.x * 4 + wid;
    if (row >= n) return;
    unsigned int hv = *(const unsigned int*)(H1b + (size_t)row * LATENT + lane * 2);
    float h0 = bf2f((unsigned short)(hv & 0xffffu));
    float h1 = bf2f((unsigned short)(hv >> 16));
    float2 x = *(const float2*)(a1 + lane * 2);
    float2 y = *(const float2*)(a2 + lane * 2);
    float d1 = h0 * x.x + h1 * x.y;
    float d2 = h0 * y.x + h1 * y.y;
    #pragma unroll
    for (int o = 32; o; o >>= 1) {
        d1 += __shfl_xor(d1, o);
        d2 += __shfl_xor(d2, o);
    }
    if (lane == 0) { o1[row] = d1; o2[row] = d2; }
}

// ---------------------------------------------------------------------------
// Atomic-free bucketed counting sort by virtual dst (vd = g*N + dst).
// pcnt/pbase layout: [NBUCK][NPB] (bucket-major).
// ---------------------------------------------------------------------------
__global__ __launch_bounds__(256)
void part_count(const int* __restrict__ edg, int* __restrict__ pcnt)
{
    __shared__ int h[NBUCK];
    int tid = threadIdx.x;
    for (int i = tid; i < NBUCK; i += 256) h[i] = 0;
    __syncthreads();
    int start = blockIdx.x * PCH;
    int stop  = min(start + PCH, E2);
    for (int i = start + tid; i < stop; i += 256) {
        int g = i >= NEDGE;
        int idx = i - (g ? NEDGE : 0);
        int dst = edg[(size_t)g * E2 + NEDGE + idx];
        atomicAdd(&h[(g * N_NODES + dst) >> 8], 1);
    }
    __syncthreads();
    for (int i = tid; i < NBUCK; i += 256)
        pcnt[i * NPB + blockIdx.x] = h[i];
}

__global__ __launch_bounds__(1024)
void part_scan(const int* __restrict__ pcnt, int* __restrict__ pbase,
               int* __restrict__ bbase, int* __restrict__ offs)
{
    __shared__ int btot[NBUCK];
    int tid = threadIdx.x;
    int lane = tid & 63, w = tid >> 6;           // 16 waves
    for (int b = w; b < NBUCK; b += 16) {
        int4 v = *(const int4*)&pcnt[b * NPB + lane * 4];
        int s = v.x + v.y + v.z + v.w;
        int x = s;
        #pragma unroll
        for (int o = 1; o < 64; o <<= 1) {
            int y = __shfl_up(x, o);
            if (lane >= o) x += y;
        }
        int ex = x - s;                           // exclusive within bucket
        int* pb = &pbase[b * NPB + lane * 4];
        pb[0] = ex;
        pb[1] = ex + v.x;
        pb[2] = ex + v.x + v.y;
        pb[3] = ex + v.x + v.y + v.z;
        if (lane == 63) btot[b] = x;
    }
    __syncthreads();
    if (tid == 0) {
        int a = 0;
        for (int b = 0; b < NBUCK; ++b) { bbase[b] = a; a += btot[b]; }
        bbase[NBUCK] = a;
        offs[VN] = E2;
    }
}

__global__ __launch_bounds__(256)
void part_fill(const int* __restrict__ edg, const int* __restrict__ pbase,
               const int* __restrict__ bbase, int* __restrict__ ebuf)
{
    __shared__ int lbase[NBUCK];
    __shared__ int lcur[NBUCK];
    int tid = threadIdx.x;
    for (int i = tid; i < NBUCK; i += 256) {
        lbase[i] = bbase[i] + pbase[i * NPB + blockIdx.x];
        lcur[i] = 0;
    }
    __syncthreads();
    int start = blockIdx.x * PCH;
    int stop  = min(start + PCH, E2);
    for (int i = start + tid; i < stop; i += 256) {
        int g = i >= NEDGE;
        int idx = i - (g ? NEDGE : 0);
        int src = edg[(size_t)g * E2 + idx];
        int dst = edg[(size_t)g * E2 + NEDGE + idx];
        int vd = g * N_NODES + dst;
        int b = vd >> 8;
        int p = lbase[b] + atomicAdd(&lcur[b], 1);
        ebuf[p] = ((vd & 255) << 16) | src;
    }
}

__global__ __launch_bounds__(256)
void bucket_csr(const int* __restrict__ ebuf, const int* __restrict__ bbase,
                int* __restrict__ offs, unsigned short* __restrict__ csr)
{
    __shared__ int cnt[256];
    __shared__ int excl[256];
    __shared__ int cur[256];
    __shared__ int wsum[4];
    int tid = threadIdx.x;
    int b = blockIdx.x;
    int lo = bbase[b], hi = bbase[b + 1];

    cnt[tid] = 0; cur[tid] = 0;
    __syncthreads();
    for (int i = lo + tid; i < hi; i += 256)
        atomicAdd(&cnt[ebuf[i] >> 16], 1);
    __syncthreads();

    int lane = tid & 63, w = tid >> 6;
    int v = cnt[tid];
    int x = v;
    #pragma unroll
    for (int o = 1; o < 64; o <<= 1) {
        int y = __shfl_up(x, o);
        if (lane >= o) x += y;
    }
    if (lane == 63) wsum[w] = x;
    __syncthreads();
    int wb = 0;
    for (int i = 0; i < w; ++i) wb += wsum[i];
    int ex = wb + x - v;
    excl[tid] = ex;
    int vd = b * 256 + tid;
    if (vd < VN) offs[vd] = lo + ex;
    __syncthreads();

    for (int i = lo + tid; i < hi; i += 256) {
        int e = ebuf[i];
        int dl = e >> 16;
        int p = excl[dl] + atomicAdd(&cur[dl], 1);
        csr[lo + p] = (unsigned short)(e & 0xFFFF);
    }
}

// ---------------------------------------------------------------------------
// Phase 1: per-edge softmax weights. Wave per virtual dst segment.
// ---------------------------------------------------------------------------
__global__ __launch_bounds__(256)
void gat_weights(const float* __restrict__ asf, const float* __restrict__ anb,
                 const int* __restrict__ offs, const unsigned short* __restrict__ csr,
                 const float* __restrict__ omega, float* __restrict__ wbuf)
{
    int lane = threadIdx.x & 63, wid = threadIdx.x >> 6;
    int vd = blockIdx.x * 4 + wid;
    if (vd >= VN) return;
    int g = vd >= N_NODES;
    int d = vd - (g ? N_NODES : 0);
    int beg = offs[vd], end = offs[vd + 1];
    if (beg == end) return;
    float ad = asf[d];
    float om = omega[g];

    float m = -INFINITY;
    for (int e = beg + lane; e < end; e += 64) {
        float sc = ad + anb[csr[e]];
        sc = sc > 0.f ? sc : 0.2f * sc;
        m = fmaxf(m, sc);
    }
    #pragma unroll
    for (int o = 32; o; o >>= 1) m = fmaxf(m, __shfl_xor(m, o));

    float ss = 0.f;
    for (int e = beg + lane; e < end; e += 64) {
        float sc = ad + anb[csr[e]];
        sc = sc > 0.f ? sc : 0.2f * sc;
        ss += __expf(sc - m);
    }
    #pragma unroll
    for (int o = 32; o; o >>= 1) ss += __shfl_xor(ss, o);
    float wsc = om / (ss + 1e-16f);

    for (int e = beg + lane; e < end; e += 64) {
        float sc = ad + anb[csr[e]];
        sc = sc > 0.f ? sc : 0.2f * sc;
        wbuf[e] = __expf(sc - m) * wsc;
    }
}

// ---------------------------------------------------------------------------
// Phase 2: gather-accumulate. Wave per dst, 16-lane groups, 2-edge software
// pipeline per group => 8 independent H1b row-loads in flight per wave.
// ---------------------------------------------------------------------------
__global__ __launch_bounds__(256)
void gat_gather(const unsigned short* __restrict__ H1b,
                const int* __restrict__ offs, const unsigned short* __restrict__ csr,
                const float* __restrict__ wbuf,
                float* __restrict__ H2, int n)
{
    int lane = threadIdx.x & 63, wid = threadIdx.x >> 6;
    int d = blockIdx.x * 4 + wid;
    if (d >= n) return;
    int sub = lane >> 4, sl = lane & 15;
    float acc[8] = {};

    #pragma unroll
    for (int g = 0; g < NGRAPH; ++g) {
        int beg = offs[g * n + d], end = offs[g * n + d + 1];
        int e = beg + sub;
        // pipelined by 2: two independent row-load chains per group
        for (; e + 4 < end; e += 8) {
            int s0 = csr[e];
            int s1 = csr[e + 4];
            float w0 = wbuf[e];
            float w1 = wbuf[e + 4];
            u16x8 h0 = *(const u16x8*)(H1b + (size_t)s0 * LATENT + (sl << 3));
            u16x8 h1 = *(const u16x8*)(H1b + (size_t)s1 * LATENT + (sl << 3));
            #pragma unroll
            for (int j = 0; j < 8; ++j) acc[j] += w0 * bf2f(h0[j]);
            #pragma unroll
            for (int j = 0; j < 8; ++j) acc[j] += w1 * bf2f(h1[j]);
        }
        if (e < end) {
            int s0 = csr[e];
            float w0 = wbuf[e];
            u16x8 h0 = *(const u16x8*)(H1b + (size_t)s0 * LATENT + (sl << 3));
            #pragma unroll
            for (int j = 0; j < 8; ++j) acc[j] += w0 * bf2f(h0[j]);
        }
    }

    #pragma unroll
    for (int j = 0; j < 8; ++j) {
        acc[j] += __shfl_xor(acc[j], 32);
        acc[j] += __shfl_xor(acc[j], 16);
    }
    if (sub == 0) {
        float* dp = H2 + (size_t)d * LATENT + sl * 8;
        *(float4*)dp       = make_float4(acc[0], acc[1], acc[2], acc[3]);
        *(float4*)(dp + 4) = make_float4(acc[4], acc[5], acc[6], acc[7]);
    }
}

// ---------------------------------------------------------------------------
__global__ __launch_bounds__(256)
void predict(const int* __restrict__ uid, const int* __restrict__ iid,
             const float* __restrict__ U, const float* __restrict__ B,
             const float* __restrict__ bu, const float* __restrict__ bb,
             const float* __restrict__ bx, float* __restrict__ out, int batch)
{
    int lane = threadIdx.x & 63, wid = threadIdx.x >> 6;
    int b = blockIdx.x * 4 + wid;
    if (b >= batch) return;
    int u = uid[b], it = iid[b];
    float p = U[(size_t)u * FINALD + lane] * B[(size_t)it * FINALD + lane];
    #pragma unroll
    for (int o = 32; o; o >>= 1) p += __shfl_xor(p, o);
    if (lane == 0) {
        float raw = p + bu[u] + bb[it] + bx[0];
        out[b] = 4.f * (1.f / (1.f + __expf(-raw))) + 1.f;
    }
}

// ---------------------------------------------------------------------------
extern "C" void kernel_launch(void* const* d_in, const int* in_sizes, int n_in,
                              void* d_out, int out_size, void* d_ws, size_t ws_size,
                              hipStream_t stream)
{
    const int N = N_NODES;

    float* ws = (float*)d_ws;
    float* bufA  = ws;                        // H1b (bf16) then H3 (f32): 6.4e6 f
    float* H2    = ws + 6400000;              // 6.4e6 f  (ebuf overlays this)
    float* U_all = ws + 12800000;             // 3.2e6 f
    float* B_all = ws + 16000000;             // 3.2e6 f  (wbuf overlays this)
    float* asf   = ws + 19200000;             // 5e4
    float* anb   = asf + N;                   // 5e4
    int*   offs  = (int*)(anb + N);           // VN+1
    int*   pcnt  = offs + VN + 1;             // NBUCK*NPB
    int*   pbase = pcnt + NBUCK * NPB;        // NBUCK*NPB
    int*   bbase = pbase + NBUCK * NPB;       // NBUCK+1
    unsigned short* csr = (unsigned short*)(bbase + NBUCK + 1);  // E2 ushorts
    int*   ebuf  = (int*)H2;                  // E2 ints, dead before gat writes H2
    float* wbuf  = B_all;                     // E2 floats, dead before final gemm (side1)

    unsigned short* H1b = (unsigned short*)bufA;
    float* H3 = bufA;

    dim3 gL(782, 2);
    dim3 gF(782, 1);

    for (int side = 0; side < 2; ++side) {
        const float* S   = (const float*)d_in[side == 0 ? 2 : 3];
        const int*   edg = (const int*)  d_in[side == 0 ? 4 : 5];
        const float* W1  = (const float*)d_in[side == 0 ? 6 : 10];
        const float* avs = (const float*)d_in[side == 0 ? 7 : 11];
        const float* avn = (const float*)d_in[side == 0 ? 8 : 12];
        const float* om  = (const float*)d_in[side == 0 ? 9 : 13];
        const float* W2a = (const float*)d_in[side == 0 ? 14 : 17];
        const float* W2s = (const float*)d_in[side == 0 ? 15 : 18];
        const float* b2  = (const float*)d_in[side == 0 ? 16 : 19];
        const float* W3  = (const float*)d_in[side == 0 ? 20 : 21];
        const float* H4  = (const float*)d_in[side == 0 ? 22 : 23];
        float* OUT = side == 0 ? U_all : B_all;

        // H1b = bf16( S @ W1 )
        gemm_mfma<<<gL, 256, 0, stream>>>(
            S, W1, IN_DIM, nullptr, nullptr, 0, nullptr, nullptr,
            H1b, N, LATENT, 0, 1);

        rowdots<<<N / 4, 256, 0, stream>>>(H1b, avs, avn, asf, anb, N);

        // atomic-free bucketed CSR build (both graphs)
        part_count<<<NPB, 256, 0, stream>>>(edg, pcnt);
        part_scan<<<1, 1024, 0, stream>>>(pcnt, pbase, bbase, offs);
        part_fill<<<NPB, 256, 0, stream>>>(edg, pbase, bbase, ebuf);
        bucket_csr<<<NBUCK, 256, 0, stream>>>(ebuf, bbase, offs, csr);

        // per-edge softmax weights, then pipelined gather
        gat_weights<<<(VN + 3) / 4, 256, 0, stream>>>(asf, anb, offs, csr, om, wbuf);
        gat_gather<<<N / 4, 256, 0, stream>>>(H1b, offs, csr, wbuf, H2, N);

        // H3 = elu(H2@W2a + S@W2s + b2)
        gemm_mfma<<<gL, 256, 0, stream>>>(
            H2, W2a, LATENT, S, W2s, IN_DIM, b2, nullptr,
            H3, N, LATENT, 1, 0);

        // OUT = elu(H3@W3) + H4
        gemm_mfma<<<gF, 256, 0, stream>>>(
            H3, W3, LATENT, nullptr, nullptr, 0, nullptr, H4,
            OUT, N, FINALD, 1, 0);
    }

    predict<<<BATCHSZ / 4, 256, 0, stream>>>(
        (const int*)d_in[0], (const int*)d_in[1], U_all, B_all,
        (const float*)d_in[24], (const float*)d_in[25], (const float*)d_in[26],
        (float*)d_out, BATCHSZ);
}

// Round 7
// 524.882 us; speedup vs baseline: 1.8801x; 1.0299x over previous
//
#include <hip/hip_runtime.h>
#include <math.h>

#define N_NODES 50000
#define IN_DIM  256
#define LATENT  128
#define FINALD  64
#define NGRAPH  2
#define NEDGE   1000000
#define BATCHSZ 16384

#define VN      (2 * N_NODES)          // virtual dst ids (graph-major)
#define NBUCK   ((VN + 255) >> 8)      // 391 buckets of 256 dsts
#define E2      (2 * NEDGE)
#define NPB     256                    // partition blocks
#define PCH     ((E2 + NPB - 1) / NPB) // edges per partition block

// pre-split weight region: per side W1(256x128) W2a(128x128) W2s(256x128) W3(128x64)
#define WSP_SIDE   180224              // ushorts per side (2*(32768+16384+32768+8192))
#define WSP_ELEMS  90112               // f32 elems per side

typedef __attribute__((ext_vector_type(8))) short bf16x8;
typedef __attribute__((ext_vector_type(4))) float f32x4;
typedef __attribute__((ext_vector_type(8))) unsigned short u16x8;
typedef __attribute__((ext_vector_type(4))) unsigned short u16x4;

__device__ inline unsigned short f2bf(float x) {
    unsigned int u = __float_as_uint(x);
    u = (u + 0x7fffu + ((u >> 16) & 1u)) >> 16;
    return (unsigned short)u;
}
__device__ inline float bf2f(unsigned short h) {
    return __uint_as_float(((unsigned int)h) << 16);
}

// ---------------------------------------------------------------------------
// Weight pre-split: f32 [K][N] -> bf16 hi/lo, transposed k-major [N][K].
// One tiny kernel covering all 8 matrices of both sides.
// ---------------------------------------------------------------------------
__global__ __launch_bounds__(256)
void prep_weights(const float* __restrict__ W1u, const float* __restrict__ Wu2,
                  const float* __restrict__ Wus2, const float* __restrict__ Wu3,
                  const float* __restrict__ W1b, const float* __restrict__ Wb2,
                  const float* __restrict__ Wbs2, const float* __restrict__ Wb3,
                  unsigned short* __restrict__ dst)
{
    int e = blockIdx.x * 256 + threadIdx.x;
    if (e >= 2 * WSP_ELEMS) return;
    int side = e >= WSP_ELEMS;
    int r = e - (side ? WSP_ELEMS : 0);
    const float* src; int K, N, hoff;
    if (r < 32768)      { src = side ? W1b  : W1u;  K = 256; N = 128; hoff = 0;      }
    else if (r < 49152) { src = side ? Wb2  : Wu2;  K = 128; N = 128; hoff = 65536;  r -= 32768; }
    else if (r < 81920) { src = side ? Wbs2 : Wus2; K = 256; N = 128; hoff = 98304;  r -= 49152; }
    else                { src = side ? Wb3  : Wu3;  K = 128; N = 64;  hoff = 163840; r -= 81920; }
    int n = (K == 256) ? (r >> 8) : (r >> 7);
    int k = (K == 256) ? (r & 255) : (r & 127);
    float x = src[k * N + n];
    unsigned short h = f2bf(x);
    unsigned short l = f2bf(x - bf2f(h));
    unsigned short* base = dst + (size_t)side * WSP_SIDE;
    base[hoff + n * K + k] = h;
    base[hoff + K * N + n * K + k] = l;
}

// ---------------------------------------------------------------------------
// Split-precision bf16 MFMA GEMM (Ah@Bh + Ah@Bl + Al@Bh), 64x64 tile, BK=64.
// A: f32 row-major (split on the fly). B: pre-split bf16 hi/lo, k-major [N][K].
// ---------------------------------------------------------------------------
#define GBM 64
#define GBK 64

__device__ inline int swz(int r, int k) {
    return r * GBK + ((((k >> 3) ^ (r & 7)) << 3) | (k & 7));
}

__global__ __launch_bounds__(256)
void gemm_mfma(const float* __restrict__ A1,
               const unsigned short* __restrict__ B1h, const unsigned short* __restrict__ B1l, int K1,
               const float* __restrict__ A2,
               const unsigned short* __restrict__ B2h, const unsigned short* __restrict__ B2l, int K2,
               const float* __restrict__ bias, const float* __restrict__ addm,
               void* __restrict__ Cout, int M, int Ncols, int act, int out_bf16)
{
    __shared__ unsigned short AhS[GBM * GBK];
    __shared__ unsigned short AlS[GBM * GBK];
    __shared__ unsigned short BhS[GBM * GBK];
    __shared__ unsigned short BlS[GBM * GBK];

    const int tid = threadIdx.x;
    const int rowBase = blockIdx.x * GBM;
    const int colBase = blockIdx.y * GBM;
    const int wave = tid >> 6, lane = tid & 63;
    const int wr = wave >> 1, wc = wave & 1;
    const int sl = lane & 15, lg = lane >> 4;

    f32x4 acc[2][2] = {};

    const float* Ap = A1;
    const unsigned short* Bph = B1h;
    const unsigned short* Bpl = B1l;
    int K = K1;

    for (int pass = 0; pass < 2; ++pass) {
        if (pass == 1) { if (!A2) break; Ap = A2; Bph = B2h; Bpl = B2l; K = K2; }
        for (int k0 = 0; k0 < K; k0 += GBK) {
            __syncthreads();
            // ---- stage A tile (f32 -> hi/lo split)
            #pragma unroll
            for (int p = 0; p < 4; ++p) {
                int q = p * 256 + tid;
                int row = q >> 4;
                int kq = (q & 15) << 2;
                int grow = rowBase + row;
                float4 v = make_float4(0.f, 0.f, 0.f, 0.f);
                if (grow < M) v = *(const float4*)(Ap + (size_t)grow * K + k0 + kq);
                unsigned short h0 = f2bf(v.x), h1 = f2bf(v.y), h2 = f2bf(v.z), h3 = f2bf(v.w);
                u16x4 hv = {h0, h1, h2, h3};
                u16x4 lv = {f2bf(v.x - bf2f(h0)), f2bf(v.y - bf2f(h1)),
                            f2bf(v.z - bf2f(h2)), f2bf(v.w - bf2f(h3))};
                int off = swz(row, kq);
                *(u16x4*)&AhS[off] = hv;
                *(u16x4*)&AlS[off] = lv;
            }
            // ---- stage B tile: pre-split, k-major -> pure vector copies
            {
                int n = tid & 63;
                int kq = (tid >> 6) << 4;   // 0,16,32,48
                const unsigned short* bp = Bph + (size_t)(colBase + n) * K + k0 + kq;
                const unsigned short* lp = Bpl + (size_t)(colBase + n) * K + k0 + kq;
                u16x8 h0 = *(const u16x8*)bp;
                u16x8 h1 = *(const u16x8*)(bp + 8);
                u16x8 l0 = *(const u16x8*)lp;
                u16x8 l1 = *(const u16x8*)(lp + 8);
                *(u16x8*)&BhS[swz(n, kq)]     = h0;
                *(u16x8*)&BhS[swz(n, kq + 8)] = h1;
                *(u16x8*)&BlS[swz(n, kq)]     = l0;
                *(u16x8*)&BlS[swz(n, kq + 8)] = l1;
            }
            __syncthreads();
            #pragma unroll
            for (int ks = 0; ks < 2; ++ks) {
                int kof = ks * 32 + lg * 8;
                bf16x8 ah[2], al[2], bh[2], bl[2];
                #pragma unroll
                for (int f = 0; f < 2; ++f) {
                    int m = wr * 32 + f * 16 + sl;
                    int oa = swz(m, kof);
                    ah[f] = *(const bf16x8*)&AhS[oa];
                    al[f] = *(const bf16x8*)&AlS[oa];
                    int n = wc * 32 + f * 16 + sl;
                    int ob = swz(n, kof);
                    bh[f] = *(const bf16x8*)&BhS[ob];
                    bl[f] = *(const bf16x8*)&BlS[ob];
                }
                #pragma unroll
                for (int fm = 0; fm < 2; ++fm)
                    #pragma unroll
                    for (int fn = 0; fn < 2; ++fn) {
                        acc[fm][fn] = __builtin_amdgcn_mfma_f32_16x16x32_bf16(ah[fm], bh[fn], acc[fm][fn], 0, 0, 0);
                        acc[fm][fn] = __builtin_amdgcn_mfma_f32_16x16x32_bf16(ah[fm], bl[fn], acc[fm][fn], 0, 0, 0);
                        acc[fm][fn] = __builtin_amdgcn_mfma_f32_16x16x32_bf16(al[fm], bh[fn], acc[fm][fn], 0, 0, 0);
                    }
            }
        }
    }

    #pragma unroll
    for (int fm = 0; fm < 2; ++fm)
        #pragma unroll
        for (int r = 0; r < 4; ++r) {
            int row = rowBase + wr * 32 + fm * 16 + lg * 4 + r;
            if (row >= M) continue;
            #pragma unroll
            for (int fn = 0; fn < 2; ++fn) {
                int col = colBase + wc * 32 + fn * 16 + sl;
                float v = acc[fm][fn][r];
                if (bias) v += bias[col];
                if (act) v = v > 0.f ? v : (__expf(v) - 1.f);
                if (addm) v += addm[(size_t)row * Ncols + col];
                if (out_bf16)
                    ((unsigned short*)Cout)[(size_t)row * Ncols + col] = f2bf(v);
                else
                    ((float*)Cout)[(size_t)row * Ncols + col] = v;
            }
        }
}

// ---------------------------------------------------------------------------
// alpha_self / alpha_nb from bf16 H1. Wave per row.
// ---------------------------------------------------------------------------
__global__ __launch_bounds__(256)
void rowdots(const unsigned short* __restrict__ H1b, const float* __restrict__ a1,
             const float* __restrict__ a2,
             float* __restrict__ o1, float* __restrict__ o2, int n)
{
    int lane = threadIdx.x & 63, wid = threadIdx.x >> 6;
    int row = blockIdx.x * 4 + wid;
    if (row >= n) return;
    unsigned int hv = *(const unsigned int*)(H1b + (size_t)row * LATENT + lane * 2);
    float h0 = bf2f((unsigned short)(hv & 0xffffu));
    float h1 = bf2f((unsigned short)(hv >> 16));
    float2 x = *(const float2*)(a1 + lane * 2);
    float2 y = *(const float2*)(a2 + lane * 2);
    float d1 = h0 * x.x + h1 * x.y;
    float d2 = h0 * y.x + h1 * y.y;
    #pragma unroll
    for (int o = 32; o; o >>= 1) {
        d1 += __shfl_xor(d1, o);
        d2 += __shfl_xor(d2, o);
    }
    if (lane == 0) { o1[row] = d1; o2[row] = d2; }
}

// ---------------------------------------------------------------------------
// Atomic-free bucketed counting sort by virtual dst (vd = g*N + dst).
// ---------------------------------------------------------------------------
__global__ __launch_bounds__(256)
void part_count(const int* __restrict__ edg, int* __restrict__ pcnt)
{
    __shared__ int h[NBUCK];
    int tid = threadIdx.x;
    for (int i = tid; i < NBUCK; i += 256) h[i] = 0;
    __syncthreads();
    int start = blockIdx.x * PCH;
    int stop  = min(start + PCH, E2);
    for (int i = start + tid; i < stop; i += 256) {
        int g = i >= NEDGE;
        int idx = i - (g ? NEDGE : 0);
        int dst = edg[(size_t)g * E2 + NEDGE + idx];
        atomicAdd(&h[(g * N_NODES + dst) >> 8], 1);
    }
    __syncthreads();
    for (int i = tid; i < NBUCK; i += 256)
        pcnt[i * NPB + blockIdx.x] = h[i];
}

__global__ __launch_bounds__(1024)
void part_scan(const int* __restrict__ pcnt, int* __restrict__ pbase,
               int* __restrict__ bbase, int* __restrict__ offs)
{
    __shared__ int btot[NBUCK];
    int tid = threadIdx.x;
    int lane = tid & 63, w = tid >> 6;           // 16 waves
    for (int b = w; b < NBUCK; b += 16) {
        int4 v = *(const int4*)&pcnt[b * NPB + lane * 4];
        int s = v.x + v.y + v.z + v.w;
        int x = s;
        #pragma unroll
        for (int o = 1; o < 64; o <<= 1) {
            int y = __shfl_up(x, o);
            if (lane >= o) x += y;
        }
        int ex = x - s;
        int* pb = &pbase[b * NPB + lane * 4];
        pb[0] = ex;
        pb[1] = ex + v.x;
        pb[2] = ex + v.x + v.y;
        pb[3] = ex + v.x + v.y + v.z;
        if (lane == 63) btot[b] = x;
    }
    __syncthreads();
    if (tid == 0) {
        int a = 0;
        for (int b = 0; b < NBUCK; ++b) { bbase[b] = a; a += btot[b]; }
        bbase[NBUCK] = a;
        offs[VN] = E2;
    }
}

__global__ __launch_bounds__(256)
void part_fill(const int* __restrict__ edg, const int* __restrict__ pbase,
               const int* __restrict__ bbase, int* __restrict__ ebuf)
{
    __shared__ int lbase[NBUCK];
    __shared__ int lcur[NBUCK];
    int tid = threadIdx.x;
    for (int i = tid; i < NBUCK; i += 256) {
        lbase[i] = bbase[i] + pbase[i * NPB + blockIdx.x];
        lcur[i] = 0;
    }
    __syncthreads();
    int start = blockIdx.x * PCH;
    int stop  = min(start + PCH, E2);
    for (int i = start + tid; i < stop; i += 256) {
        int g = i >= NEDGE;
        int idx = i - (g ? NEDGE : 0);
        int src = edg[(size_t)g * E2 + idx];
        int dst = edg[(size_t)g * E2 + NEDGE + idx];
        int vd = g * N_NODES + dst;
        int b = vd >> 8;
        int p = lbase[b] + atomicAdd(&lcur[b], 1);
        ebuf[p] = ((vd & 255) << 16) | src;
    }
}

__global__ __launch_bounds__(256)
void bucket_csr(const int* __restrict__ ebuf, const int* __restrict__ bbase,
                int* __restrict__ offs, unsigned short* __restrict__ csr)
{
    __shared__ int cnt[256];
    __shared__ int excl[256];
    __shared__ int cur[256];
    __shared__ int wsum[4];
    int tid = threadIdx.x;
    int b = blockIdx.x;
    int lo = bbase[b], hi = bbase[b + 1];

    cnt[tid] = 0; cur[tid] = 0;
    __syncthreads();
    for (int i = lo + tid; i < hi; i += 256)
        atomicAdd(&cnt[ebuf[i] >> 16], 1);
    __syncthreads();

    int lane = tid & 63, w = tid >> 6;
    int v = cnt[tid];
    int x = v;
    #pragma unroll
    for (int o = 1; o < 64; o <<= 1) {
        int y = __shfl_up(x, o);
        if (lane >= o) x += y;
    }
    if (lane == 63) wsum[w] = x;
    __syncthreads();
    int wb = 0;
    for (int i = 0; i < w; ++i) wb += wsum[i];
    int ex = wb + x - v;
    excl[tid] = ex;
    int vd = b * 256 + tid;
    if (vd < VN) offs[vd] = lo + ex;
    __syncthreads();

    for (int i = lo + tid; i < hi; i += 256) {
        int e = ebuf[i];
        int dl = e >> 16;
        int p = excl[dl] + atomicAdd(&cur[dl], 1);
        csr[lo + p] = (unsigned short)(e & 0xFFFF);
    }
}

// ---------------------------------------------------------------------------
// Merged GAT aggregation: shift-free softmax (scores bounded, shift cancels
// exactly in e/sum), 2 passes: 64-lane sum-of-exp, then pipelined 16x4 gather.
// ---------------------------------------------------------------------------
__global__ __launch_bounds__(256)
void gat_gather(const unsigned short* __restrict__ H1b, const float* __restrict__ asf,
                const float* __restrict__ anb,
                const int* __restrict__ offs, const unsigned short* __restrict__ csr,
                const float* __restrict__ omega,
                float* __restrict__ H2, int n)
{
    int lane = threadIdx.x & 63, wid = threadIdx.x >> 6;
    int d = blockIdx.x * 4 + wid;
    if (d >= n) return;
    float ad = asf[d];
    int sub = lane >> 4, sl = lane & 15;
    float acc[8] = {};

    #pragma unroll
    for (int g = 0; g < NGRAPH; ++g) {
        int beg = offs[g * n + d], end = offs[g * n + d + 1];
        float om = omega[g];

        // pass 1: sum of exp (no shift needed: |score| <= ~10, exp safe in f32)
        float ss = 0.f;
        for (int e = beg + lane; e < end; e += 64) {
            float sc = ad + anb[csr[e]];
            sc = sc > 0.f ? sc : 0.2f * sc;
            ss += __expf(sc);
        }
        #pragma unroll
        for (int o = 32; o; o >>= 1) ss += __shfl_xor(ss, o);
        float wsc = om / (ss + 1e-16f);

        // pass 2: pipelined gather, weight recomputed inline
        int e = beg + sub;
        for (; e + 4 < end; e += 8) {
            int s0 = csr[e];
            int s1 = csr[e + 4];
            float a0 = anb[s0];
            float a1 = anb[s1];
            u16x8 h0 = *(const u16x8*)(H1b + (size_t)s0 * LATENT + (sl << 3));
            u16x8 h1 = *(const u16x8*)(H1b + (size_t)s1 * LATENT + (sl << 3));
            float sc0 = ad + a0; sc0 = sc0 > 0.f ? sc0 : 0.2f * sc0;
            float sc1 = ad + a1; sc1 = sc1 > 0.f ? sc1 : 0.2f * sc1;
            float w0 = __expf(sc0) * wsc;
            float w1 = __expf(sc1) * wsc;
            #pragma unroll
            for (int j = 0; j < 8; ++j) acc[j] += w0 * bf2f(h0[j]);
            #pragma unroll
            for (int j = 0; j < 8; ++j) acc[j] += w1 * bf2f(h1[j]);
        }
        if (e < end) {
            int s0 = csr[e];
            float a0 = anb[s0];
            u16x8 h0 = *(const u16x8*)(H1b + (size_t)s0 * LATENT + (sl << 3));
            float sc0 = ad + a0; sc0 = sc0 > 0.f ? sc0 : 0.2f * sc0;
            float w0 = __expf(sc0) * wsc;
            #pragma unroll
            for (int j = 0; j < 8; ++j) acc[j] += w0 * bf2f(h0[j]);
        }
    }

    #pragma unroll
    for (int j = 0; j < 8; ++j) {
        acc[j] += __shfl_xor(acc[j], 32);
        acc[j] += __shfl_xor(acc[j], 16);
    }
    if (sub == 0) {
        float* dp = H2 + (size_t)d * LATENT + sl * 8;
        *(float4*)dp       = make_float4(acc[0], acc[1], acc[2], acc[3]);
        *(float4*)(dp + 4) = make_float4(acc[4], acc[5], acc[6], acc[7]);
    }
}

// ---------------------------------------------------------------------------
__global__ __launch_bounds__(256)
void predict(const int* __restrict__ uid, const int* __restrict__ iid,
             const float* __restrict__ U, const float* __restrict__ B,
             const float* __restrict__ bu, const float* __restrict__ bb,
             const float* __restrict__ bx, float* __restrict__ out, int batch)
{
    int lane = threadIdx.x & 63, wid = threadIdx.x >> 6;
    int b = blockIdx.x * 4 + wid;
    if (b >= batch) return;
    int u = uid[b], it = iid[b];
    float p = U[(size_t)u * FINALD + lane] * B[(size_t)it * FINALD + lane];
    #pragma unroll
    for (int o = 32; o; o >>= 1) p += __shfl_xor(p, o);
    if (lane == 0) {
        float raw = p + bu[u] + bb[it] + bx[0];
        out[b] = 4.f * (1.f / (1.f + __expf(-raw))) + 1.f;
    }
}

// ---------------------------------------------------------------------------
extern "C" void kernel_launch(void* const* d_in, const int* in_sizes, int n_in,
                              void* d_out, int out_size, void* d_ws, size_t ws_size,
                              hipStream_t stream)
{
    const int N = N_NODES;

    float* ws = (float*)d_ws;
    float* bufA  = ws;                        // H1b (bf16) then H3 (f32): 6.4e6 f
    float* H2    = ws + 6400000;              // 6.4e6 f  (ebuf overlays this)
    float* U_all = ws + 12800000;             // 3.2e6 f
    float* B_all = ws + 16000000;             // 3.2e6 f
    float* asf   = ws + 19200000;             // 5e4
    float* anb   = asf + N;                   // 5e4
    int*   offs  = (int*)(anb + N);           // VN+1
    int*   pcnt  = offs + VN + 1;             // NBUCK*NPB
    int*   pbase = pcnt + NBUCK * NPB;        // NBUCK*NPB
    int*   bbase = pbase + NBUCK * NPB;       // NBUCK+1
    unsigned short* csr = (unsigned short*)(bbase + NBUCK + 1);  // E2 ushorts
    unsigned short* wsp = (unsigned short*)(((uintptr_t)(csr + E2) + 15) & ~(uintptr_t)15);
    int*   ebuf  = (int*)H2;                  // E2 ints, dead before gat writes H2

    unsigned short* H1b = (unsigned short*)bufA;
    float* H3 = bufA;

    dim3 gL(782, 2);
    dim3 gF(782, 1);

    // pre-split + transpose all weight matrices (both sides)
    prep_weights<<<(2 * WSP_ELEMS + 255) / 256, 256, 0, stream>>>(
        (const float*)d_in[6],  (const float*)d_in[14], (const float*)d_in[15], (const float*)d_in[20],
        (const float*)d_in[10], (const float*)d_in[17], (const float*)d_in[18], (const float*)d_in[21],
        wsp);

    for (int side = 0; side < 2; ++side) {
        const float* S   = (const float*)d_in[side == 0 ? 2 : 3];
        const int*   edg = (const int*)  d_in[side == 0 ? 4 : 5];
        const float* avs = (const float*)d_in[side == 0 ? 7 : 11];
        const float* avn = (const float*)d_in[side == 0 ? 8 : 12];
        const float* om  = (const float*)d_in[side == 0 ? 9 : 13];
        const float* b2  = (const float*)d_in[side == 0 ? 16 : 19];
        const float* H4  = (const float*)d_in[side == 0 ? 22 : 23];
        float* OUT = side == 0 ? U_all : B_all;

        unsigned short* wb = wsp + (size_t)side * WSP_SIDE;
        const unsigned short* W1h  = wb;
        const unsigned short* W1l  = wb + 32768;
        const unsigned short* W2ah = wb + 65536;
        const unsigned short* W2al = wb + 81920;
        const unsigned short* W2sh = wb + 98304;
        const unsigned short* W2sl = wb + 131072;
        const unsigned short* W3h  = wb + 163840;
        const unsigned short* W3l  = wb + 172032;

        // H1b = bf16( S @ W1 )
        gemm_mfma<<<gL, 256, 0, stream>>>(
            S, W1h, W1l, IN_DIM, nullptr, nullptr, nullptr, 0,
            nullptr, nullptr, H1b, N, LATENT, 0, 1);

        rowdots<<<N / 4, 256, 0, stream>>>(H1b, avs, avn, asf, anb, N);

        // atomic-free bucketed CSR build (both graphs)
        part_count<<<NPB, 256, 0, stream>>>(edg, pcnt);
        part_scan<<<1, 1024, 0, stream>>>(pcnt, pbase, bbase, offs);
        part_fill<<<NPB, 256, 0, stream>>>(edg, pbase, bbase, ebuf);
        bucket_csr<<<NBUCK, 256, 0, stream>>>(ebuf, bbase, offs, csr);

        // merged 2-pass aggregation (shift-free softmax + pipelined gather)
        gat_gather<<<N / 4, 256, 0, stream>>>(
            H1b, asf, anb, offs, csr, om, H2, N);

        // H3 = elu(H2@W2a + S@W2s + b2)
        gemm_mfma<<<gL, 256, 0, stream>>>(
            H2, W2ah, W2al, LATENT, S, W2sh, W2sl, IN_DIM,
            b2, nullptr, H3, N, LATENT, 1, 0);

        // OUT = elu(H3@W3) + H4
        gemm_mfma<<<gF, 256, 0, stream>>>(
            H3, W3h, W3l, LATENT, nullptr, nullptr, nullptr, 0,
            nullptr, H4, OUT, N, FINALD, 1, 0);
    }

    predict<<<BATCHSZ / 4, 256, 0, stream>>>(
        (const int*)d_in[0], (const int*)d_in[1], U_all, B_all,
        (const float*)d_in[24], (const float*)d_in[25], (const float*)d_in[26],
        (float*)d_out, BATCHSZ);
}

// Round 8
// 451.531 us; speedup vs baseline: 2.1855x; 1.1624x over previous
//
#include <hip/hip_runtime.h>
#include <math.h>

#define N_NODES 50000
#define IN_DIM  256
#define LATENT  128
#define FINALD  64
#define NGRAPH  2
#define NEDGE   1000000
#define BATCHSZ 16384

#define VN      (2 * N_NODES)          // virtual dst ids (graph-major)
#define NBUCK   ((VN + 255) >> 8)      // 391 buckets of 256 dsts
#define E2      (2 * NEDGE)
#define NPB     256                    // partition blocks
#define PCH     ((E2 + NPB - 1) / NPB) // edges per partition block
#define BCAP    8192                   // bucket_csr LDS cache entries

// pre-split (bf16-hi only) weights: per side W1(256x128) W2a(128x128) W2s(256x128) W3(128x64)
#define WSP_SIDE   90112               // ushorts per side
#define WSP_ELEMS  90112

typedef __attribute__((ext_vector_type(8))) short bf16x8;
typedef __attribute__((ext_vector_type(4))) float f32x4;
typedef __attribute__((ext_vector_type(8))) unsigned short u16x8;
typedef __attribute__((ext_vector_type(4))) unsigned short u16x4;

__device__ inline unsigned short f2bf(float x) {
    unsigned int u = __float_as_uint(x);
    u = (u + 0x7fffu + ((u >> 16) & 1u)) >> 16;
    return (unsigned short)u;
}
__device__ inline float bf2f(unsigned short h) {
    return __uint_as_float(((unsigned int)h) << 16);
}

// ---------------------------------------------------------------------------
// Weight prep: f32 [K][N] -> bf16, transposed k-major [N][K]. Both sides.
// ---------------------------------------------------------------------------
__global__ __launch_bounds__(256)
void prep_weights(const float* __restrict__ W1u, const float* __restrict__ Wu2,
                  const float* __restrict__ Wus2, const float* __restrict__ Wu3,
                  const float* __restrict__ W1b, const float* __restrict__ Wb2,
                  const float* __restrict__ Wbs2, const float* __restrict__ Wb3,
                  unsigned short* __restrict__ dst)
{
    int e = blockIdx.x * 256 + threadIdx.x;
    if (e >= 2 * WSP_ELEMS) return;
    int side = e >= WSP_ELEMS;
    int r = e - (side ? WSP_ELEMS : 0);
    const float* src; int K, N, hoff;
    if (r < 32768)      { src = side ? W1b  : W1u;  K = 256; N = 128; hoff = 0;     }
    else if (r < 49152) { src = side ? Wb2  : Wu2;  K = 128; N = 128; hoff = 32768; r -= 32768; }
    else if (r < 81920) { src = side ? Wbs2 : Wus2; K = 256; N = 128; hoff = 49152; r -= 49152; }
    else                { src = side ? Wb3  : Wu3;  K = 128; N = 64;  hoff = 81920; r -= 81920; }
    int n = (K == 256) ? (r >> 8) : (r >> 7);
    int k = (K == 256) ? (r & 255) : (r & 127);
    dst[(size_t)side * WSP_SIDE + hoff + n * K + k] = f2bf(src[k * N + n]);
}

// ---------------------------------------------------------------------------
// Pure-bf16 MFMA GEMM (1 MFMA/fragment). 64x64 tile, BK=64.
// A: f32 row-major (cvt on stage). B: pre-cvt bf16 k-major [N][K].
// ---------------------------------------------------------------------------
#define GBM 64
#define GBK 64

__device__ inline int swz(int r, int k) {
    return r * GBK + ((((k >> 3) ^ (r & 7)) << 3) | (k & 7));
}

__global__ __launch_bounds__(256)
void gemm_mfma(const float* __restrict__ A1, const unsigned short* __restrict__ B1h, int K1,
               const float* __restrict__ A2, const unsigned short* __restrict__ B2h, int K2,
               const float* __restrict__ bias, const float* __restrict__ addm,
               void* __restrict__ Cout, int M, int Ncols, int act, int out_bf16)
{
    __shared__ unsigned short AhS[GBM * GBK];
    __shared__ unsigned short BhS[GBM * GBK];

    const int tid = threadIdx.x;
    const int rowBase = blockIdx.x * GBM;
    const int colBase = blockIdx.y * GBM;
    const int wave = tid >> 6, lane = tid & 63;
    const int wr = wave >> 1, wc = wave & 1;
    const int sl = lane & 15, lg = lane >> 4;

    f32x4 acc[2][2] = {};

    const float* Ap = A1;
    const unsigned short* Bph = B1h;
    int K = K1;

    for (int pass = 0; pass < 2; ++pass) {
        if (pass == 1) { if (!A2) break; Ap = A2; Bph = B2h; K = K2; }
        for (int k0 = 0; k0 < K; k0 += GBK) {
            __syncthreads();
            // stage A (f32 -> bf16)
            #pragma unroll
            for (int p = 0; p < 4; ++p) {
                int q = p * 256 + tid;
                int row = q >> 4;
                int kq = (q & 15) << 2;
                int grow = rowBase + row;
                float4 v = make_float4(0.f, 0.f, 0.f, 0.f);
                if (grow < M) v = *(const float4*)(Ap + (size_t)grow * K + k0 + kq);
                u16x4 hv = {f2bf(v.x), f2bf(v.y), f2bf(v.z), f2bf(v.w)};
                *(u16x4*)&AhS[swz(row, kq)] = hv;
            }
            // stage B (pre-cvt, k-major vector copies)
            {
                int n = tid & 63;
                int kq = (tid >> 6) << 4;   // 0,16,32,48
                const unsigned short* bp = Bph + (size_t)(colBase + n) * K + k0 + kq;
                u16x8 h0 = *(const u16x8*)bp;
                u16x8 h1 = *(const u16x8*)(bp + 8);
                *(u16x8*)&BhS[swz(n, kq)]     = h0;
                *(u16x8*)&BhS[swz(n, kq + 8)] = h1;
            }
            __syncthreads();
            #pragma unroll
            for (int ks = 0; ks < 2; ++ks) {
                int kof = ks * 32 + lg * 8;
                bf16x8 ah[2], bh[2];
                #pragma unroll
                for (int f = 0; f < 2; ++f) {
                    ah[f] = *(const bf16x8*)&AhS[swz(wr * 32 + f * 16 + sl, kof)];
                    bh[f] = *(const bf16x8*)&BhS[swz(wc * 32 + f * 16 + sl, kof)];
                }
                #pragma unroll
                for (int fm = 0; fm < 2; ++fm)
                    #pragma unroll
                    for (int fn = 0; fn < 2; ++fn)
                        acc[fm][fn] = __builtin_amdgcn_mfma_f32_16x16x32_bf16(ah[fm], bh[fn], acc[fm][fn], 0, 0, 0);
            }
        }
    }

    #pragma unroll
    for (int fm = 0; fm < 2; ++fm)
        #pragma unroll
        for (int r = 0; r < 4; ++r) {
            int row = rowBase + wr * 32 + fm * 16 + lg * 4 + r;
            if (row >= M) continue;
            #pragma unroll
            for (int fn = 0; fn < 2; ++fn) {
                int col = colBase + wc * 32 + fn * 16 + sl;
                float v = acc[fm][fn][r];
                if (bias) v += bias[col];
                if (act) v = v > 0.f ? v : (__expf(v) - 1.f);
                if (addm) v += addm[(size_t)row * Ncols + col];
                if (out_bf16)
                    ((unsigned short*)Cout)[(size_t)row * Ncols + col] = f2bf(v);
                else
                    ((float*)Cout)[(size_t)row * Ncols + col] = v;
            }
        }
}

// ---------------------------------------------------------------------------
// alpha_self / alpha_nb from bf16 H1. Wave per row.
// ---------------------------------------------------------------------------
__global__ __launch_bounds__(256)
void rowdots(const unsigned short* __restrict__ H1b, const float* __restrict__ a1,
             const float* __restrict__ a2,
             float* __restrict__ o1, float* __restrict__ o2, int n)
{
    int lane = threadIdx.x & 63, wid = threadIdx.x >> 6;
    int row = blockIdx.x * 4 + wid;
    if (row >= n) return;
    unsigned int hv = *(const unsigned int*)(H1b + (size_t)row * LATENT + lane * 2);
    float h0 = bf2f((unsigned short)(hv & 0xffffu));
    float h1 = bf2f((unsigned short)(hv >> 16));
    float2 x = *(const float2*)(a1 + lane * 2);
    float2 y = *(const float2*)(a2 + lane * 2);
    float d1 = h0 * x.x + h1 * x.y;
    float d2 = h0 * y.x + h1 * y.y;
    #pragma unroll
    for (int o = 32; o; o >>= 1) {
        d1 += __shfl_xor(d1, o);
        d2 += __shfl_xor(d2, o);
    }
    if (lane == 0) { o1[row] = d1; o2[row] = d2; }
}

// ---------------------------------------------------------------------------
// Atomic-free bucketed counting sort by virtual dst (vd = g*N + dst).
// ---------------------------------------------------------------------------
__global__ __launch_bounds__(256)
void part_count(const int* __restrict__ edg, int* __restrict__ pcnt)
{
    __shared__ int h[NBUCK];
    int tid = threadIdx.x;
    for (int i = tid; i < NBUCK; i += 256) h[i] = 0;
    __syncthreads();
    int start = blockIdx.x * PCH;
    int stop  = min(start + PCH, E2);
    for (int i = start + tid; i < stop; i += 256) {
        int g = i >= NEDGE;
        int idx = i - (g ? NEDGE : 0);
        int dst = edg[(size_t)g * E2 + NEDGE + idx];
        atomicAdd(&h[(g * N_NODES + dst) >> 8], 1);
    }
    __syncthreads();
    for (int i = tid; i < NBUCK; i += 256)
        pcnt[i * NPB + blockIdx.x] = h[i];
}

__global__ __launch_bounds__(1024)
void part_scan(const int* __restrict__ pcnt, int* __restrict__ pbase,
               int* __restrict__ bbase, int* __restrict__ offs)
{
    __shared__ int btot[NBUCK];
    int tid = threadIdx.x;
    int lane = tid & 63, w = tid >> 6;           // 16 waves
    for (int b = w; b < NBUCK; b += 16) {
        int4 v = *(const int4*)&pcnt[b * NPB + lane * 4];
        int s = v.x + v.y + v.z + v.w;
        int x = s;
        #pragma unroll
        for (int o = 1; o < 64; o <<= 1) {
            int y = __shfl_up(x, o);
            if (lane >= o) x += y;
        }
        int ex = x - s;
        int* pb = &pbase[b * NPB + lane * 4];
        pb[0] = ex;
        pb[1] = ex + v.x;
        pb[2] = ex + v.x + v.y;
        pb[3] = ex + v.x + v.y + v.z;
        if (lane == 63) btot[b] = x;
    }
    __syncthreads();
    if (tid == 0) {
        int a = 0;
        for (int b = 0; b < NBUCK; ++b) { bbase[b] = a; a += btot[b]; }
        bbase[NBUCK] = a;
        offs[VN] = E2;
    }
}

__global__ __launch_bounds__(256)
void part_fill(const int* __restrict__ edg, const int* __restrict__ pbase,
               const int* __restrict__ bbase, int* __restrict__ ebuf)
{
    __shared__ int lbase[NBUCK];
    __shared__ int lcur[NBUCK];
    int tid = threadIdx.x;
    for (int i = tid; i < NBUCK; i += 256) {
        lbase[i] = bbase[i] + pbase[i * NPB + blockIdx.x];
        lcur[i] = 0;
    }
    __syncthreads();
    int start = blockIdx.x * PCH;
    int stop  = min(start + PCH, E2);
    for (int i = start + tid; i < stop; i += 256) {
        int g = i >= NEDGE;
        int idx = i - (g ? NEDGE : 0);
        int src = edg[(size_t)g * E2 + idx];
        int dst = edg[(size_t)g * E2 + NEDGE + idx];
        int vd = g * N_NODES + dst;
        int b = vd >> 8;
        int p = lbase[b] + atomicAdd(&lcur[b], 1);
        ebuf[p] = ((vd & 255) << 16) | src;
    }
}

__global__ __launch_bounds__(256)
void bucket_csr(const int* __restrict__ ebuf, const int* __restrict__ bbase,
                int* __restrict__ offs, unsigned short* __restrict__ csr)
{
    __shared__ int lds_e[BCAP];
    __shared__ int cnt[256];
    __shared__ int excl[256];
    __shared__ int cur[256];
    __shared__ int wsum[4];
    int tid = threadIdx.x;
    int b = blockIdx.x;
    int lo = bbase[b], hi = bbase[b + 1];
    int sz = hi - lo;

    cnt[tid] = 0; cur[tid] = 0;
    __syncthreads();
    for (int i = tid; i < sz; i += 256) {
        int v = ebuf[lo + i];
        if (i < BCAP) lds_e[i] = v;
        atomicAdd(&cnt[v >> 16], 1);
    }
    __syncthreads();

    int lane = tid & 63, w = tid >> 6;
    int v = cnt[tid];
    int x = v;
    #pragma unroll
    for (int o = 1; o < 64; o <<= 1) {
        int y = __shfl_up(x, o);
        if (lane >= o) x += y;
    }
    if (lane == 63) wsum[w] = x;
    __syncthreads();
    int wb = 0;
    for (int i = 0; i < w; ++i) wb += wsum[i];
    int ex = wb + x - v;
    excl[tid] = ex;
    int vd = b * 256 + tid;
    if (vd < VN) offs[vd] = lo + ex;
    __syncthreads();

    for (int i = tid; i < sz; i += 256) {
        int e = (i < BCAP) ? lds_e[i] : ebuf[lo + i];
        int dl = e >> 16;
        int p = excl[dl] + atomicAdd(&cur[dl], 1);
        csr[lo + p] = (unsigned short)(e & 0xFFFF);
    }
}

// ---------------------------------------------------------------------------
// GAT aggregation: shift-free softmax sum pass + 4-deep pipelined gather.
// ---------------------------------------------------------------------------
__global__ __launch_bounds__(256)
void gat_gather(const unsigned short* __restrict__ H1b, const float* __restrict__ asf,
                const float* __restrict__ anb,
                const int* __restrict__ offs, const unsigned short* __restrict__ csr,
                const float* __restrict__ omega,
                float* __restrict__ H2, int n)
{
    int lane = threadIdx.x & 63, wid = threadIdx.x >> 6;
    int d = blockIdx.x * 4 + wid;
    if (d >= n) return;
    float ad = asf[d];
    int sub = lane >> 4, sl = lane & 15;
    const unsigned short* Hp = H1b + (sl << 3);
    float acc[8] = {};

    #pragma unroll
    for (int g = 0; g < NGRAPH; ++g) {
        int beg = offs[g * n + d], end = offs[g * n + d + 1];
        float om = omega[g];

        float ss = 0.f;
        for (int e = beg + lane; e < end; e += 64) {
            float sc = ad + anb[csr[e]];
            sc = sc > 0.f ? sc : 0.2f * sc;
            ss += __expf(sc);
        }
        #pragma unroll
        for (int o = 32; o; o >>= 1) ss += __shfl_xor(ss, o);
        float wsc = om / (ss + 1e-16f);

        int e = beg + sub;
        for (; e + 12 < end; e += 16) {
            int s0 = csr[e], s1 = csr[e + 4], s2 = csr[e + 8], s3 = csr[e + 12];
            float a0 = anb[s0], a1 = anb[s1], a2 = anb[s2], a3 = anb[s3];
            u16x8 h0 = *(const u16x8*)(Hp + (size_t)s0 * LATENT);
            u16x8 h1 = *(const u16x8*)(Hp + (size_t)s1 * LATENT);
            u16x8 h2 = *(const u16x8*)(Hp + (size_t)s2 * LATENT);
            u16x8 h3 = *(const u16x8*)(Hp + (size_t)s3 * LATENT);
            float sc0 = ad + a0; sc0 = sc0 > 0.f ? sc0 : 0.2f * sc0;
            float sc1 = ad + a1; sc1 = sc1 > 0.f ? sc1 : 0.2f * sc1;
            float sc2 = ad + a2; sc2 = sc2 > 0.f ? sc2 : 0.2f * sc2;
            float sc3 = ad + a3; sc3 = sc3 > 0.f ? sc3 : 0.2f * sc3;
            float w0 = __expf(sc0) * wsc;
            float w1 = __expf(sc1) * wsc;
            float w2 = __expf(sc2) * wsc;
            float w3 = __expf(sc3) * wsc;
            #pragma unroll
            for (int j = 0; j < 8; ++j) acc[j] += w0 * bf2f(h0[j]);
            #pragma unroll
            for (int j = 0; j < 8; ++j) acc[j] += w1 * bf2f(h1[j]);
            #pragma unroll
            for (int j = 0; j < 8; ++j) acc[j] += w2 * bf2f(h2[j]);
            #pragma unroll
            for (int j = 0; j < 8; ++j) acc[j] += w3 * bf2f(h3[j]);
        }
        for (; e < end; e += 4) {
            int s0 = csr[e];
            float a0 = anb[s0];
            u16x8 h0 = *(const u16x8*)(Hp + (size_t)s0 * LATENT);
            float sc0 = ad + a0; sc0 = sc0 > 0.f ? sc0 : 0.2f * sc0;
            float w0 = __expf(sc0) * wsc;
            #pragma unroll
            for (int j = 0; j < 8; ++j) acc[j] += w0 * bf2f(h0[j]);
        }
    }

    #pragma unroll
    for (int j = 0; j < 8; ++j) {
        acc[j] += __shfl_xor(acc[j], 32);
        acc[j] += __shfl_xor(acc[j], 16);
    }
    if (sub == 0) {
        float* dp = H2 + (size_t)d * LATENT + sl * 8;
        *(float4*)dp       = make_float4(acc[0], acc[1], acc[2], acc[3]);
        *(float4*)(dp + 4) = make_float4(acc[4], acc[5], acc[6], acc[7]);
    }
}

// ---------------------------------------------------------------------------
__global__ __launch_bounds__(256)
void predict(const int* __restrict__ uid, const int* __restrict__ iid,
             const float* __restrict__ U, const float* __restrict__ B,
             const float* __restrict__ bu, const float* __restrict__ bb,
             const float* __restrict__ bx, float* __restrict__ out, int batch)
{
    int lane = threadIdx.x & 63, wid = threadIdx.x >> 6;
    int b = blockIdx.x * 4 + wid;
    if (b >= batch) return;
    int u = uid[b], it = iid[b];
    float p = U[(size_t)u * FINALD + lane] * B[(size_t)it * FINALD + lane];
    #pragma unroll
    for (int o = 32; o; o >>= 1) p += __shfl_xor(p, o);
    if (lane == 0) {
        float raw = p + bu[u] + bb[it] + bx[0];
        out[b] = 4.f * (1.f / (1.f + __expf(-raw))) + 1.f;
    }
}

// ---------------------------------------------------------------------------
extern "C" void kernel_launch(void* const* d_in, const int* in_sizes, int n_in,
                              void* d_out, int out_size, void* d_ws, size_t ws_size,
                              hipStream_t stream)
{
    const int N = N_NODES;

    float* ws = (float*)d_ws;
    float* bufA  = ws;                        // H1b (bf16) then H3 (f32): 6.4e6 f
    float* H2    = ws + 6400000;              // 6.4e6 f  (ebuf overlays this)
    float* U_all = ws + 12800000;             // 3.2e6 f
    float* B_all = ws + 16000000;             // 3.2e6 f
    float* asf   = ws + 19200000;             // 5e4
    float* anb   = asf + N;                   // 5e4
    int*   offs  = (int*)(anb + N);           // VN+1
    int*   pcnt  = offs + VN + 1;             // NBUCK*NPB
    int*   pbase = pcnt + NBUCK * NPB;        // NBUCK*NPB
    int*   bbase = pbase + NBUCK * NPB;       // NBUCK+1
    unsigned short* csr = (unsigned short*)(bbase + NBUCK + 1);  // E2 ushorts
    unsigned short* wsp = (unsigned short*)(((uintptr_t)(csr + E2) + 15) & ~(uintptr_t)15);
    int*   ebuf  = (int*)H2;                  // E2 ints, dead before gat writes H2

    unsigned short* H1b = (unsigned short*)bufA;
    float* H3 = bufA;

    dim3 gL(782, 2);
    dim3 gF(782, 1);

    prep_weights<<<(2 * WSP_ELEMS + 255) / 256, 256, 0, stream>>>(
        (const float*)d_in[6],  (const float*)d_in[14], (const float*)d_in[15], (const float*)d_in[20],
        (const float*)d_in[10], (const float*)d_in[17], (const float*)d_in[18], (const float*)d_in[21],
        wsp);

    for (int side = 0; side < 2; ++side) {
        const float* S   = (const float*)d_in[side == 0 ? 2 : 3];
        const int*   edg = (const int*)  d_in[side == 0 ? 4 : 5];
        const float* avs = (const float*)d_in[side == 0 ? 7 : 11];
        const float* avn = (const float*)d_in[side == 0 ? 8 : 12];
        const float* om  = (const float*)d_in[side == 0 ? 9 : 13];
        const float* b2  = (const float*)d_in[side == 0 ? 16 : 19];
        const float* H4  = (const float*)d_in[side == 0 ? 22 : 23];
        float* OUT = side == 0 ? U_all : B_all;

        unsigned short* wb = wsp + (size_t)side * WSP_SIDE;
        const unsigned short* W1h  = wb;
        const unsigned short* W2ah = wb + 32768;
        const unsigned short* W2sh = wb + 49152;
        const unsigned short* W3h  = wb + 81920;

        // H1b = bf16( S @ W1 )
        gemm_mfma<<<gL, 256, 0, stream>>>(
            S, W1h, IN_DIM, nullptr, nullptr, 0,
            nullptr, nullptr, H1b, N, LATENT, 0, 1);

        rowdots<<<N / 4, 256, 0, stream>>>(H1b, avs, avn, asf, anb, N);

        // atomic-free bucketed CSR build (both graphs)
        part_count<<<NPB, 256, 0, stream>>>(edg, pcnt);
        part_scan<<<1, 1024, 0, stream>>>(pcnt, pbase, bbase, offs);
        part_fill<<<NPB, 256, 0, stream>>>(edg, pbase, bbase, ebuf);
        bucket_csr<<<NBUCK, 256, 0, stream>>>(ebuf, bbase, offs, csr);

        // merged 2-pass aggregation (shift-free softmax + 4-deep gather)
        gat_gather<<<N / 4, 256, 0, stream>>>(
            H1b, asf, anb, offs, csr, om, H2, N);

        // H3 = elu(H2@W2a + S@W2s + b2)
        gemm_mfma<<<gL, 256, 0, stream>>>(
            H2, W2ah, LATENT, S, W2sh, IN_DIM,
            b2, nullptr, H3, N, LATENT, 1, 0);

        // OUT = elu(H3@W3) + H4
        gemm_mfma<<<gF, 256, 0, stream>>>(
            H3, W3h, LATENT, nullptr, nullptr, 0,
            nullptr, H4, OUT, N, FINALD, 1, 0);
    }

    predict<<<BATCHSZ / 4, 256, 0, stream>>>(
        (const int*)d_in[0], (const int*)d_in[1], U_all, B_all,
        (const float*)d_in[24], (const float*)d_in[25], (const float*)d_in[26],
        (float*)d_out, BATCHSZ);
}

// Round 9
// 400.326 us; speedup vs baseline: 2.4650x; 1.1279x over previous
//
#include <hip/hip_runtime.h>
#include <math.h>

#define N_NODES 50000
#define IN_DIM  256
#define LATENT  128
#define FINALD  64
#define NGRAPH  2
#define NEDGE   1000000
#define BATCHSZ 16384

#define VN4     (4 * N_NODES)          // unified virtual dst ids: side*2N + g*N + dst
#define NBU     ((VN4 + 255) >> 8)     // 782 buckets of 256 vds
#define E2      (2 * NEDGE)
#define E4      (4 * NEDGE)
#define NPB     256                    // partition blocks
#define PCH     ((E4 + NPB - 1) / NPB) // 15625 edges per partition block
#define BCAP    8192                   // bucket_csr LDS cache entries

// pre-cvt bf16 weights: per side W1(256x128) W2a(128x128) W2s(256x128) W3(128x64)
#define WSP_SIDE   90112
#define WSP_ELEMS  90112

typedef __attribute__((ext_vector_type(8))) short bf16x8;
typedef __attribute__((ext_vector_type(4))) float f32x4;
typedef __attribute__((ext_vector_type(8))) unsigned short u16x8;
typedef __attribute__((ext_vector_type(4))) unsigned short u16x4;

__device__ inline unsigned short f2bf(float x) {
    unsigned int u = __float_as_uint(x);
    u = (u + 0x7fffu + ((u >> 16) & 1u)) >> 16;
    return (unsigned short)u;
}
__device__ inline float bf2f(unsigned short h) {
    return __uint_as_float(((unsigned int)h) << 16);
}

// ---------------------------------------------------------------------------
// Weight prep: f32 [K][N] -> bf16, transposed k-major [N][K]. Both sides.
// ---------------------------------------------------------------------------
__global__ __launch_bounds__(256)
void prep_weights(const float* __restrict__ W1u, const float* __restrict__ Wu2,
                  const float* __restrict__ Wus2, const float* __restrict__ Wu3,
                  const float* __restrict__ W1b, const float* __restrict__ Wb2,
                  const float* __restrict__ Wbs2, const float* __restrict__ Wb3,
                  unsigned short* __restrict__ dst)
{
    int e = blockIdx.x * 256 + threadIdx.x;
    if (e >= 2 * WSP_ELEMS) return;
    int side = e >= WSP_ELEMS;
    int r = e - (side ? WSP_ELEMS : 0);
    const float* src; int K, N, hoff;
    if (r < 32768)      { src = side ? W1b  : W1u;  K = 256; N = 128; hoff = 0;     }
    else if (r < 49152) { src = side ? Wb2  : Wu2;  K = 128; N = 128; hoff = 32768; r -= 32768; }
    else if (r < 81920) { src = side ? Wbs2 : Wus2; K = 256; N = 128; hoff = 49152; r -= 49152; }
    else                { src = side ? Wb3  : Wu3;  K = 128; N = 64;  hoff = 81920; r -= 81920; }
    int n = (K == 256) ? (r >> 8) : (r >> 7);
    int k = (K == 256) ? (r & 255) : (r & 127);
    dst[(size_t)side * WSP_SIDE + hoff + n * K + k] = f2bf(src[k * N + n]);
}

// ---------------------------------------------------------------------------
// Pure-bf16 MFMA GEMM (1 MFMA/fragment). 64x64 tile, BK=64.
// ---------------------------------------------------------------------------
#define GBM 64
#define GBK 64

__device__ inline int swz(int r, int k) {
    return r * GBK + ((((k >> 3) ^ (r & 7)) << 3) | (k & 7));
}

__global__ __launch_bounds__(256)
void gemm_mfma(const float* __restrict__ A1, const unsigned short* __restrict__ B1h, int K1,
               const float* __restrict__ A2, const unsigned short* __restrict__ B2h, int K2,
               const float* __restrict__ bias, const float* __restrict__ addm,
               void* __restrict__ Cout, int M, int Ncols, int act, int out_bf16)
{
    __shared__ unsigned short AhS[GBM * GBK];
    __shared__ unsigned short BhS[GBM * GBK];

    const int tid = threadIdx.x;
    const int rowBase = blockIdx.x * GBM;
    const int colBase = blockIdx.y * GBM;
    const int wave = tid >> 6, lane = tid & 63;
    const int wr = wave >> 1, wc = wave & 1;
    const int sl = lane & 15, lg = lane >> 4;

    f32x4 acc[2][2] = {};

    const float* Ap = A1;
    const unsigned short* Bph = B1h;
    int K = K1;

    for (int pass = 0; pass < 2; ++pass) {
        if (pass == 1) { if (!A2) break; Ap = A2; Bph = B2h; K = K2; }
        for (int k0 = 0; k0 < K; k0 += GBK) {
            __syncthreads();
            #pragma unroll
            for (int p = 0; p < 4; ++p) {
                int q = p * 256 + tid;
                int row = q >> 4;
                int kq = (q & 15) << 2;
                int grow = rowBase + row;
                float4 v = make_float4(0.f, 0.f, 0.f, 0.f);
                if (grow < M) v = *(const float4*)(Ap + (size_t)grow * K + k0 + kq);
                u16x4 hv = {f2bf(v.x), f2bf(v.y), f2bf(v.z), f2bf(v.w)};
                *(u16x4*)&AhS[swz(row, kq)] = hv;
            }
            {
                int n = tid & 63;
                int kq = (tid >> 6) << 4;
                const unsigned short* bp = Bph + (size_t)(colBase + n) * K + k0 + kq;
                u16x8 h0 = *(const u16x8*)bp;
                u16x8 h1 = *(const u16x8*)(bp + 8);
                *(u16x8*)&BhS[swz(n, kq)]     = h0;
                *(u16x8*)&BhS[swz(n, kq + 8)] = h1;
            }
            __syncthreads();
            #pragma unroll
            for (int ks = 0; ks < 2; ++ks) {
                int kof = ks * 32 + lg * 8;
                bf16x8 ah[2], bh[2];
                #pragma unroll
                for (int f = 0; f < 2; ++f) {
                    ah[f] = *(const bf16x8*)&AhS[swz(wr * 32 + f * 16 + sl, kof)];
                    bh[f] = *(const bf16x8*)&BhS[swz(wc * 32 + f * 16 + sl, kof)];
                }
                #pragma unroll
                for (int fm = 0; fm < 2; ++fm)
                    #pragma unroll
                    for (int fn = 0; fn < 2; ++fn)
                        acc[fm][fn] = __builtin_amdgcn_mfma_f32_16x16x32_bf16(ah[fm], bh[fn], acc[fm][fn], 0, 0, 0);
            }
        }
    }

    #pragma unroll
    for (int fm = 0; fm < 2; ++fm)
        #pragma unroll
        for (int r = 0; r < 4; ++r) {
            int row = rowBase + wr * 32 + fm * 16 + lg * 4 + r;
            if (row >= M) continue;
            #pragma unroll
            for (int fn = 0; fn < 2; ++fn) {
                int col = colBase + wc * 32 + fn * 16 + sl;
                float v = acc[fm][fn][r];
                if (bias) v += bias[col];
                if (act) v = v > 0.f ? v : (__expf(v) - 1.f);
                if (addm) v += addm[(size_t)row * Ncols + col];
                if (out_bf16)
                    ((unsigned short*)Cout)[(size_t)row * Ncols + col] = f2bf(v);
                else
                    ((float*)Cout)[(size_t)row * Ncols + col] = v;
            }
        }
}

// ---------------------------------------------------------------------------
// alpha_self / alpha_nb from bf16 H1. Wave per row.
// ---------------------------------------------------------------------------
__global__ __launch_bounds__(256)
void rowdots(const unsigned short* __restrict__ H1b, const float* __restrict__ a1,
             const float* __restrict__ a2,
             float* __restrict__ o1, float* __restrict__ o2, int n)
{
    int lane = threadIdx.x & 63, wid = threadIdx.x >> 6;
    int row = blockIdx.x * 4 + wid;
    if (row >= n) return;
    unsigned int hv = *(const unsigned int*)(H1b + (size_t)row * LATENT + lane * 2);
    float h0 = bf2f((unsigned short)(hv & 0xffffu));
    float h1 = bf2f((unsigned short)(hv >> 16));
    float2 x = *(const float2*)(a1 + lane * 2);
    float2 y = *(const float2*)(a2 + lane * 2);
    float d1 = h0 * x.x + h1 * x.y;
    float d2 = h0 * y.x + h1 * y.y;
    #pragma unroll
    for (int o = 32; o; o >>= 1) {
        d1 += __shfl_xor(d1, o);
        d2 += __shfl_xor(d2, o);
    }
    if (lane == 0) { o1[row] = d1; o2[row] = d2; }
}

// ---------------------------------------------------------------------------
// Unified atomic-free bucketed counting sort over ALL 4 graphs (2 sides x 2).
// vd = side*2N + g*N + dst in [0, VN4). 782 buckets of 256 vds.
// ---------------------------------------------------------------------------
__device__ inline void edge_decomp(int i, int& side, int& g, int& idx) {
    if (i < NEDGE)          { side = 0; g = 0; idx = i; }
    else if (i < 2 * NEDGE) { side = 0; g = 1; idx = i - NEDGE; }
    else if (i < 3 * NEDGE) { side = 1; g = 0; idx = i - 2 * NEDGE; }
    else                    { side = 1; g = 1; idx = i - 3 * NEDGE; }
}

__global__ __launch_bounds__(256)
void part_count(const int* __restrict__ eU, const int* __restrict__ eB,
                int* __restrict__ pcnt)
{
    __shared__ int h[NBU];
    int tid = threadIdx.x;
    for (int i = tid; i < NBU; i += 256) h[i] = 0;
    __syncthreads();
    int start = blockIdx.x * PCH;
    int stop  = min(start + PCH, E4);
    for (int i = start + tid; i < stop; i += 256) {
        int side, g, idx;
        edge_decomp(i, side, g, idx);
        const int* base = side ? eB : eU;
        int dst = base[(size_t)(2 * g + 1) * NEDGE + idx];
        int vd = side * (2 * N_NODES) + g * N_NODES + dst;
        atomicAdd(&h[vd >> 8], 1);
    }
    __syncthreads();
    for (int i = tid; i < NBU; i += 256)
        pcnt[i * NPB + blockIdx.x] = h[i];
}

__global__ __launch_bounds__(1024)
void part_scan(const int* __restrict__ pcnt, int* __restrict__ pbase,
               int* __restrict__ bbase, int* __restrict__ offs)
{
    __shared__ int btot[NBU];
    __shared__ int wsum2[16];
    int tid = threadIdx.x;
    int lane = tid & 63, w = tid >> 6;           // 16 waves
    for (int b = w; b < NBU; b += 16) {
        int4 v = *(const int4*)&pcnt[b * NPB + lane * 4];
        int s = v.x + v.y + v.z + v.w;
        int x = s;
        #pragma unroll
        for (int o = 1; o < 64; o <<= 1) {
            int y = __shfl_up(x, o);
            if (lane >= o) x += y;
        }
        int ex = x - s;
        int* pb = &pbase[b * NPB + lane * 4];
        pb[0] = ex;
        pb[1] = ex + v.x;
        pb[2] = ex + v.x + v.y;
        pb[3] = ex + v.x + v.y + v.z;
        if (lane == 63) btot[b] = x;
    }
    __syncthreads();
    // parallel exclusive scan of btot[0..NBU)
    int v = (tid < NBU) ? btot[tid] : 0;
    int x = v;
    #pragma unroll
    for (int o = 1; o < 64; o <<= 1) {
        int y = __shfl_up(x, o);
        if (lane >= o) x += y;
    }
    if (lane == 63) wsum2[w] = x;
    __syncthreads();
    int wb = 0;
    for (int i = 0; i < w; ++i) wb += wsum2[i];
    int ex = wb + x - v;
    if (tid < NBU) bbase[tid] = ex;
    if (tid == NBU - 1) bbase[NBU] = ex + v;
    if (tid == 0) offs[VN4] = E4;
}

__global__ __launch_bounds__(256)
void part_fill(const int* __restrict__ eU, const int* __restrict__ eB,
               const int* __restrict__ pbase, const int* __restrict__ bbase,
               int* __restrict__ ebuf)
{
    __shared__ int lbase[NBU];
    __shared__ int lcur[NBU];
    int tid = threadIdx.x;
    for (int i = tid; i < NBU; i += 256) {
        lbase[i] = bbase[i] + pbase[i * NPB + blockIdx.x];
        lcur[i] = 0;
    }
    __syncthreads();
    int start = blockIdx.x * PCH;
    int stop  = min(start + PCH, E4);
    for (int i = start + tid; i < stop; i += 256) {
        int side, g, idx;
        edge_decomp(i, side, g, idx);
        const int* base = side ? eB : eU;
        int src = base[(size_t)(2 * g) * NEDGE + idx];
        int dst = base[(size_t)(2 * g + 1) * NEDGE + idx];
        int vd = side * (2 * N_NODES) + g * N_NODES + dst;
        int b = vd >> 8;
        int p = lbase[b] + atomicAdd(&lcur[b], 1);
        ebuf[p] = ((vd & 255) << 16) | src;
    }
}

__global__ __launch_bounds__(256)
void bucket_csr(const int* __restrict__ ebuf, const int* __restrict__ bbase,
                int* __restrict__ offs, unsigned short* __restrict__ csr)
{
    __shared__ int lds_e[BCAP];
    __shared__ int cnt[256];
    __shared__ int excl[256];
    __shared__ int cur[256];
    __shared__ int wsum[4];
    int tid = threadIdx.x;
    int b = blockIdx.x;
    int lo = bbase[b], hi = bbase[b + 1];
    int sz = hi - lo;

    cnt[tid] = 0; cur[tid] = 0;
    __syncthreads();
    for (int i = tid; i < sz; i += 256) {
        int v = ebuf[lo + i];
        if (i < BCAP) lds_e[i] = v;
        atomicAdd(&cnt[v >> 16], 1);
    }
    __syncthreads();

    int lane = tid & 63, w = tid >> 6;
    int v = cnt[tid];
    int x = v;
    #pragma unroll
    for (int o = 1; o < 64; o <<= 1) {
        int y = __shfl_up(x, o);
        if (lane >= o) x += y;
    }
    if (lane == 63) wsum[w] = x;
    __syncthreads();
    int wb = 0;
    for (int i = 0; i < w; ++i) wb += wsum[i];
    int ex = wb + x - v;
    excl[tid] = ex;
    int vd = b * 256 + tid;
    if (vd < VN4) offs[vd] = lo + ex;
    __syncthreads();

    for (int i = tid; i < sz; i += 256) {
        int e = (i < BCAP) ? lds_e[i] : ebuf[lo + i];
        int dl = e >> 16;
        int p = excl[dl] + atomicAdd(&cur[dl], 1);
        csr[lo + p] = (unsigned short)(e & 0xFFFF);
    }
}

// ---------------------------------------------------------------------------
// Single-pass GAT aggregation with deferred normalization:
// unnorm[j] = sum exp(sc)*h[j], ss = sum exp(sc); fin += (om/ss)*unnorm.
// Wave per dst, 16-lane groups, 2-deep pipeline.
// ---------------------------------------------------------------------------
__global__ __launch_bounds__(256)
void gat_gather(const unsigned short* __restrict__ H1b, const float* __restrict__ asf,
                const float* __restrict__ anb,
                const int* __restrict__ offs, const unsigned short* __restrict__ csr,
                const float* __restrict__ omega,
                float* __restrict__ H2, int n)
{
    int lane = threadIdx.x & 63, wid = threadIdx.x >> 6;
    int d = blockIdx.x * 4 + wid;
    if (d >= n) return;
    float ad = asf[d];
    int sub = lane >> 4, sl = lane & 15;
    const unsigned short* Hp = H1b + (sl << 3);
    float fin[8] = {};

    #pragma unroll
    for (int g = 0; g < NGRAPH; ++g) {
        int beg = offs[g * n + d], end = offs[g * n + d + 1];
        float om = omega[g];
        float un[8] = {};
        float ss = 0.f;

        int e = beg + sub;
        for (; e + 4 < end; e += 8) {
            int s0 = csr[e], s1 = csr[e + 4];
            float a0 = anb[s0], a1 = anb[s1];
            u16x8 h0 = *(const u16x8*)(Hp + (size_t)s0 * LATENT);
            u16x8 h1 = *(const u16x8*)(Hp + (size_t)s1 * LATENT);
            float sc0 = ad + a0; sc0 = sc0 > 0.f ? sc0 : 0.2f * sc0;
            float sc1 = ad + a1; sc1 = sc1 > 0.f ? sc1 : 0.2f * sc1;
            float w0 = __expf(sc0), w1 = __expf(sc1);
            ss += w0 + w1;
            #pragma unroll
            for (int j = 0; j < 8; ++j) un[j] += w0 * bf2f(h0[j]);
            #pragma unroll
            for (int j = 0; j < 8; ++j) un[j] += w1 * bf2f(h1[j]);
        }
        if (e < end) {
            int s0 = csr[e];
            float a0 = anb[s0];
            u16x8 h0 = *(const u16x8*)(Hp + (size_t)s0 * LATENT);
            float sc0 = ad + a0; sc0 = sc0 > 0.f ? sc0 : 0.2f * sc0;
            float w0 = __expf(sc0);
            ss += w0;
            #pragma unroll
            for (int j = 0; j < 8; ++j) un[j] += w0 * bf2f(h0[j]);
        }

        // cross-group sum of exp (groups hold disjoint edge subsets)
        ss += __shfl_xor(ss, 32);
        ss += __shfl_xor(ss, 16);
        float wsc = om / (ss + 1e-16f);
        #pragma unroll
        for (int j = 0; j < 8; ++j) fin[j] += wsc * un[j];
    }

    #pragma unroll
    for (int j = 0; j < 8; ++j) {
        fin[j] += __shfl_xor(fin[j], 32);
        fin[j] += __shfl_xor(fin[j], 16);
    }
    if (sub == 0) {
        float* dp = H2 + (size_t)d * LATENT + sl * 8;
        *(float4*)dp       = make_float4(fin[0], fin[1], fin[2], fin[3]);
        *(float4*)(dp + 4) = make_float4(fin[4], fin[5], fin[6], fin[7]);
    }
}

// ---------------------------------------------------------------------------
__global__ __launch_bounds__(256)
void predict(const int* __restrict__ uid, const int* __restrict__ iid,
             const float* __restrict__ U, const float* __restrict__ B,
             const float* __restrict__ bu, const float* __restrict__ bb,
             const float* __restrict__ bx, float* __restrict__ out, int batch)
{
    int lane = threadIdx.x & 63, wid = threadIdx.x >> 6;
    int b = blockIdx.x * 4 + wid;
    if (b >= batch) return;
    int u = uid[b], it = iid[b];
    float p = U[(size_t)u * FINALD + lane] * B[(size_t)it * FINALD + lane];
    #pragma unroll
    for (int o = 32; o; o >>= 1) p += __shfl_xor(p, o);
    if (lane == 0) {
        float raw = p + bu[u] + bb[it] + bx[0];
        out[b] = 4.f * (1.f / (1.f + __expf(-raw))) + 1.f;
    }
}

// ---------------------------------------------------------------------------
extern "C" void kernel_launch(void* const* d_in, const int* in_sizes, int n_in,
                              void* d_out, int out_size, void* d_ws, size_t ws_size,
                              hipStream_t stream)
{
    const int N = N_NODES;

    float* ws = (float*)d_ws;
    float* bufA  = ws;                        // H1b (bf16) / H3 (f32): 6.4e6 f
    float* H2    = ws + 6400000;              // 6.4e6 f; ebuf (4e6 ints) overlays
    float* U_all = ws + 12800000;             // 3.2e6 f; pcnt/pbase overlay
    float* B_all = ws + 16000000;             // 3.2e6 f
    float* asf   = ws + 19200000;             // 5e4
    float* anb   = asf + N;                   // 5e4
    int*   offs  = (int*)(anb + N);           // VN4+1
    int*   bbase = offs + VN4 + 1;            // NBU+1
    unsigned short* csr = (unsigned short*)(bbase + NBU + 1);  // E4 ushorts
    unsigned short* wsp = (unsigned short*)(((uintptr_t)(csr + E4) + 15) & ~(uintptr_t)15);
    int*   ebuf  = (int*)H2;                  // E4 ints, dead before gathers
    int*   pcnt  = (int*)U_all;               // NBU*NPB ints
    int*   pbase = pcnt + NBU * NPB;          // NBU*NPB ints (total 400384 <= 3.2e6)

    unsigned short* H1b = (unsigned short*)bufA;
    float* H3 = bufA;

    dim3 gL(782, 2);
    dim3 gF(782, 1);

    prep_weights<<<(2 * WSP_ELEMS + 255) / 256, 256, 0, stream>>>(
        (const float*)d_in[6],  (const float*)d_in[14], (const float*)d_in[15], (const float*)d_in[20],
        (const float*)d_in[10], (const float*)d_in[17], (const float*)d_in[18], (const float*)d_in[21],
        wsp);

    // unified CSR build over all 4 graphs
    const int* eU = (const int*)d_in[4];
    const int* eB = (const int*)d_in[5];
    part_count<<<NPB, 256, 0, stream>>>(eU, eB, pcnt);
    part_scan<<<1, 1024, 0, stream>>>(pcnt, pbase, bbase, offs);
    part_fill<<<NPB, 256, 0, stream>>>(eU, eB, pbase, bbase, ebuf);
    bucket_csr<<<NBU, 256, 0, stream>>>(ebuf, bbase, offs, csr);

    for (int side = 0; side < 2; ++side) {
        const float* S   = (const float*)d_in[side == 0 ? 2 : 3];
        const float* avs = (const float*)d_in[side == 0 ? 7 : 11];
        const float* avn = (const float*)d_in[side == 0 ? 8 : 12];
        const float* om  = (const float*)d_in[side == 0 ? 9 : 13];
        const float* b2  = (const float*)d_in[side == 0 ? 16 : 19];
        const float* H4  = (const float*)d_in[side == 0 ? 22 : 23];
        float* OUT = side == 0 ? U_all : B_all;

        unsigned short* wb = wsp + (size_t)side * WSP_SIDE;
        const unsigned short* W1h  = wb;
        const unsigned short* W2ah = wb + 32768;
        const unsigned short* W2sh = wb + 49152;
        const unsigned short* W3h  = wb + 81920;

        // H1b = bf16( S @ W1 )
        gemm_mfma<<<gL, 256, 0, stream>>>(
            S, W1h, IN_DIM, nullptr, nullptr, 0,
            nullptr, nullptr, H1b, N, LATENT, 0, 1);

        rowdots<<<N / 4, 256, 0, stream>>>(H1b, avs, avn, asf, anb, N);

        // single-pass aggregation (deferred normalization)
        gat_gather<<<N / 4, 256, 0, stream>>>(
            H1b, asf, anb, offs + side * 2 * N, csr, om, H2, N);

        // H3 = elu(H2@W2a + S@W2s + b2)
        gemm_mfma<<<gL, 256, 0, stream>>>(
            H2, W2ah, LATENT, S, W2sh, IN_DIM,
            b2, nullptr, H3, N, LATENT, 1, 0);

        // OUT = elu(H3@W3) + H4
        gemm_mfma<<<gF, 256, 0, stream>>>(
            H3, W3h, LATENT, nullptr, nullptr, 0,
            nullptr, H4, OUT, N, FINALD, 1, 0);
    }

    predict<<<BATCHSZ / 4, 256, 0, stream>>>(
        (const int*)d_in[0], (const int*)d_in[1], U_all, B_all,
        (const float*)d_in[24], (const float*)d_in[25], (const float*)d_in[26],
        (float*)d_out, BATCHSZ);
}

// Round 10
// 393.864 us; speedup vs baseline: 2.5055x; 1.0164x over previous
//
#include <hip/hip_runtime.h>
#include <math.h>

#define N_NODES 50000
#define IN_DIM  256
#define LATENT  128
#define FINALD  64
#define NGRAPH  2
#define NEDGE   1000000
#define BATCHSZ 16384

#define VN4     (4 * N_NODES)          // unified virtual dst ids: side*2N + g*N + dst
#define NBU     ((VN4 + 255) >> 8)     // 782 buckets of 256 vds
#define E4      (4 * NEDGE)
#define NPB     256                    // partition blocks
#define PCH     ((E4 + NPB - 1) / NPB) // 15625 edges per partition block
#define BCAP    8192                   // bucket_csr LDS cache entries

// bf16 weights per side: W1[128][256] W2a[128][128] W2s[128][256] W3pad[128][128] (k-major [N][K])
#define WSP_SIDE   98304
#define HSTRIDE    (N_NODES * LATENT)  // per-side ushort stride for H1b/H2b/H3b

typedef __attribute__((ext_vector_type(8))) short bf16x8;
typedef __attribute__((ext_vector_type(4))) float f32x4;
typedef __attribute__((ext_vector_type(8))) unsigned short u16x8;
typedef __attribute__((ext_vector_type(4))) unsigned short u16x4;

__device__ inline unsigned short f2bf(float x) {
    unsigned int u = __float_as_uint(x);
    u = (u + 0x7fffu + ((u >> 16) & 1u)) >> 16;
    return (unsigned short)u;
}
__device__ inline float bf2f(unsigned short h) {
    return __uint_as_float(((unsigned int)h) << 16);
}

// ---------------------------------------------------------------------------
// Weight prep: f32 [K][N] -> bf16 k-major [N][K]; W3 zero-padded to N=128.
// ---------------------------------------------------------------------------
__global__ __launch_bounds__(256)
void prep_weights(const float* __restrict__ W1u, const float* __restrict__ Wu2,
                  const float* __restrict__ Wus2, const float* __restrict__ Wu3,
                  const float* __restrict__ W1b, const float* __restrict__ Wb2,
                  const float* __restrict__ Wbs2, const float* __restrict__ Wb3,
                  unsigned short* __restrict__ dst)
{
    int e = blockIdx.x * 256 + threadIdx.x;
    if (e >= 2 * WSP_SIDE) return;
    int side = e >= WSP_SIDE;
    int r = e - (side ? WSP_SIDE : 0);
    const float* src; int K, hoff; int w3 = 0;
    if (r < 32768)      { src = side ? W1b  : W1u;  K = 256; hoff = 0;     }
    else if (r < 49152) { src = side ? Wb2  : Wu2;  K = 128; hoff = 32768; r -= 32768; }
    else if (r < 81920) { src = side ? Wbs2 : Wus2; K = 256; hoff = 49152; r -= 49152; }
    else                { src = side ? Wb3  : Wu3;  K = 128; hoff = 81920; r -= 81920; w3 = 1; }
    int n = (K == 256) ? (r >> 8) : (r >> 7);
    int k = (K == 256) ? (r & 255) : (r & 127);
    float x;
    if (w3) x = (n < 64) ? src[k * 64 + n] : 0.f;
    else    x = src[k * 128 + n];
    dst[(size_t)side * WSP_SIDE + hoff + n * K + k] = f2bf(x);
}

// ---------------------------------------------------------------------------
// bf16 MFMA GEMM, 128x128 tile, BK=64, 256 thr (4 waves 2x2, 64x64/wave,
// 4x4 frags of 16x16x32). Both sides batched via blockIdx.z.
// A per pass: f32 or bf16 row-major [M][K]. B: wsp slot [128][K] k-major.
// ---------------------------------------------------------------------------
#define BM 128
#define BK 64

__device__ inline int swz(int r, int k) {
    return r * BK + ((((k >> 3) ^ (r & 7)) << 3) | (k & 7));
}

__global__ __launch_bounds__(256)
void gemm_big(const void* __restrict__ A1u, const void* __restrict__ A1b, int a1f32, int K1,
              const void* __restrict__ A2u, const void* __restrict__ A2b, int a2f32, int K2,
              const unsigned short* __restrict__ wspb, int b1off, int b2off,
              const float* __restrict__ bias_u, const float* __restrict__ bias_b,
              const float* __restrict__ addm_u, const float* __restrict__ addm_b,
              void* __restrict__ Cu, void* __restrict__ Cb,
              int M, int Ncols, int act, int out_bf16)
{
    __shared__ unsigned short AhS[BM * BK];
    __shared__ unsigned short BhS[BM * BK];

    const int side = blockIdx.z;
    const unsigned short* Bside = wspb + (size_t)side * WSP_SIDE;
    const float* bias = side ? bias_b : bias_u;
    const float* addm = side ? addm_b : addm_u;
    void* Cout = side ? Cb : Cu;

    const int tid = threadIdx.x;
    const int rowBase = blockIdx.x * BM;
    const int wave = tid >> 6, lane = tid & 63;
    const int wr = wave >> 1, wc = wave & 1;
    const int sl = lane & 15, lg = lane >> 4;

    f32x4 acc[4][4] = {};

    const void* Ap = side ? A1b : A1u;
    const unsigned short* Bp = Bside + b1off;
    int K = K1, af32 = a1f32;

    for (int pass = 0; pass < 2; ++pass) {
        if (pass == 1) {
            if (!A2u) break;
            Ap = side ? A2b : A2u; Bp = Bside + b2off; K = K2; af32 = a2f32;
        }
        for (int k0 = 0; k0 < K; k0 += BK) {
            __syncthreads();
            // stage A: 128 rows x 64 k (u16x8 per thread x4)
            #pragma unroll
            for (int p = 0; p < 4; ++p) {
                int q = p * 256 + tid;
                int row = q >> 3;
                int kq = (q & 7) << 3;
                int grow = rowBase + row;
                u16x8 hv = {0, 0, 0, 0, 0, 0, 0, 0};
                if (grow < M) {
                    if (af32) {
                        const float* a = (const float*)Ap + (size_t)grow * K + k0 + kq;
                        float4 v0 = *(const float4*)a;
                        float4 v1 = *(const float4*)(a + 4);
                        hv[0] = f2bf(v0.x); hv[1] = f2bf(v0.y); hv[2] = f2bf(v0.z); hv[3] = f2bf(v0.w);
                        hv[4] = f2bf(v1.x); hv[5] = f2bf(v1.y); hv[6] = f2bf(v1.z); hv[7] = f2bf(v1.w);
                    } else {
                        hv = *(const u16x8*)((const unsigned short*)Ap + (size_t)grow * K + k0 + kq);
                    }
                }
                *(u16x8*)&AhS[swz(row, kq)] = hv;
            }
            // stage B: 128 n-rows x 64 k (pure bf16 vector copies)
            #pragma unroll
            for (int p = 0; p < 4; ++p) {
                int q = p * 256 + tid;
                int n = q >> 3;
                int kq = (q & 7) << 3;
                u16x8 hv = *(const u16x8*)(Bp + (size_t)n * K + k0 + kq);
                *(u16x8*)&BhS[swz(n, kq)] = hv;
            }
            __syncthreads();
            #pragma unroll
            for (int ks = 0; ks < 2; ++ks) {
                int kof = ks * 32 + lg * 8;
                bf16x8 af[4], bf[4];
                #pragma unroll
                for (int f = 0; f < 4; ++f) {
                    af[f] = *(const bf16x8*)&AhS[swz(wr * 64 + f * 16 + sl, kof)];
                    bf[f] = *(const bf16x8*)&BhS[swz(wc * 64 + f * 16 + sl, kof)];
                }
                #pragma unroll
                for (int fm = 0; fm < 4; ++fm)
                    #pragma unroll
                    for (int fn = 0; fn < 4; ++fn)
                        acc[fm][fn] = __builtin_amdgcn_mfma_f32_16x16x32_bf16(af[fm], bf[fn], acc[fm][fn], 0, 0, 0);
            }
        }
    }

    #pragma unroll
    for (int fm = 0; fm < 4; ++fm)
        #pragma unroll
        for (int r = 0; r < 4; ++r) {
            int row = rowBase + wr * 64 + fm * 16 + lg * 4 + r;
            if (row >= M) continue;
            #pragma unroll
            for (int fn = 0; fn < 4; ++fn) {
                int col = wc * 64 + fn * 16 + sl;
                if (col >= Ncols) continue;
                float v = acc[fm][fn][r];
                if (bias) v += bias[col];
                if (act) v = v > 0.f ? v : (__expf(v) - 1.f);
                if (addm) v += addm[(size_t)row * Ncols + col];
                if (out_bf16)
                    ((unsigned short*)Cout)[(size_t)row * Ncols + col] = f2bf(v);
                else
                    ((float*)Cout)[(size_t)row * Ncols + col] = v;
            }
        }
}

// ---------------------------------------------------------------------------
// alpha_self / alpha_nb from bf16 H1, both sides (blockIdx.y). Wave per row.
// ---------------------------------------------------------------------------
__global__ __launch_bounds__(256)
void rowdots(const unsigned short* __restrict__ H1b,
             const float* __restrict__ a1u, const float* __restrict__ a2u,
             const float* __restrict__ a1b, const float* __restrict__ a2b,
             float* __restrict__ o1, float* __restrict__ o2, int n)
{
    int side = blockIdx.y;
    int lane = threadIdx.x & 63, wid = threadIdx.x >> 6;
    int row = blockIdx.x * 4 + wid;
    if (row >= n) return;
    const unsigned short* Hb = H1b + (size_t)side * HSTRIDE;
    const float* a1 = side ? a1b : a1u;
    const float* a2 = side ? a2b : a2u;
    unsigned int hv = *(const unsigned int*)(Hb + (size_t)row * LATENT + lane * 2);
    float h0 = bf2f((unsigned short)(hv & 0xffffu));
    float h1 = bf2f((unsigned short)(hv >> 16));
    float2 x = *(const float2*)(a1 + lane * 2);
    float2 y = *(const float2*)(a2 + lane * 2);
    float d1 = h0 * x.x + h1 * x.y;
    float d2 = h0 * y.x + h1 * y.y;
    #pragma unroll
    for (int o = 32; o; o >>= 1) {
        d1 += __shfl_xor(d1, o);
        d2 += __shfl_xor(d2, o);
    }
    if (lane == 0) { o1[side * n + row] = d1; o2[side * n + row] = d2; }
}

// ---------------------------------------------------------------------------
// Unified atomic-free bucketed counting sort over ALL 4 graphs.
// vd = side*2N + g*N + dst in [0, VN4). 782 buckets of 256 vds.
// ---------------------------------------------------------------------------
__device__ inline void edge_decomp(int i, int& side, int& g, int& idx) {
    if (i < NEDGE)          { side = 0; g = 0; idx = i; }
    else if (i < 2 * NEDGE) { side = 0; g = 1; idx = i - NEDGE; }
    else if (i < 3 * NEDGE) { side = 1; g = 0; idx = i - 2 * NEDGE; }
    else                    { side = 1; g = 1; idx = i - 3 * NEDGE; }
}

__global__ __launch_bounds__(256)
void part_count(const int* __restrict__ eU, const int* __restrict__ eB,
                int* __restrict__ pcnt)
{
    __shared__ int h[NBU];
    int tid = threadIdx.x;
    for (int i = tid; i < NBU; i += 256) h[i] = 0;
    __syncthreads();
    int start = blockIdx.x * PCH;
    int stop  = min(start + PCH, E4);
    for (int i = start + tid; i < stop; i += 256) {
        int side, g, idx;
        edge_decomp(i, side, g, idx);
        const int* base = side ? eB : eU;
        int dst = base[(size_t)(2 * g + 1) * NEDGE + idx];
        int vd = side * (2 * N_NODES) + g * N_NODES + dst;
        atomicAdd(&h[vd >> 8], 1);
    }
    __syncthreads();
    for (int i = tid; i < NBU; i += 256)
        pcnt[i * NPB + blockIdx.x] = h[i];
}

__global__ __launch_bounds__(1024)
void part_scan(const int* __restrict__ pcnt, int* __restrict__ pbase,
               int* __restrict__ bbase, int* __restrict__ offs)
{
    __shared__ int btot[NBU];
    __shared__ int wsum2[16];
    int tid = threadIdx.x;
    int lane = tid & 63, w = tid >> 6;           // 16 waves
    for (int b = w; b < NBU; b += 16) {
        int4 v = *(const int4*)&pcnt[b * NPB + lane * 4];
        int s = v.x + v.y + v.z + v.w;
        int x = s;
        #pragma unroll
        for (int o = 1; o < 64; o <<= 1) {
            int y = __shfl_up(x, o);
            if (lane >= o) x += y;
        }
        int ex = x - s;
        int* pb = &pbase[b * NPB + lane * 4];
        pb[0] = ex;
        pb[1] = ex + v.x;
        pb[2] = ex + v.x + v.y;
        pb[3] = ex + v.x + v.y + v.z;
        if (lane == 63) btot[b] = x;
    }
    __syncthreads();
    int v = (tid < NBU) ? btot[tid] : 0;
    int x = v;
    #pragma unroll
    for (int o = 1; o < 64; o <<= 1) {
        int y = __shfl_up(x, o);
        if (lane >= o) x += y;
    }
    if (lane == 63) wsum2[w] = x;
    __syncthreads();
    int wb = 0;
    for (int i = 0; i < w; ++i) wb += wsum2[i];
    int ex = wb + x - v;
    if (tid < NBU) bbase[tid] = ex;
    if (tid == NBU - 1) bbase[NBU] = ex + v;
    if (tid == 0) offs[VN4] = E4;
}

__global__ __launch_bounds__(256)
void part_fill(const int* __restrict__ eU, const int* __restrict__ eB,
               const int* __restrict__ pbase, const int* __restrict__ bbase,
               int* __restrict__ ebuf)
{
    __shared__ int lbase[NBU];
    __shared__ int lcur[NBU];
    int tid = threadIdx.x;
    for (int i = tid; i < NBU; i += 256) {
        lbase[i] = bbase[i] + pbase[i * NPB + blockIdx.x];
        lcur[i] = 0;
    }
    __syncthreads();
    int start = blockIdx.x * PCH;
    int stop  = min(start + PCH, E4);
    for (int i = start + tid; i < stop; i += 256) {
        int side, g, idx;
        edge_decomp(i, side, g, idx);
        const int* base = side ? eB : eU;
        int src = base[(size_t)(2 * g) * NEDGE + idx];
        int dst = base[(size_t)(2 * g + 1) * NEDGE + idx];
        int vd = side * (2 * N_NODES) + g * N_NODES + dst;
        int b = vd >> 8;
        int p = lbase[b] + atomicAdd(&lcur[b], 1);
        ebuf[p] = ((vd & 255) << 16) | src;
    }
}

__global__ __launch_bounds__(256)
void bucket_csr(const int* __restrict__ ebuf, const int* __restrict__ bbase,
                int* __restrict__ offs, unsigned short* __restrict__ csr)
{
    __shared__ int lds_e[BCAP];
    __shared__ int cnt[256];
    __shared__ int excl[256];
    __shared__ int cur[256];
    __shared__ int wsum[4];
    int tid = threadIdx.x;
    int b = blockIdx.x;
    int lo = bbase[b], hi = bbase[b + 1];
    int sz = hi - lo;

    cnt[tid] = 0; cur[tid] = 0;
    __syncthreads();
    for (int i = tid; i < sz; i += 256) {
        int v = ebuf[lo + i];
        if (i < BCAP) lds_e[i] = v;
        atomicAdd(&cnt[v >> 16], 1);
    }
    __syncthreads();

    int lane = tid & 63, w = tid >> 6;
    int v = cnt[tid];
    int x = v;
    #pragma unroll
    for (int o = 1; o < 64; o <<= 1) {
        int y = __shfl_up(x, o);
        if (lane >= o) x += y;
    }
    if (lane == 63) wsum[w] = x;
    __syncthreads();
    int wb = 0;
    for (int i = 0; i < w; ++i) wb += wsum[i];
    int ex = wb + x - v;
    excl[tid] = ex;
    int vd = b * 256 + tid;
    if (vd < VN4) offs[vd] = lo + ex;
    __syncthreads();

    for (int i = tid; i < sz; i += 256) {
        int e = (i < BCAP) ? lds_e[i] : ebuf[lo + i];
        int dl = e >> 16;
        int p = excl[dl] + atomicAdd(&cur[dl], 1);
        csr[lo + p] = (unsigned short)(e & 0xFFFF);
    }
}

// ---------------------------------------------------------------------------
// Single-pass GAT aggregation, deferred normalization, both sides batched.
// Wave per dst, 16-lane groups, 2-deep pipeline. bf16 output.
// ---------------------------------------------------------------------------
__global__ __launch_bounds__(256)
void gat_gather(const unsigned short* __restrict__ H1b, const float* __restrict__ asf,
                const float* __restrict__ anb,
                const int* __restrict__ offs, const unsigned short* __restrict__ csr,
                const float* __restrict__ omu, const float* __restrict__ omb,
                unsigned short* __restrict__ H2b, int n)
{
    int side = blockIdx.y;
    int lane = threadIdx.x & 63, wid = threadIdx.x >> 6;
    int d = blockIdx.x * 4 + wid;
    if (d >= n) return;
    const unsigned short* Hbase = H1b + (size_t)side * HSTRIDE;
    const int* offside = offs + side * 2 * N_NODES;
    const float* om_p = side ? omb : omu;
    float ad = asf[side * n + d];
    const float* anb_s = anb + side * n;
    int sub = lane >> 4, sl = lane & 15;
    const unsigned short* Hp = Hbase + (sl << 3);
    float fin[8] = {};

    #pragma unroll
    for (int g = 0; g < NGRAPH; ++g) {
        int beg = offside[g * n + d], end = offside[g * n + d + 1];
        float om = om_p[g];
        float un[8] = {};
        float ss = 0.f;

        int e = beg + sub;
        for (; e + 4 < end; e += 8) {
            int s0 = csr[e], s1 = csr[e + 4];
            float a0 = anb_s[s0], a1 = anb_s[s1];
            u16x8 h0 = *(const u16x8*)(Hp + (size_t)s0 * LATENT);
            u16x8 h1 = *(const u16x8*)(Hp + (size_t)s1 * LATENT);
            float sc0 = ad + a0; sc0 = sc0 > 0.f ? sc0 : 0.2f * sc0;
            float sc1 = ad + a1; sc1 = sc1 > 0.f ? sc1 : 0.2f * sc1;
            float w0 = __expf(sc0), w1 = __expf(sc1);
            ss += w0 + w1;
            #pragma unroll
            for (int j = 0; j < 8; ++j) un[j] += w0 * bf2f(h0[j]);
            #pragma unroll
            for (int j = 0; j < 8; ++j) un[j] += w1 * bf2f(h1[j]);
        }
        if (e < end) {
            int s0 = csr[e];
            float a0 = anb_s[s0];
            u16x8 h0 = *(const u16x8*)(Hp + (size_t)s0 * LATENT);
            float sc0 = ad + a0; sc0 = sc0 > 0.f ? sc0 : 0.2f * sc0;
            float w0 = __expf(sc0);
            ss += w0;
            #pragma unroll
            for (int j = 0; j < 8; ++j) un[j] += w0 * bf2f(h0[j]);
        }

        ss += __shfl_xor(ss, 32);
        ss += __shfl_xor(ss, 16);
        float wsc = om / (ss + 1e-16f);
        #pragma unroll
        for (int j = 0; j < 8; ++j) fin[j] += wsc * un[j];
    }

    #pragma unroll
    for (int j = 0; j < 8; ++j) {
        fin[j] += __shfl_xor(fin[j], 32);
        fin[j] += __shfl_xor(fin[j], 16);
    }
    if (sub == 0) {
        u16x8 o;
        #pragma unroll
        for (int j = 0; j < 8; ++j) o[j] = f2bf(fin[j]);
        *(u16x8*)(H2b + (size_t)side * HSTRIDE + (size_t)d * LATENT + sl * 8) = o;
    }
}

// ---------------------------------------------------------------------------
__global__ __launch_bounds__(256)
void predict(const int* __restrict__ uid, const int* __restrict__ iid,
             const float* __restrict__ U, const float* __restrict__ B,
             const float* __restrict__ bu, const float* __restrict__ bb,
             const float* __restrict__ bx, float* __restrict__ out, int batch)
{
    int lane = threadIdx.x & 63, wid = threadIdx.x >> 6;
    int b = blockIdx.x * 4 + wid;
    if (b >= batch) return;
    int u = uid[b], it = iid[b];
    float p = U[(size_t)u * FINALD + lane] * B[(size_t)it * FINALD + lane];
    #pragma unroll
    for (int o = 32; o; o >>= 1) p += __shfl_xor(p, o);
    if (lane == 0) {
        float raw = p + bu[u] + bb[it] + bx[0];
        out[b] = 4.f * (1.f / (1.f + __expf(-raw))) + 1.f;
    }
}

// ---------------------------------------------------------------------------
extern "C" void kernel_launch(void* const* d_in, const int* in_sizes, int n_in,
                              void* d_out, int out_size, void* d_ws, size_t ws_size,
                              hipStream_t stream)
{
    const int N = N_NODES;

    float* ws = (float*)d_ws;
    // [0, 6.4e6): H1b / H3b  (2 sides x 50000x128 bf16)
    // [6.4e6, 12.8e6): H2b (2 sides bf16); ebuf (4e6 ints) overlays
    // [12.8e6,16e6): U_all f32; pcnt/pbase (400384 ints) overlay
    // [16e6,19.2e6): B_all f32
    unsigned short* H1b = (unsigned short*)ws;
    unsigned short* H3b = H1b;                       // overlay (H1b dead after gather)
    unsigned short* H2b = (unsigned short*)(ws + 6400000);
    float* U_all = ws + 12800000;
    float* B_all = ws + 16000000;
    float* asf   = ws + 19200000;                    // [2][N]
    float* anb   = asf + 2 * N;                      // [2][N]
    int*   offs  = (int*)(anb + 2 * N);              // VN4+1
    int*   bbase = offs + VN4 + 1;                   // NBU+1
    unsigned short* csr = (unsigned short*)(bbase + NBU + 1);  // E4 ushorts
    unsigned short* wsp = (unsigned short*)(((uintptr_t)(csr + E4) + 15) & ~(uintptr_t)15);
    int*   ebuf  = (int*)H2b;                        // E4 ints
    int*   pcnt  = (int*)U_all;                      // NBU*NPB
    int*   pbase = pcnt + NBU * NPB;                 // NBU*NPB

    prep_weights<<<(2 * WSP_SIDE + 255) / 256, 256, 0, stream>>>(
        (const float*)d_in[6],  (const float*)d_in[14], (const float*)d_in[15], (const float*)d_in[20],
        (const float*)d_in[10], (const float*)d_in[17], (const float*)d_in[18], (const float*)d_in[21],
        wsp);

    const int* eU = (const int*)d_in[4];
    const int* eB = (const int*)d_in[5];
    part_count<<<NPB, 256, 0, stream>>>(eU, eB, pcnt);
    part_scan<<<1, 1024, 0, stream>>>(pcnt, pbase, bbase, offs);
    part_fill<<<NPB, 256, 0, stream>>>(eU, eB, pbase, bbase, ebuf);
    bucket_csr<<<NBU, 256, 0, stream>>>(ebuf, bbase, offs, csr);

    const float* Su = (const float*)d_in[2];
    const float* Sb = (const float*)d_in[3];
    dim3 gG(391, 1, 2);

    // H1b = bf16( S @ W1 ), both sides
    gemm_big<<<gG, 256, 0, stream>>>(
        Su, Sb, 1, IN_DIM, nullptr, nullptr, 0, 0,
        wsp, 0, 0, nullptr, nullptr, nullptr, nullptr,
        H1b, H1b + HSTRIDE, N, LATENT, 0, 1);

    // alphas, both sides
    rowdots<<<dim3(N / 4, 2), 256, 0, stream>>>(
        H1b, (const float*)d_in[7], (const float*)d_in[8],
        (const float*)d_in[11], (const float*)d_in[12], asf, anb, N);

    // aggregation, both sides
    gat_gather<<<dim3(N / 4, 2), 256, 0, stream>>>(
        H1b, asf, anb, offs, csr,
        (const float*)d_in[9], (const float*)d_in[13], H2b, N);

    // H3b = bf16( elu(H2@W2a + S@W2s + b2) ), both sides
    gemm_big<<<gG, 256, 0, stream>>>(
        H2b, H2b + HSTRIDE, 0, LATENT, Su, Sb, 1, IN_DIM,
        wsp, 32768, 49152,
        (const float*)d_in[16], (const float*)d_in[19], nullptr, nullptr,
        H3b, H3b + HSTRIDE, N, LATENT, 1, 1);

    // OUT = elu(H3@W3) + H4, both sides (W3 zero-padded to 128 cols)
    gemm_big<<<gG, 256, 0, stream>>>(
        H3b, H3b + HSTRIDE, 0, LATENT, nullptr, nullptr, 0, 0,
        wsp, 81920, 0, nullptr, nullptr,
        (const float*)d_in[22], (const float*)d_in[23],
        U_all, B_all, N, FINALD, 1, 0);

    predict<<<BATCHSZ / 4, 256, 0, stream>>>(
        (const int*)d_in[0], (const int*)d_in[1], U_all, B_all,
        (const float*)d_in[24], (const float*)d_in[25], (const float*)d_in[26],
        (float*)d_out, BATCHSZ);
}

// Round 12
// 383.825 us; speedup vs baseline: 2.5710x; 1.0262x over previous
//
#include <hip/hip_runtime.h>
#include <math.h>

#define N_NODES 50000
#define IN_DIM  256
#define LATENT  128
#define FINALD  64
#define NGRAPH  2
#define NEDGE   1000000
#define BATCHSZ 16384

#define VN4     (4 * N_NODES)          // unified virtual dst ids: side*2N + g*N + dst
#define NBU     ((VN4 + 255) >> 8)     // 782 buckets of 256 vds
#define E4      (4 * NEDGE)
#define NPB     256                    // partition blocks
#define PCH     ((E4 + NPB - 1) / NPB) // 15625 edges per partition block
#define BCAP    8192                   // bucket_csr LDS cache entries

// bf16 weights per side: W1[128][256] W2a[128][128] W2s[128][256] W3pad[128][128] (k-major [N][K])
#define WSP_SIDE   98304
#define HSTRIDE    (N_NODES * LATENT)  // per-side ushort stride for H1b/H2b

typedef __attribute__((ext_vector_type(8))) short bf16x8;
typedef __attribute__((ext_vector_type(4))) float f32x4;
typedef __attribute__((ext_vector_type(8))) unsigned short u16x8;
typedef __attribute__((ext_vector_type(4))) unsigned short u16x4;

__device__ inline unsigned short f2bf(float x) {
    unsigned int u = __float_as_uint(x);
    u = (u + 0x7fffu + ((u >> 16) & 1u)) >> 16;
    return (unsigned short)u;
}
__device__ inline float bf2f(unsigned short h) {
    return __uint_as_float(((unsigned int)h) << 16);
}

// ---------------------------------------------------------------------------
// Weight prep: f32 [K][N] -> bf16 k-major [N][K]; W3 zero-padded to N=128.
// ---------------------------------------------------------------------------
__global__ __launch_bounds__(256)
void prep_weights(const float* __restrict__ W1u, const float* __restrict__ Wu2,
                  const float* __restrict__ Wus2, const float* __restrict__ Wu3,
                  const float* __restrict__ W1b, const float* __restrict__ Wb2,
                  const float* __restrict__ Wbs2, const float* __restrict__ Wb3,
                  unsigned short* __restrict__ dst)
{
    int e = blockIdx.x * 256 + threadIdx.x;
    if (e >= 2 * WSP_SIDE) return;
    int side = e >= WSP_SIDE;
    int r = e - (side ? WSP_SIDE : 0);
    const float* src; int K, hoff; int w3 = 0;
    if (r < 32768)      { src = side ? W1b  : W1u;  K = 256; hoff = 0;     }
    else if (r < 49152) { src = side ? Wb2  : Wu2;  K = 128; hoff = 32768; r -= 32768; }
    else if (r < 81920) { src = side ? Wbs2 : Wus2; K = 256; hoff = 49152; r -= 49152; }
    else                { src = side ? Wb3  : Wu3;  K = 128; hoff = 81920; r -= 81920; w3 = 1; }
    int n = (K == 256) ? (r >> 8) : (r >> 7);
    int k = (K == 256) ? (r & 255) : (r & 127);
    float x;
    if (w3) x = (n < 64) ? src[k * 64 + n] : 0.f;
    else    x = src[k * 128 + n];
    dst[(size_t)side * WSP_SIDE + hoff + n * K + k] = f2bf(x);
}

// ---------------------------------------------------------------------------
#define BM 128
#define BK 64

__device__ inline int swz(int r, int k) {      // [*][64] tiles
    return r * BK + ((((k >> 3) ^ (r & 7)) << 3) | (k & 7));
}
__device__ inline int swz2(int r, int c) {     // [*][128] tiles
    return r * 128 + ((((c >> 3) ^ (r & 7)) << 3) | (c & 7));
}

// ---------------------------------------------------------------------------
// GEMM1 + fused rowdots: H1b = bf16(S @ W1); asf/anb = H1 row-dots.
// 128x128 tile (full LATENT width), K=256. Both sides via blockIdx.z.
// ---------------------------------------------------------------------------
__global__ __launch_bounds__(256)
void gemm_h1(const float* __restrict__ Su, const float* __restrict__ Sb,
             const unsigned short* __restrict__ wspb,
             const float* __restrict__ aself_u, const float* __restrict__ anbv_u,
             const float* __restrict__ aself_b, const float* __restrict__ anbv_b,
             unsigned short* __restrict__ H1b, float* __restrict__ asf,
             float* __restrict__ anb, int M)
{
    __shared__ unsigned short AhS[BM * BK];
    __shared__ unsigned short BhS[BM * BK];
    __shared__ float dotL[BM][2];

    const int side = blockIdx.z;
    const float* Ap = side ? Sb : Su;
    const unsigned short* Bp = wspb + (size_t)side * WSP_SIDE;   // W1 slot
    const float* avs = side ? aself_b : aself_u;
    const float* avn = side ? anbv_b : anbv_u;
    unsigned short* Cout = H1b + (size_t)side * HSTRIDE;

    const int tid = threadIdx.x;
    const int rowBase = blockIdx.x * BM;
    const int wave = tid >> 6, lane = tid & 63;
    const int wr = wave >> 1, wc = wave & 1;
    const int sl = lane & 15, lg = lane >> 4;
    const int K = IN_DIM;

    if (tid < BM) { dotL[tid][0] = 0.f; dotL[tid][1] = 0.f; }

    f32x4 acc[4][4] = {};

    for (int k0 = 0; k0 < K; k0 += BK) {
        __syncthreads();
        #pragma unroll
        for (int p = 0; p < 4; ++p) {
            int q = p * 256 + tid;
            int row = q >> 3;
            int kq = (q & 7) << 3;
            int grow = rowBase + row;
            u16x8 hv = {0, 0, 0, 0, 0, 0, 0, 0};
            if (grow < M) {
                const float* a = Ap + (size_t)grow * K + k0 + kq;
                float4 v0 = *(const float4*)a;
                float4 v1 = *(const float4*)(a + 4);
                hv[0] = f2bf(v0.x); hv[1] = f2bf(v0.y); hv[2] = f2bf(v0.z); hv[3] = f2bf(v0.w);
                hv[4] = f2bf(v1.x); hv[5] = f2bf(v1.y); hv[6] = f2bf(v1.z); hv[7] = f2bf(v1.w);
            }
            *(u16x8*)&AhS[swz(row, kq)] = hv;
        }
        #pragma unroll
        for (int p = 0; p < 4; ++p) {
            int q = p * 256 + tid;
            int n = q >> 3;
            int kq = (q & 7) << 3;
            u16x8 hv = *(const u16x8*)(Bp + (size_t)n * K + k0 + kq);
            *(u16x8*)&BhS[swz(n, kq)] = hv;
        }
        __syncthreads();
        #pragma unroll
        for (int ks = 0; ks < 2; ++ks) {
            int kof = ks * 32 + lg * 8;
            bf16x8 af[4], bf[4];
            #pragma unroll
            for (int f = 0; f < 4; ++f) {
                af[f] = *(const bf16x8*)&AhS[swz(wr * 64 + f * 16 + sl, kof)];
                bf[f] = *(const bf16x8*)&BhS[swz(wc * 64 + f * 16 + sl, kof)];
            }
            #pragma unroll
            for (int fm = 0; fm < 4; ++fm)
                #pragma unroll
                for (int fn = 0; fn < 4; ++fn)
                    acc[fm][fn] = __builtin_amdgcn_mfma_f32_16x16x32_bf16(af[fm], bf[fn], acc[fm][fn], 0, 0, 0);
        }
    }

    // C write (bf16)
    #pragma unroll
    for (int fm = 0; fm < 4; ++fm)
        #pragma unroll
        for (int r = 0; r < 4; ++r) {
            int row = rowBase + wr * 64 + fm * 16 + lg * 4 + r;
            if (row >= M) continue;
            #pragma unroll
            for (int fn = 0; fn < 4; ++fn) {
                int col = wc * 64 + fn * 16 + sl;
                Cout[(size_t)row * LATENT + col] = f2bf(acc[fm][fn][r]);
            }
        }

    // fused rowdots: per-row dot with a_self / a_nb (all lanes active, uniform)
    float as_[4], an_[4];
    #pragma unroll
    for (int fn = 0; fn < 4; ++fn) {
        int col = wc * 64 + fn * 16 + sl;
        as_[fn] = avs[col];
        an_[fn] = avn[col];
    }
    #pragma unroll
    for (int fm = 0; fm < 4; ++fm)
        #pragma unroll
        for (int r = 0; r < 4; ++r) {
            float p1 = 0.f, p2 = 0.f;
            #pragma unroll
            for (int fn = 0; fn < 4; ++fn) {
                float v = acc[fm][fn][r];
                p1 += v * as_[fn];
                p2 += v * an_[fn];
            }
            #pragma unroll
            for (int o = 1; o <= 8; o <<= 1) {
                p1 += __shfl_xor(p1, o);
                p2 += __shfl_xor(p2, o);
            }
            if (sl == 0) {
                int row_l = wr * 64 + fm * 16 + lg * 4 + r;
                atomicAdd(&dotL[row_l][0], p1);
                atomicAdd(&dotL[row_l][1], p2);
            }
        }
    __syncthreads();
    if (tid < BM) {
        int row = rowBase + tid;
        if (row < M) {
            asf[side * M + row] = dotL[tid][0];
            anb[side * M + row] = dotL[tid][1];
        }
    }
}

// ---------------------------------------------------------------------------
// Fused GEMM2+GEMM3: H3 = elu(H2@W2a + S@W2s + b2) kept in LDS (bf16),
// then OUT = elu(H3@W3) + H4, f32. Both sides via blockIdx.z. LDS 48KB.
// ---------------------------------------------------------------------------
__global__ __launch_bounds__(256)
void gemm_fused23(const unsigned short* __restrict__ H2b,
                  const float* __restrict__ Su, const float* __restrict__ Sb,
                  const unsigned short* __restrict__ wspb,
                  const float* __restrict__ b2u, const float* __restrict__ b2b,
                  const float* __restrict__ H4u, const float* __restrict__ H4b,
                  float* __restrict__ Uo, float* __restrict__ Bo, int M)
{
    __shared__ unsigned short sm[BM * BK * 2];   // AhS/BhS; H3S overlays (32KB)
    __shared__ unsigned short W3S[64 * 128];     // 16KB
    unsigned short* AhS = sm;
    unsigned short* BhS = sm + BM * BK;

    const int side = blockIdx.z;
    const unsigned short* Bside = wspb + (size_t)side * WSP_SIDE;
    const float* bias = side ? b2b : b2u;
    const float* H4 = side ? H4b : H4u;
    float* Cout = side ? Bo : Uo;

    const int tid = threadIdx.x;
    const int rowBase = blockIdx.x * BM;
    const int wave = tid >> 6, lane = tid & 63;
    const int wr = wave >> 1, wc = wave & 1;
    const int sl = lane & 15, lg = lane >> 4;

    // preload W3 [64][128] k-major (swizzled); region untouched by main loop
    {
        const unsigned short* w3 = Bside + 81920;
        #pragma unroll
        for (int p = 0; p < 4; ++p) {
            int i = p * 256 + tid;        // 1024 chunks of 8
            int n = i >> 4;               // 0..63
            int kq = (i & 15) << 3;       // 0..120
            u16x8 v = *(const u16x8*)(w3 + (size_t)n * 128 + kq);
            *(u16x8*)&W3S[swz2(n, kq)] = v;
        }
    }

    f32x4 acc[4][4] = {};

    const void* Ap; const unsigned short* Bp; int K, af32;
    for (int pass = 0; pass < 2; ++pass) {
        if (pass == 0) {
            Ap = H2b + (size_t)side * HSTRIDE; af32 = 0; K = LATENT; Bp = Bside + 32768;   // W2a
        } else {
            Ap = side ? (const void*)Sb : (const void*)Su; af32 = 1; K = IN_DIM; Bp = Bside + 49152; // W2s
        }
        for (int k0 = 0; k0 < K; k0 += BK) {
            __syncthreads();
            #pragma unroll
            for (int p = 0; p < 4; ++p) {
                int q = p * 256 + tid;
                int row = q >> 3;
                int kq = (q & 7) << 3;
                int grow = rowBase + row;
                u16x8 hv = {0, 0, 0, 0, 0, 0, 0, 0};
                if (grow < M) {
                    if (af32) {
                        const float* a = (const float*)Ap + (size_t)grow * K + k0 + kq;
                        float4 v0 = *(const float4*)a;
                        float4 v1 = *(const float4*)(a + 4);
                        hv[0] = f2bf(v0.x); hv[1] = f2bf(v0.y); hv[2] = f2bf(v0.z); hv[3] = f2bf(v0.w);
                        hv[4] = f2bf(v1.x); hv[5] = f2bf(v1.y); hv[6] = f2bf(v1.z); hv[7] = f2bf(v1.w);
                    } else {
                        hv = *(const u16x8*)((const unsigned short*)Ap + (size_t)grow * K + k0 + kq);
                    }
                }
                *(u16x8*)&AhS[swz(row, kq)] = hv;
            }
            #pragma unroll
            for (int p = 0; p < 4; ++p) {
                int q = p * 256 + tid;
                int n = q >> 3;
                int kq = (q & 7) << 3;
                u16x8 hv = *(const u16x8*)(Bp + (size_t)n * K + k0 + kq);
                *(u16x8*)&BhS[swz(n, kq)] = hv;
            }
            __syncthreads();
            #pragma unroll
            for (int ks = 0; ks < 2; ++ks) {
                int kof = ks * 32 + lg * 8;
                bf16x8 af[4], bf[4];
                #pragma unroll
                for (int f = 0; f < 4; ++f) {
                    af[f] = *(const bf16x8*)&AhS[swz(wr * 64 + f * 16 + sl, kof)];
                    bf[f] = *(const bf16x8*)&BhS[swz(wc * 64 + f * 16 + sl, kof)];
                }
                #pragma unroll
                for (int fm = 0; fm < 4; ++fm)
                    #pragma unroll
                    for (int fn = 0; fn < 4; ++fn)
                        acc[fm][fn] = __builtin_amdgcn_mfma_f32_16x16x32_bf16(af[fm], bf[fn], acc[fm][fn], 0, 0, 0);
            }
        }
    }

    __syncthreads();   // main-loop LDS reads done; reuse sm as H3S
    unsigned short* H3S = sm;   // [128][128] bf16, swz2

    // epilogue 1: H3 = elu(acc + b2) -> LDS
    #pragma unroll
    for (int fm = 0; fm < 4; ++fm)
        #pragma unroll
        for (int r = 0; r < 4; ++r) {
            int row_l = wr * 64 + fm * 16 + lg * 4 + r;
            #pragma unroll
            for (int fn = 0; fn < 4; ++fn) {
                int col = wc * 64 + fn * 16 + sl;
                float v = acc[fm][fn][r] + bias[col];
                v = v > 0.f ? v : (__expf(v) - 1.f);
                H3S[swz2(row_l, col)] = f2bf(v);
            }
        }
    __syncthreads();

    // matmul2: OUT[128][64] = H3 @ W3, K=128
    f32x4 acc2[4][2] = {};
    #pragma unroll
    for (int ks = 0; ks < 4; ++ks) {
        int kof = ks * 32 + lg * 8;
        bf16x8 a2[4], b2f[2];
        #pragma unroll
        for (int f = 0; f < 4; ++f)
            a2[f] = *(const bf16x8*)&H3S[swz2(wr * 64 + f * 16 + sl, kof)];
        #pragma unroll
        for (int f = 0; f < 2; ++f)
            b2f[f] = *(const bf16x8*)&W3S[swz2(wc * 32 + f * 16 + sl, kof)];
        #pragma unroll
        for (int fm = 0; fm < 4; ++fm)
            #pragma unroll
            for (int fn = 0; fn < 2; ++fn)
                acc2[fm][fn] = __builtin_amdgcn_mfma_f32_16x16x32_bf16(a2[fm], b2f[fn], acc2[fm][fn], 0, 0, 0);
    }

    // epilogue 2: OUT = elu(acc2) + H4
    #pragma unroll
    for (int fm = 0; fm < 4; ++fm)
        #pragma unroll
        for (int r = 0; r < 4; ++r) {
            int row = rowBase + wr * 64 + fm * 16 + lg * 4 + r;
            if (row >= M) continue;
            #pragma unroll
            for (int fn = 0; fn < 2; ++fn) {
                int col = wc * 32 + fn * 16 + sl;
                float v = acc2[fm][fn][r];
                v = v > 0.f ? v : (__expf(v) - 1.f);
                v += H4[(size_t)row * FINALD + col];
                Cout[(size_t)row * FINALD + col] = v;
            }
        }
}

// ---------------------------------------------------------------------------
// Unified atomic-free bucketed counting sort over ALL 4 graphs.
// ---------------------------------------------------------------------------
__device__ inline void edge_decomp(int i, int& side, int& g, int& idx) {
    if (i < NEDGE)          { side = 0; g = 0; idx = i; }
    else if (i < 2 * NEDGE) { side = 0; g = 1; idx = i - NEDGE; }
    else if (i < 3 * NEDGE) { side = 1; g = 0; idx = i - 2 * NEDGE; }
    else                    { side = 1; g = 1; idx = i - 3 * NEDGE; }
}

__global__ __launch_bounds__(256)
void part_count(const int* __restrict__ eU, const int* __restrict__ eB,
                int* __restrict__ pcnt)
{
    __shared__ int h[NBU];
    int tid = threadIdx.x;
    for (int i = tid; i < NBU; i += 256) h[i] = 0;
    __syncthreads();
    int start = blockIdx.x * PCH;
    int stop  = min(start + PCH, E4);
    for (int i = start + tid; i < stop; i += 256) {
        int side, g, idx;
        edge_decomp(i, side, g, idx);
        const int* base = side ? eB : eU;
        int dst = base[(size_t)(2 * g + 1) * NEDGE + idx];
        int vd = side * (2 * N_NODES) + g * N_NODES + dst;
        atomicAdd(&h[vd >> 8], 1);
    }
    __syncthreads();
    for (int i = tid; i < NBU; i += 256)
        pcnt[i * NPB + blockIdx.x] = h[i];
}

__global__ __launch_bounds__(1024)
void part_scan(const int* __restrict__ pcnt, int* __restrict__ pbase,
               int* __restrict__ bbase, int* __restrict__ offs)
{
    __shared__ int btot[NBU];
    __shared__ int wsum2[16];
    int tid = threadIdx.x;
    int lane = tid & 63, w = tid >> 6;           // 16 waves
    for (int b = w; b < NBU; b += 16) {
        int4 v = *(const int4*)&pcnt[b * NPB + lane * 4];
        int s = v.x + v.y + v.z + v.w;
        int x = s;
        #pragma unroll
        for (int o = 1; o < 64; o <<= 1) {
            int y = __shfl_up(x, o);
            if (lane >= o) x += y;
        }
        int ex = x - s;
        int* pb = &pbase[b * NPB + lane * 4];
        pb[0] = ex;
        pb[1] = ex + v.x;
        pb[2] = ex + v.x + v.y;
        pb[3] = ex + v.x + v.y + v.z;
        if (lane == 63) btot[b] = x;
    }
    __syncthreads();
    int v = (tid < NBU) ? btot[tid] : 0;
    int x = v;
    #pragma unroll
    for (int o = 1; o < 64; o <<= 1) {
        int y = __shfl_up(x, o);
        if (lane >= o) x += y;
    }
    if (lane == 63) wsum2[w] = x;
    __syncthreads();
    int wb = 0;
    for (int i = 0; i < w; ++i) wb += wsum2[i];
    int ex = wb + x - v;
    if (tid < NBU) bbase[tid] = ex;
    if (tid == NBU - 1) bbase[NBU] = ex + v;
    if (tid == 0) offs[VN4] = E4;
}

__global__ __launch_bounds__(256)
void part_fill(const int* __restrict__ eU, const int* __restrict__ eB,
               const int* __restrict__ pbase, const int* __restrict__ bbase,
               int* __restrict__ ebuf)
{
    __shared__ int lbase[NBU];
    __shared__ int lcur[NBU];
    int tid = threadIdx.x;
    for (int i = tid; i < NBU; i += 256) {
        lbase[i] = bbase[i] + pbase[i * NPB + blockIdx.x];
        lcur[i] = 0;
    }
    __syncthreads();
    int start = blockIdx.x * PCH;
    int stop  = min(start + PCH, E4);
    for (int i = start + tid; i < stop; i += 256) {
        int side, g, idx;
        edge_decomp(i, side, g, idx);
        const int* base = side ? eB : eU;
        int src = base[(size_t)(2 * g) * NEDGE + idx];
        int dst = base[(size_t)(2 * g + 1) * NEDGE + idx];
        int vd = side * (2 * N_NODES) + g * N_NODES + dst;
        int b = vd >> 8;
        int p = lbase[b] + atomicAdd(&lcur[b], 1);
        ebuf[p] = ((vd & 255) << 16) | src;
    }
}

__global__ __launch_bounds__(256)
void bucket_csr(const int* __restrict__ ebuf, const int* __restrict__ bbase,
                int* __restrict__ offs, unsigned short* __restrict__ csr)
{
    __shared__ int lds_e[BCAP];
    __shared__ int cnt[256];
    __shared__ int excl[256];
    __shared__ int cur[256];
    __shared__ int wsum[4];
    int tid = threadIdx.x;
    int b = blockIdx.x;
    int lo = bbase[b], hi = bbase[b + 1];
    int sz = hi - lo;

    cnt[tid] = 0; cur[tid] = 0;
    __syncthreads();
    for (int i = tid; i < sz; i += 256) {
        int v = ebuf[lo + i];
        if (i < BCAP) lds_e[i] = v;
        atomicAdd(&cnt[v >> 16], 1);
    }
    __syncthreads();

    int lane = tid & 63, w = tid >> 6;
    int v = cnt[tid];
    int x = v;
    #pragma unroll
    for (int o = 1; o < 64; o <<= 1) {
        int y = __shfl_up(x, o);
        if (lane >= o) x += y;
    }
    if (lane == 63) wsum[w] = x;
    __syncthreads();
    int wb = 0;
    for (int i = 0; i < w; ++i) wb += wsum[i];
    int ex = wb + x - v;
    excl[tid] = ex;
    int vd = b * 256 + tid;
    if (vd < VN4) offs[vd] = lo + ex;
    __syncthreads();

    for (int i = tid; i < sz; i += 256) {
        int e = (i < BCAP) ? lds_e[i] : ebuf[lo + i];
        int dl = e >> 16;
        int p = excl[dl] + atomicAdd(&cur[dl], 1);
        csr[lo + p] = (unsigned short)(e & 0xFFFF);
    }
}

// ---------------------------------------------------------------------------
// GAT aggregation: per-64-edge-chunk weight precompute + broadcast.
// FIX vs r11: shfls are executed with FULL exec mask — the inner loop trip
// count (nIter) is wave-uniform (ce is per-wave), and only the per-edge
// gathers are guarded. Divergent-exec ds_bpermute was the r11 bug.
// ---------------------------------------------------------------------------
__global__ __launch_bounds__(256)
void gat_gather(const unsigned short* __restrict__ H1b, const float* __restrict__ asf,
                const float* __restrict__ anb,
                const int* __restrict__ offs, const unsigned short* __restrict__ csr,
                const float* __restrict__ omu, const float* __restrict__ omb,
                unsigned short* __restrict__ H2b, int n)
{
    int side = blockIdx.y;
    int lane = threadIdx.x & 63, wid = threadIdx.x >> 6;
    int d = blockIdx.x * 4 + wid;
    if (d >= n) return;
    const unsigned short* Hbase = H1b + (size_t)side * HSTRIDE;
    const int* offside = offs + side * 2 * N_NODES;
    const float* om_p = side ? omb : omu;
    float ad = asf[side * n + d];
    const float* anb_s = anb + side * n;
    int sub = lane >> 4, sl = lane & 15;
    const unsigned short* Hp = Hbase + (sl << 3);
    float fin[8] = {};

    #pragma unroll
    for (int g = 0; g < NGRAPH; ++g) {
        int beg = offside[g * n + d], end = offside[g * n + d + 1];
        float om = om_p[g];
        float un[8] = {};
        float ss = 0.f;

        for (int c0 = beg; c0 < end; c0 += 64) {
            int ce = min(end - c0, 64);          // wave-uniform
            float wreg = 0.f;
            if (lane < ce) {
                int s = csr[c0 + lane];
                float sc = ad + anb_s[s];
                sc = sc > 0.f ? sc : 0.2f * sc;
                wreg = __expf(sc);
            }
            ss += wreg;
            int nIter = (ce + 7) >> 3;           // wave-uniform trip count
            for (int it = 0; it < nIter; ++it) {
                int t = it * 8 + sub;
                float w0 = __shfl(wreg, t);      // full exec mask: well-defined
                float w1 = __shfl(wreg, t + 4);
                if (t < ce) {
                    int s0 = csr[c0 + t];
                    u16x8 h0 = *(const u16x8*)(Hp + (size_t)s0 * LATENT);
                    #pragma unroll
                    for (int j = 0; j < 8; ++j) un[j] += w0 * bf2f(h0[j]);
                }
                if (t + 4 < ce) {
                    int s1 = csr[c0 + t + 4];
                    u16x8 h1 = *(const u16x8*)(Hp + (size_t)s1 * LATENT);
                    #pragma unroll
                    for (int j = 0; j < 8; ++j) un[j] += w1 * bf2f(h1[j]);
                }
            }
        }

        // full-wave sum of exp
        #pragma unroll
        for (int o = 32; o; o >>= 1) ss += __shfl_xor(ss, o);
        float wsc = om / (ss + 1e-16f);
        #pragma unroll
        for (int j = 0; j < 8; ++j) fin[j] += wsc * un[j];
    }

    #pragma unroll
    for (int j = 0; j < 8; ++j) {
        fin[j] += __shfl_xor(fin[j], 32);
        fin[j] += __shfl_xor(fin[j], 16);
    }
    if (sub == 0) {
        u16x8 o;
        #pragma unroll
        for (int j = 0; j < 8; ++j) o[j] = f2bf(fin[j]);
        *(u16x8*)(H2b + (size_t)side * HSTRIDE + (size_t)d * LATENT + sl * 8) = o;
    }
}

// ---------------------------------------------------------------------------
__global__ __launch_bounds__(256)
void predict(const int* __restrict__ uid, const int* __restrict__ iid,
             const float* __restrict__ U, const float* __restrict__ B,
             const float* __restrict__ bu, const float* __restrict__ bb,
             const float* __restrict__ bx, float* __restrict__ out, int batch)
{
    int lane = threadIdx.x & 63, wid = threadIdx.x >> 6;
    int b = blockIdx.x * 4 + wid;
    if (b >= batch) return;
    int u = uid[b], it = iid[b];
    float p = U[(size_t)u * FINALD + lane] * B[(size_t)it * FINALD + lane];
    #pragma unroll
    for (int o = 32; o; o >>= 1) p += __shfl_xor(p, o);
    if (lane == 0) {
        float raw = p + bu[u] + bb[it] + bx[0];
        out[b] = 4.f * (1.f / (1.f + __expf(-raw))) + 1.f;
    }
}

// ---------------------------------------------------------------------------
extern "C" void kernel_launch(void* const* d_in, const int* in_sizes, int n_in,
                              void* d_out, int out_size, void* d_ws, size_t ws_size,
                              hipStream_t stream)
{
    const int N = N_NODES;

    float* ws = (float*)d_ws;
    unsigned short* H1b = (unsigned short*)ws;           // 2 sides bf16 (12.8e6 ush)
    unsigned short* H2b = (unsigned short*)(ws + 6400000);
    float* U_all = ws + 12800000;
    float* B_all = ws + 16000000;
    float* asf   = ws + 19200000;                        // [2][N]
    float* anb   = asf + 2 * N;                          // [2][N]
    int*   offs  = (int*)(anb + 2 * N);                  // VN4+1
    int*   bbase = offs + VN4 + 1;                       // NBU+1
    unsigned short* csr = (unsigned short*)(bbase + NBU + 1);  // E4 ushorts
    unsigned short* wsp = (unsigned short*)(((uintptr_t)(csr + E4) + 15) & ~(uintptr_t)15);
    int*   ebuf  = (int*)H2b;                            // E4 ints (dead before gather)
    int*   pcnt  = (int*)U_all;                          // NBU*NPB
    int*   pbase = pcnt + NBU * NPB;                     // NBU*NPB

    prep_weights<<<(2 * WSP_SIDE + 255) / 256, 256, 0, stream>>>(
        (const float*)d_in[6],  (const float*)d_in[14], (const float*)d_in[15], (const float*)d_in[20],
        (const float*)d_in[10], (const float*)d_in[17], (const float*)d_in[18], (const float*)d_in[21],
        wsp);

    const int* eU = (const int*)d_in[4];
    const int* eB = (const int*)d_in[5];
    part_count<<<NPB, 256, 0, stream>>>(eU, eB, pcnt);
    part_scan<<<1, 1024, 0, stream>>>(pcnt, pbase, bbase, offs);
    part_fill<<<NPB, 256, 0, stream>>>(eU, eB, pbase, bbase, ebuf);
    bucket_csr<<<NBU, 256, 0, stream>>>(ebuf, bbase, offs, csr);

    const float* Su = (const float*)d_in[2];
    const float* Sb = (const float*)d_in[3];
    dim3 gG(391, 1, 2);

    // H1 GEMM + fused rowdots
    gemm_h1<<<gG, 256, 0, stream>>>(
        Su, Sb, wsp,
        (const float*)d_in[7], (const float*)d_in[8],
        (const float*)d_in[11], (const float*)d_in[12],
        H1b, asf, anb, N);

    // aggregation, both sides
    gat_gather<<<dim3(N / 4, 2), 256, 0, stream>>>(
        H1b, asf, anb, offs, csr,
        (const float*)d_in[9], (const float*)d_in[13], H2b, N);

    // fused H3 GEMM + final GEMM
    gemm_fused23<<<gG, 256, 0, stream>>>(
        H2b, Su, Sb, wsp,
        (const float*)d_in[16], (const float*)d_in[19],
        (const float*)d_in[22], (const float*)d_in[23],
        U_all, B_all, N);

    predict<<<BATCHSZ / 4, 256, 0, stream>>>(
        (const int*)d_in[0], (const int*)d_in[1], U_all, B_all,
        (const float*)d_in[24], (const float*)d_in[25], (const float*)d_in[26],
        (float*)d_out, BATCHSZ);
}

// Round 13
// 344.264 us; speedup vs baseline: 2.8665x; 1.1149x over previous
//
#include <hip/hip_runtime.h>
#include <math.h>

#define N_NODES 50000
#define IN_DIM  256
#define LATENT  128
#define FINALD  64
#define NGRAPH  2
#define NEDGE   1000000
#define BATCHSZ 16384

#define VN4     (4 * N_NODES)          // unified virtual dst ids: side*2N + g*N + dst
#define NBU     ((VN4 + 255) >> 8)     // 782 buckets of 256 vds
#define E4      (4 * NEDGE)
#define NPB     256                    // partition blocks
#define PCH     ((E4 + NPB - 1) / NPB) // 15625 edges per partition block
#define BCAP    8192                   // bucket_csr LDS cache entries

// bf16 weights per side: W1[128][256] W2a[128][128] W2s[128][256] W3pad[128][128] (k-major [N][K])
#define WSP_SIDE   98304
#define HSTRIDE    (N_NODES * LATENT)  // per-side ushort stride for H1b/H2b

typedef __attribute__((ext_vector_type(8))) short bf16x8;
typedef __attribute__((ext_vector_type(4))) float f32x4;
typedef __attribute__((ext_vector_type(8))) unsigned short u16x8;
typedef __attribute__((ext_vector_type(4))) unsigned short u16x4;

__device__ inline unsigned short f2bf(float x) {
    unsigned int u = __float_as_uint(x);
    u = (u + 0x7fffu + ((u >> 16) & 1u)) >> 16;
    return (unsigned short)u;
}
__device__ inline float bf2f(unsigned short h) {
    return __uint_as_float(((unsigned int)h) << 16);
}

// ---------------------------------------------------------------------------
// Weight prep: f32 [K][N] -> bf16 k-major [N][K]; W3 zero-padded to N=128.
// ---------------------------------------------------------------------------
__global__ __launch_bounds__(256)
void prep_weights(const float* __restrict__ W1u, const float* __restrict__ Wu2,
                  const float* __restrict__ Wus2, const float* __restrict__ Wu3,
                  const float* __restrict__ W1b, const float* __restrict__ Wb2,
                  const float* __restrict__ Wbs2, const float* __restrict__ Wb3,
                  unsigned short* __restrict__ dst)
{
    int e = blockIdx.x * 256 + threadIdx.x;
    if (e >= 2 * WSP_SIDE) return;
    int side = e >= WSP_SIDE;
    int r = e - (side ? WSP_SIDE : 0);
    const float* src; int K, hoff; int w3 = 0;
    if (r < 32768)      { src = side ? W1b  : W1u;  K = 256; hoff = 0;     }
    else if (r < 49152) { src = side ? Wb2  : Wu2;  K = 128; hoff = 32768; r -= 32768; }
    else if (r < 81920) { src = side ? Wbs2 : Wus2; K = 256; hoff = 49152; r -= 49152; }
    else                { src = side ? Wb3  : Wu3;  K = 128; hoff = 81920; r -= 81920; w3 = 1; }
    int n = (K == 256) ? (r >> 8) : (r >> 7);
    int k = (K == 256) ? (r & 255) : (r & 127);
    float x;
    if (w3) x = (n < 64) ? src[k * 64 + n] : 0.f;
    else    x = src[k * 128 + n];
    dst[(size_t)side * WSP_SIDE + hoff + n * K + k] = f2bf(x);
}

// ---------------------------------------------------------------------------
#define BM 128
#define BK 64

__device__ inline int swz(int r, int k) {      // [*][64] tiles
    return r * BK + ((((k >> 3) ^ (r & 7)) << 3) | (k & 7));
}
__device__ inline int swz2(int r, int c) {     // [*][128] tiles
    return r * 128 + ((((c >> 3) ^ (r & 7)) << 3) | (c & 7));
}

// ---------------------------------------------------------------------------
// GEMM1 + fused rowdots: H1b = bf16(S @ W1); asf/anb = H1 row-dots.
// 128x128 tile (full LATENT width), K=256. Both sides via blockIdx.z.
// ---------------------------------------------------------------------------
__global__ __launch_bounds__(256)
void gemm_h1(const float* __restrict__ Su, const float* __restrict__ Sb,
             const unsigned short* __restrict__ wspb,
             const float* __restrict__ aself_u, const float* __restrict__ anbv_u,
             const float* __restrict__ aself_b, const float* __restrict__ anbv_b,
             unsigned short* __restrict__ H1b, float* __restrict__ asf,
             float* __restrict__ anb, int M)
{
    __shared__ unsigned short AhS[BM * BK];
    __shared__ unsigned short BhS[BM * BK];
    __shared__ float dotL[BM][2];

    const int side = blockIdx.z;
    const float* Ap = side ? Sb : Su;
    const unsigned short* Bp = wspb + (size_t)side * WSP_SIDE;   // W1 slot
    const float* avs = side ? aself_b : aself_u;
    const float* avn = side ? anbv_b : anbv_u;
    unsigned short* Cout = H1b + (size_t)side * HSTRIDE;

    const int tid = threadIdx.x;
    const int rowBase = blockIdx.x * BM;
    const int wave = tid >> 6, lane = tid & 63;
    const int wr = wave >> 1, wc = wave & 1;
    const int sl = lane & 15, lg = lane >> 4;
    const int K = IN_DIM;

    if (tid < BM) { dotL[tid][0] = 0.f; dotL[tid][1] = 0.f; }

    f32x4 acc[4][4] = {};

    for (int k0 = 0; k0 < K; k0 += BK) {
        __syncthreads();
        #pragma unroll
        for (int p = 0; p < 4; ++p) {
            int q = p * 256 + tid;
            int row = q >> 3;
            int kq = (q & 7) << 3;
            int grow = rowBase + row;
            u16x8 hv = {0, 0, 0, 0, 0, 0, 0, 0};
            if (grow < M) {
                const float* a = Ap + (size_t)grow * K + k0 + kq;
                float4 v0 = *(const float4*)a;
                float4 v1 = *(const float4*)(a + 4);
                hv[0] = f2bf(v0.x); hv[1] = f2bf(v0.y); hv[2] = f2bf(v0.z); hv[3] = f2bf(v0.w);
                hv[4] = f2bf(v1.x); hv[5] = f2bf(v1.y); hv[6] = f2bf(v1.z); hv[7] = f2bf(v1.w);
            }
            *(u16x8*)&AhS[swz(row, kq)] = hv;
        }
        #pragma unroll
        for (int p = 0; p < 4; ++p) {
            int q = p * 256 + tid;
            int n = q >> 3;
            int kq = (q & 7) << 3;
            u16x8 hv = *(const u16x8*)(Bp + (size_t)n * K + k0 + kq);
            *(u16x8*)&BhS[swz(n, kq)] = hv;
        }
        __syncthreads();
        #pragma unroll
        for (int ks = 0; ks < 2; ++ks) {
            int kof = ks * 32 + lg * 8;
            bf16x8 af[4], bf[4];
            #pragma unroll
            for (int f = 0; f < 4; ++f) {
                af[f] = *(const bf16x8*)&AhS[swz(wr * 64 + f * 16 + sl, kof)];
                bf[f] = *(const bf16x8*)&BhS[swz(wc * 64 + f * 16 + sl, kof)];
            }
            #pragma unroll
            for (int fm = 0; fm < 4; ++fm)
                #pragma unroll
                for (int fn = 0; fn < 4; ++fn)
                    acc[fm][fn] = __builtin_amdgcn_mfma_f32_16x16x32_bf16(af[fm], bf[fn], acc[fm][fn], 0, 0, 0);
        }
    }

    // C write (bf16)
    #pragma unroll
    for (int fm = 0; fm < 4; ++fm)
        #pragma unroll
        for (int r = 0; r < 4; ++r) {
            int row = rowBase + wr * 64 + fm * 16 + lg * 4 + r;
            if (row >= M) continue;
            #pragma unroll
            for (int fn = 0; fn < 4; ++fn) {
                int col = wc * 64 + fn * 16 + sl;
                Cout[(size_t)row * LATENT + col] = f2bf(acc[fm][fn][r]);
            }
        }

    // fused rowdots: per-row dot with a_self / a_nb (all lanes active, uniform)
    float as_[4], an_[4];
    #pragma unroll
    for (int fn = 0; fn < 4; ++fn) {
        int col = wc * 64 + fn * 16 + sl;
        as_[fn] = avs[col];
        an_[fn] = avn[col];
    }
    #pragma unroll
    for (int fm = 0; fm < 4; ++fm)
        #pragma unroll
        for (int r = 0; r < 4; ++r) {
            float p1 = 0.f, p2 = 0.f;
            #pragma unroll
            for (int fn = 0; fn < 4; ++fn) {
                float v = acc[fm][fn][r];
                p1 += v * as_[fn];
                p2 += v * an_[fn];
            }
            #pragma unroll
            for (int o = 1; o <= 8; o <<= 1) {
                p1 += __shfl_xor(p1, o);
                p2 += __shfl_xor(p2, o);
            }
            if (sl == 0) {
                int row_l = wr * 64 + fm * 16 + lg * 4 + r;
                atomicAdd(&dotL[row_l][0], p1);
                atomicAdd(&dotL[row_l][1], p2);
            }
        }
    __syncthreads();
    if (tid < BM) {
        int row = rowBase + tid;
        if (row < M) {
            asf[side * M + row] = dotL[tid][0];
            anb[side * M + row] = dotL[tid][1];
        }
    }
}

// ---------------------------------------------------------------------------
// Fused GEMM2+GEMM3: H3 = elu(H2@W2a + S@W2s + b2) kept in LDS (bf16),
// then OUT = elu(H3@W3) + H4, f32. Both sides via blockIdx.z. LDS 48KB.
// ---------------------------------------------------------------------------
__global__ __launch_bounds__(256)
void gemm_fused23(const unsigned short* __restrict__ H2b,
                  const float* __restrict__ Su, const float* __restrict__ Sb,
                  const unsigned short* __restrict__ wspb,
                  const float* __restrict__ b2u, const float* __restrict__ b2b,
                  const float* __restrict__ H4u, const float* __restrict__ H4b,
                  float* __restrict__ Uo, float* __restrict__ Bo, int M)
{
    __shared__ unsigned short sm[BM * BK * 2];   // AhS/BhS; H3S overlays (32KB)
    __shared__ unsigned short W3S[64 * 128];     // 16KB
    unsigned short* AhS = sm;
    unsigned short* BhS = sm + BM * BK;

    const int side = blockIdx.z;
    const unsigned short* Bside = wspb + (size_t)side * WSP_SIDE;
    const float* bias = side ? b2b : b2u;
    const float* H4 = side ? H4b : H4u;
    float* Cout = side ? Bo : Uo;

    const int tid = threadIdx.x;
    const int rowBase = blockIdx.x * BM;
    const int wave = tid >> 6, lane = tid & 63;
    const int wr = wave >> 1, wc = wave & 1;
    const int sl = lane & 15, lg = lane >> 4;

    // preload W3 [64][128] k-major (swizzled); region untouched by main loop
    {
        const unsigned short* w3 = Bside + 81920;
        #pragma unroll
        for (int p = 0; p < 4; ++p) {
            int i = p * 256 + tid;        // 1024 chunks of 8
            int n = i >> 4;               // 0..63
            int kq = (i & 15) << 3;       // 0..120
            u16x8 v = *(const u16x8*)(w3 + (size_t)n * 128 + kq);
            *(u16x8*)&W3S[swz2(n, kq)] = v;
        }
    }

    f32x4 acc[4][4] = {};

    const void* Ap; const unsigned short* Bp; int K, af32;
    for (int pass = 0; pass < 2; ++pass) {
        if (pass == 0) {
            Ap = H2b + (size_t)side * HSTRIDE; af32 = 0; K = LATENT; Bp = Bside + 32768;   // W2a
        } else {
            Ap = side ? (const void*)Sb : (const void*)Su; af32 = 1; K = IN_DIM; Bp = Bside + 49152; // W2s
        }
        for (int k0 = 0; k0 < K; k0 += BK) {
            __syncthreads();
            #pragma unroll
            for (int p = 0; p < 4; ++p) {
                int q = p * 256 + tid;
                int row = q >> 3;
                int kq = (q & 7) << 3;
                int grow = rowBase + row;
                u16x8 hv = {0, 0, 0, 0, 0, 0, 0, 0};
                if (grow < M) {
                    if (af32) {
                        const float* a = (const float*)Ap + (size_t)grow * K + k0 + kq;
                        float4 v0 = *(const float4*)a;
                        float4 v1 = *(const float4*)(a + 4);
                        hv[0] = f2bf(v0.x); hv[1] = f2bf(v0.y); hv[2] = f2bf(v0.z); hv[3] = f2bf(v0.w);
                        hv[4] = f2bf(v1.x); hv[5] = f2bf(v1.y); hv[6] = f2bf(v1.z); hv[7] = f2bf(v1.w);
                    } else {
                        hv = *(const u16x8*)((const unsigned short*)Ap + (size_t)grow * K + k0 + kq);
                    }
                }
                *(u16x8*)&AhS[swz(row, kq)] = hv;
            }
            #pragma unroll
            for (int p = 0; p < 4; ++p) {
                int q = p * 256 + tid;
                int n = q >> 3;
                int kq = (q & 7) << 3;
                u16x8 hv = *(const u16x8*)(Bp + (size_t)n * K + k0 + kq);
                *(u16x8*)&BhS[swz(n, kq)] = hv;
            }
            __syncthreads();
            #pragma unroll
            for (int ks = 0; ks < 2; ++ks) {
                int kof = ks * 32 + lg * 8;
                bf16x8 af[4], bf[4];
                #pragma unroll
                for (int f = 0; f < 4; ++f) {
                    af[f] = *(const bf16x8*)&AhS[swz(wr * 64 + f * 16 + sl, kof)];
                    bf[f] = *(const bf16x8*)&BhS[swz(wc * 64 + f * 16 + sl, kof)];
                }
                #pragma unroll
                for (int fm = 0; fm < 4; ++fm)
                    #pragma unroll
                    for (int fn = 0; fn < 4; ++fn)
                        acc[fm][fn] = __builtin_amdgcn_mfma_f32_16x16x32_bf16(af[fm], bf[fn], acc[fm][fn], 0, 0, 0);
            }
        }
    }

    __syncthreads();   // main-loop LDS reads done; reuse sm as H3S
    unsigned short* H3S = sm;   // [128][128] bf16, swz2

    // epilogue 1: H3 = elu(acc + b2) -> LDS
    #pragma unroll
    for (int fm = 0; fm < 4; ++fm)
        #pragma unroll
        for (int r = 0; r < 4; ++r) {
            int row_l = wr * 64 + fm * 16 + lg * 4 + r;
            #pragma unroll
            for (int fn = 0; fn < 4; ++fn) {
                int col = wc * 64 + fn * 16 + sl;
                float v = acc[fm][fn][r] + bias[col];
                v = v > 0.f ? v : (__expf(v) - 1.f);
                H3S[swz2(row_l, col)] = f2bf(v);
            }
        }
    __syncthreads();

    // matmul2: OUT[128][64] = H3 @ W3, K=128
    f32x4 acc2[4][2] = {};
    #pragma unroll
    for (int ks = 0; ks < 4; ++ks) {
        int kof = ks * 32 + lg * 8;
        bf16x8 a2[4], b2f[2];
        #pragma unroll
        for (int f = 0; f < 4; ++f)
            a2[f] = *(const bf16x8*)&H3S[swz2(wr * 64 + f * 16 + sl, kof)];
        #pragma unroll
        for (int f = 0; f < 2; ++f)
            b2f[f] = *(const bf16x8*)&W3S[swz2(wc * 32 + f * 16 + sl, kof)];
        #pragma unroll
        for (int fm = 0; fm < 4; ++fm)
            #pragma unroll
            for (int fn = 0; fn < 2; ++fn)
                acc2[fm][fn] = __builtin_amdgcn_mfma_f32_16x16x32_bf16(a2[fm], b2f[fn], acc2[fm][fn], 0, 0, 0);
    }

    // epilogue 2: OUT = elu(acc2) + H4
    #pragma unroll
    for (int fm = 0; fm < 4; ++fm)
        #pragma unroll
        for (int r = 0; r < 4; ++r) {
            int row = rowBase + wr * 64 + fm * 16 + lg * 4 + r;
            if (row >= M) continue;
            #pragma unroll
            for (int fn = 0; fn < 2; ++fn) {
                int col = wc * 32 + fn * 16 + sl;
                float v = acc2[fm][fn][r];
                v = v > 0.f ? v : (__expf(v) - 1.f);
                v += H4[(size_t)row * FINALD + col];
                Cout[(size_t)row * FINALD + col] = v;
            }
        }
}

// ---------------------------------------------------------------------------
// Unified atomic-free bucketed counting sort over ALL 4 graphs.
// ---------------------------------------------------------------------------
__device__ inline void edge_decomp(int i, int& side, int& g, int& idx) {
    if (i < NEDGE)          { side = 0; g = 0; idx = i; }
    else if (i < 2 * NEDGE) { side = 0; g = 1; idx = i - NEDGE; }
    else if (i < 3 * NEDGE) { side = 1; g = 0; idx = i - 2 * NEDGE; }
    else                    { side = 1; g = 1; idx = i - 3 * NEDGE; }
}

__global__ __launch_bounds__(256)
void part_count(const int* __restrict__ eU, const int* __restrict__ eB,
                int* __restrict__ pcnt)
{
    __shared__ int h[NBU];
    int tid = threadIdx.x;
    for (int i = tid; i < NBU; i += 256) h[i] = 0;
    __syncthreads();
    int start = blockIdx.x * PCH;
    int stop  = min(start + PCH, E4);
    for (int i = start + tid; i < stop; i += 256) {
        int side, g, idx;
        edge_decomp(i, side, g, idx);
        const int* base = side ? eB : eU;
        int dst = base[(size_t)(2 * g + 1) * NEDGE + idx];
        int vd = side * (2 * N_NODES) + g * N_NODES + dst;
        atomicAdd(&h[vd >> 8], 1);
    }
    __syncthreads();
    for (int i = tid; i < NBU; i += 256)
        pcnt[i * NPB + blockIdx.x] = h[i];
}

__global__ __launch_bounds__(1024)
void part_scan(const int* __restrict__ pcnt, int* __restrict__ pbase,
               int* __restrict__ bbase, int* __restrict__ offs)
{
    __shared__ int btot[NBU];
    __shared__ int wsum2[16];
    int tid = threadIdx.x;
    int lane = tid & 63, w = tid >> 6;           // 16 waves
    for (int b = w; b < NBU; b += 16) {
        int4 v = *(const int4*)&pcnt[b * NPB + lane * 4];
        int s = v.x + v.y + v.z + v.w;
        int x = s;
        #pragma unroll
        for (int o = 1; o < 64; o <<= 1) {
            int y = __shfl_up(x, o);
            if (lane >= o) x += y;
        }
        int ex = x - s;
        int* pb = &pbase[b * NPB + lane * 4];
        pb[0] = ex;
        pb[1] = ex + v.x;
        pb[2] = ex + v.x + v.y;
        pb[3] = ex + v.x + v.y + v.z;
        if (lane == 63) btot[b] = x;
    }
    __syncthreads();
    int v = (tid < NBU) ? btot[tid] : 0;
    int x = v;
    #pragma unroll
    for (int o = 1; o < 64; o <<= 1) {
        int y = __shfl_up(x, o);
        if (lane >= o) x += y;
    }
    if (lane == 63) wsum2[w] = x;
    __syncthreads();
    int wb = 0;
    for (int i = 0; i < w; ++i) wb += wsum2[i];
    int ex = wb + x - v;
    if (tid < NBU) bbase[tid] = ex;
    if (tid == NBU - 1) bbase[NBU] = ex + v;
    if (tid == 0) offs[VN4] = E4;
}

__global__ __launch_bounds__(256)
void part_fill(const int* __restrict__ eU, const int* __restrict__ eB,
               const int* __restrict__ pbase, const int* __restrict__ bbase,
               int* __restrict__ ebuf)
{
    __shared__ int lbase[NBU];
    __shared__ int lcur[NBU];
    int tid = threadIdx.x;
    for (int i = tid; i < NBU; i += 256) {
        lbase[i] = bbase[i] + pbase[i * NPB + blockIdx.x];
        lcur[i] = 0;
    }
    __syncthreads();
    int start = blockIdx.x * PCH;
    int stop  = min(start + PCH, E4);
    for (int i = start + tid; i < stop; i += 256) {
        int side, g, idx;
        edge_decomp(i, side, g, idx);
        const int* base = side ? eB : eU;
        int src = base[(size_t)(2 * g) * NEDGE + idx];
        int dst = base[(size_t)(2 * g + 1) * NEDGE + idx];
        int vd = side * (2 * N_NODES) + g * N_NODES + dst;
        int b = vd >> 8;
        int p = lbase[b] + atomicAdd(&lcur[b], 1);
        ebuf[p] = ((vd & 255) << 16) | src;
    }
}

__global__ __launch_bounds__(256)
void bucket_csr(const int* __restrict__ ebuf, const int* __restrict__ bbase,
                int* __restrict__ offs, unsigned short* __restrict__ csr)
{
    __shared__ int lds_e[BCAP];
    __shared__ int cnt[256];
    __shared__ int excl[256];
    __shared__ int cur[256];
    __shared__ int wsum[4];
    int tid = threadIdx.x;
    int b = blockIdx.x;
    int lo = bbase[b], hi = bbase[b + 1];
    int sz = hi - lo;

    cnt[tid] = 0; cur[tid] = 0;
    __syncthreads();
    for (int i = tid; i < sz; i += 256) {
        int v = ebuf[lo + i];
        if (i < BCAP) lds_e[i] = v;
        atomicAdd(&cnt[v >> 16], 1);
    }
    __syncthreads();

    int lane = tid & 63, w = tid >> 6;
    int v = cnt[tid];
    int x = v;
    #pragma unroll
    for (int o = 1; o < 64; o <<= 1) {
        int y = __shfl_up(x, o);
        if (lane >= o) x += y;
    }
    if (lane == 63) wsum[w] = x;
    __syncthreads();
    int wb = 0;
    for (int i = 0; i < w; ++i) wb += wsum[i];
    int ex = wb + x - v;
    excl[tid] = ex;
    int vd = b * 256 + tid;
    if (vd < VN4) offs[vd] = lo + ex;
    __syncthreads();

    for (int i = tid; i < sz; i += 256) {
        int e = (i < BCAP) ? lds_e[i] : ebuf[lo + i];
        int dl = e >> 16;
        int p = excl[dl] + atomicAdd(&cur[dl], 1);
        csr[lo + p] = (unsigned short)(e & 0xFFFF);
    }
}

// ---------------------------------------------------------------------------
// GAT aggregation (round-10 proven structure): single pass, deferred
// normalization, 16-lane groups, 2-deep pipeline, inline score recompute.
// ---------------------------------------------------------------------------
__global__ __launch_bounds__(256)
void gat_gather(const unsigned short* __restrict__ H1b, const float* __restrict__ asf,
                const float* __restrict__ anb,
                const int* __restrict__ offs, const unsigned short* __restrict__ csr,
                const float* __restrict__ omu, const float* __restrict__ omb,
                unsigned short* __restrict__ H2b, int n)
{
    int side = blockIdx.y;
    int lane = threadIdx.x & 63, wid = threadIdx.x >> 6;
    int d = blockIdx.x * 4 + wid;
    if (d >= n) return;
    const unsigned short* Hbase = H1b + (size_t)side * HSTRIDE;
    const int* offside = offs + side * 2 * N_NODES;
    const float* om_p = side ? omb : omu;
    float ad = asf[side * n + d];
    const float* anb_s = anb + side * n;
    int sub = lane >> 4, sl = lane & 15;
    const unsigned short* Hp = Hbase + (sl << 3);
    float fin[8] = {};

    #pragma unroll
    for (int g = 0; g < NGRAPH; ++g) {
        int beg = offside[g * n + d], end = offside[g * n + d + 1];
        float om = om_p[g];
        float un[8] = {};
        float ss = 0.f;

        int e = beg + sub;
        for (; e + 4 < end; e += 8) {
            int s0 = csr[e], s1 = csr[e + 4];
            float a0 = anb_s[s0], a1 = anb_s[s1];
            u16x8 h0 = *(const u16x8*)(Hp + (size_t)s0 * LATENT);
            u16x8 h1 = *(const u16x8*)(Hp + (size_t)s1 * LATENT);
            float sc0 = ad + a0; sc0 = fmaxf(sc0, 0.2f * sc0);
            float sc1 = ad + a1; sc1 = fmaxf(sc1, 0.2f * sc1);
            float w0 = __expf(sc0), w1 = __expf(sc1);
            ss += w0 + w1;
            #pragma unroll
            for (int j = 0; j < 8; ++j) un[j] += w0 * bf2f(h0[j]);
            #pragma unroll
            for (int j = 0; j < 8; ++j) un[j] += w1 * bf2f(h1[j]);
        }
        if (e < end) {
            int s0 = csr[e];
            float a0 = anb_s[s0];
            u16x8 h0 = *(const u16x8*)(Hp + (size_t)s0 * LATENT);
            float sc0 = ad + a0; sc0 = fmaxf(sc0, 0.2f * sc0);
            float w0 = __expf(sc0);
            ss += w0;
            #pragma unroll
            for (int j = 0; j < 8; ++j) un[j] += w0 * bf2f(h0[j]);
        }

        // cross-group sum of exp (groups hold disjoint edge subsets)
        ss += __shfl_xor(ss, 32);
        ss += __shfl_xor(ss, 16);
        float wsc = om / (ss + 1e-16f);
        #pragma unroll
        for (int j = 0; j < 8; ++j) fin[j] += wsc * un[j];
    }

    #pragma unroll
    for (int j = 0; j < 8; ++j) {
        fin[j] += __shfl_xor(fin[j], 32);
        fin[j] += __shfl_xor(fin[j], 16);
    }
    if (sub == 0) {
        u16x8 o;
        #pragma unroll
        for (int j = 0; j < 8; ++j) o[j] = f2bf(fin[j]);
        *(u16x8*)(H2b + (size_t)side * HSTRIDE + (size_t)d * LATENT + sl * 8) = o;
    }
}

// ---------------------------------------------------------------------------
__global__ __launch_bounds__(256)
void predict(const int* __restrict__ uid, const int* __restrict__ iid,
             const float* __restrict__ U, const float* __restrict__ B,
             const float* __restrict__ bu, const float* __restrict__ bb,
             const float* __restrict__ bx, float* __restrict__ out, int batch)
{
    int lane = threadIdx.x & 63, wid = threadIdx.x >> 6;
    int b = blockIdx.x * 4 + wid;
    if (b >= batch) return;
    int u = uid[b], it = iid[b];
    float p = U[(size_t)u * FINALD + lane] * B[(size_t)it * FINALD + lane];
    #pragma unroll
    for (int o = 32; o; o >>= 1) p += __shfl_xor(p, o);
    if (lane == 0) {
        float raw = p + bu[u] + bb[it] + bx[0];
        out[b] = 4.f * (1.f / (1.f + __expf(-raw))) + 1.f;
    }
}

// ---------------------------------------------------------------------------
extern "C" void kernel_launch(void* const* d_in, const int* in_sizes, int n_in,
                              void* d_out, int out_size, void* d_ws, size_t ws_size,
                              hipStream_t stream)
{
    const int N = N_NODES;

    float* ws = (float*)d_ws;
    unsigned short* H1b = (unsigned short*)ws;           // 2 sides bf16 (12.8e6 ush)
    unsigned short* H2b = (unsigned short*)(ws + 6400000);
    float* U_all = ws + 12800000;
    float* B_all = ws + 16000000;
    float* asf   = ws + 19200000;                        // [2][N]
    float* anb   = asf + 2 * N;                          // [2][N]
    int*   offs  = (int*)(anb + 2 * N);                  // VN4+1
    int*   bbase = offs + VN4 + 1;                       // NBU+1
    unsigned short* csr = (unsigned short*)(bbase + NBU + 1);  // E4 ushorts
    unsigned short* wsp = (unsigned short*)(((uintptr_t)(csr + E4) + 15) & ~(uintptr_t)15);
    int*   ebuf  = (int*)H2b;                            // E4 ints (dead before gather)
    int*   pcnt  = (int*)U_all;                          // NBU*NPB
    int*   pbase = pcnt + NBU * NPB;                     // NBU*NPB

    prep_weights<<<(2 * WSP_SIDE + 255) / 256, 256, 0, stream>>>(
        (const float*)d_in[6],  (const float*)d_in[14], (const float*)d_in[15], (const float*)d_in[20],
        (const float*)d_in[10], (const float*)d_in[17], (const float*)d_in[18], (const float*)d_in[21],
        wsp);

    const int* eU = (const int*)d_in[4];
    const int* eB = (const int*)d_in[5];
    part_count<<<NPB, 256, 0, stream>>>(eU, eB, pcnt);
    part_scan<<<1, 1024, 0, stream>>>(pcnt, pbase, bbase, offs);
    part_fill<<<NPB, 256, 0, stream>>>(eU, eB, pbase, bbase, ebuf);
    bucket_csr<<<NBU, 256, 0, stream>>>(ebuf, bbase, offs, csr);

    const float* Su = (const float*)d_in[2];
    const float* Sb = (const float*)d_in[3];
    dim3 gG(391, 1, 2);

    // H1 GEMM + fused rowdots
    gemm_h1<<<gG, 256, 0, stream>>>(
        Su, Sb, wsp,
        (const float*)d_in[7], (const float*)d_in[8],
        (const float*)d_in[11], (const float*)d_in[12],
        H1b, asf, anb, N);

    // aggregation, both sides
    gat_gather<<<dim3(N / 4, 2), 256, 0, stream>>>(
        H1b, asf, anb, offs, csr,
        (const float*)d_in[9], (const float*)d_in[13], H2b, N);

    // fused H3 GEMM + final GEMM
    gemm_fused23<<<gG, 256, 0, stream>>>(
        H2b, Su, Sb, wsp,
        (const float*)d_in[16], (const float*)d_in[19],
        (const float*)d_in[22], (const float*)d_in[23],
        U_all, B_all, N);

    predict<<<BATCHSZ / 4, 256, 0, stream>>>(
        (const int*)d_in[0], (const int*)d_in[1], U_all, B_all,
        (const float*)d_in[24], (const float*)d_in[25], (const float*)d_in[26],
        (float*)d_out, BATCHSZ);
}

// Round 14
// 320.730 us; speedup vs baseline: 3.0768x; 1.0734x over previous
//
#include <hip/hip_runtime.h>
#include <math.h>

#define N_NODES 50000
#define IN_DIM  256
#define LATENT  128
#define FINALD  64
#define NGRAPH  2
#define NEDGE   1000000
#define BATCHSZ 16384

#define VN4     (4 * N_NODES)          // unified virtual dst ids: side*2N + g*N + dst
#define NBU     ((VN4 + 255) >> 8)     // 782 buckets of 256 vds
#define E4      (4 * NEDGE)
#define NPB     256                    // partition blocks
#define PCH     ((E4 + NPB - 1) / NPB) // 15625 edges per partition block
#define BCAP    8192                   // bucket_csr LDS cache entries
#define PREPB   768                    // prep blocks: 2*WSP_SIDE/256

// weights per side: W1[128][256]bf16 W2a[128][128]f16 W2s[128][256]bf16 W3pad[128][128]bf16
#define WSP_SIDE   98304
#define HSTRIDE    (N_NODES * LATENT)  // per-side ushort stride for H1h/H2h

typedef __attribute__((ext_vector_type(8))) short bf16x8;
typedef __attribute__((ext_vector_type(8))) _Float16 f16x8;
typedef __attribute__((ext_vector_type(4))) float f32x4;
typedef __attribute__((ext_vector_type(8))) unsigned short u16x8;

__device__ inline unsigned short f2bf(float x) {
    unsigned int u = __float_as_uint(x);
    u = (u + 0x7fffu + ((u >> 16) & 1u)) >> 16;
    return (unsigned short)u;
}
__device__ inline float bf2f(unsigned short h) {
    return __uint_as_float(((unsigned int)h) << 16);
}
__device__ inline f16x8 splat8(float x) {
    _Float16 h = (_Float16)x;
    f16x8 v = {h, h, h, h, h, h, h, h};
    return v;
}

#define BM 128
#define BK 64

__device__ inline int swz(int r, int k) {      // [*][64] tiles
    return r * BK + ((((k >> 3) ^ (r & 7)) << 3) | (k & 7));
}
__device__ inline int swz2(int r, int c) {     // [*][128] tiles
    return r * 128 + ((((c >> 3) ^ (r & 7)) << 3) | (c & 7));
}

__device__ inline void edge_decomp(int i, int& side, int& g, int& idx) {
    if (i < NEDGE)          { side = 0; g = 0; idx = i; }
    else if (i < 2 * NEDGE) { side = 0; g = 1; idx = i - NEDGE; }
    else if (i < 3 * NEDGE) { side = 1; g = 0; idx = i - 2 * NEDGE; }
    else                    { side = 1; g = 1; idx = i - 3 * NEDGE; }
}

// ---------------------------------------------------------------------------
// FAT1: part_count (blocks 0..NPB) || prep_weights (blocks NPB..NPB+PREPB)
// ---------------------------------------------------------------------------
__global__ __launch_bounds__(256)
void fat_count_prep(const int* __restrict__ eU, const int* __restrict__ eB,
                    int* __restrict__ pcnt,
                    const float* __restrict__ W1u, const float* __restrict__ Wu2,
                    const float* __restrict__ Wus2, const float* __restrict__ Wu3,
                    const float* __restrict__ W1b, const float* __restrict__ Wb2,
                    const float* __restrict__ Wbs2, const float* __restrict__ Wb3,
                    unsigned short* __restrict__ dst)
{
    __shared__ int h[NBU];
    int tid = threadIdx.x;
    if (blockIdx.x < NPB) {
        // ----- part_count -----
        for (int i = tid; i < NBU; i += 256) h[i] = 0;
        __syncthreads();
        int start = blockIdx.x * PCH;
        int stop  = min(start + PCH, E4);
        for (int i = start + tid; i < stop; i += 256) {
            int side, g, idx;
            edge_decomp(i, side, g, idx);
            const int* base = side ? eB : eU;
            int d = base[(size_t)(2 * g + 1) * NEDGE + idx];
            int vd = side * (2 * N_NODES) + g * N_NODES + d;
            atomicAdd(&h[vd >> 8], 1);
        }
        __syncthreads();
        for (int i = tid; i < NBU; i += 256)
            pcnt[i * NPB + blockIdx.x] = h[i];
    } else {
        // ----- prep_weights: W2a slot -> f16, others bf16 -----
        int e = (blockIdx.x - NPB) * 256 + tid;
        if (e >= 2 * WSP_SIDE) return;
        int side = e >= WSP_SIDE;
        int r = e - (side ? WSP_SIDE : 0);
        const float* src; int K, hoff; int w3 = 0, fp16 = 0;
        if (r < 32768)      { src = side ? W1b  : W1u;  K = 256; hoff = 0;     }
        else if (r < 49152) { src = side ? Wb2  : Wu2;  K = 128; hoff = 32768; r -= 32768; fp16 = 1; }
        else if (r < 81920) { src = side ? Wbs2 : Wus2; K = 256; hoff = 49152; r -= 49152; }
        else                { src = side ? Wb3  : Wu3;  K = 128; hoff = 81920; r -= 81920; w3 = 1; }
        int n = (K == 256) ? (r >> 8) : (r >> 7);
        int k = (K == 256) ? (r & 255) : (r & 127);
        float x;
        if (w3) x = (n < 64) ? src[k * 64 + n] : 0.f;
        else    x = src[k * 128 + n];
        unsigned short o;
        if (fp16) { _Float16 hx = (_Float16)x; o = *(unsigned short*)&hx; }
        else      o = f2bf(x);
        dst[(size_t)side * WSP_SIDE + hoff + n * K + k] = o;
    }
}

// ---------------------------------------------------------------------------
__global__ __launch_bounds__(1024)
void part_scan(const int* __restrict__ pcnt, int* __restrict__ pbase,
               int* __restrict__ bbase, int* __restrict__ offs)
{
    __shared__ int btot[NBU];
    __shared__ int wsum2[16];
    int tid = threadIdx.x;
    int lane = tid & 63, w = tid >> 6;           // 16 waves
    for (int b = w; b < NBU; b += 16) {
        int4 v = *(const int4*)&pcnt[b * NPB + lane * 4];
        int s = v.x + v.y + v.z + v.w;
        int x = s;
        #pragma unroll
        for (int o = 1; o < 64; o <<= 1) {
            int y = __shfl_up(x, o);
            if (lane >= o) x += y;
        }
        int ex = x - s;
        int* pb = &pbase[b * NPB + lane * 4];
        pb[0] = ex;
        pb[1] = ex + v.x;
        pb[2] = ex + v.x + v.y;
        pb[3] = ex + v.x + v.y + v.z;
        if (lane == 63) btot[b] = x;
    }
    __syncthreads();
    int v = (tid < NBU) ? btot[tid] : 0;
    int x = v;
    #pragma unroll
    for (int o = 1; o < 64; o <<= 1) {
        int y = __shfl_up(x, o);
        if (lane >= o) x += y;
    }
    if (lane == 63) wsum2[w] = x;
    __syncthreads();
    int wb = 0;
    for (int i = 0; i < w; ++i) wb += wsum2[i];
    int ex = wb + x - v;
    if (tid < NBU) bbase[tid] = ex;
    if (tid == NBU - 1) bbase[NBU] = ex + v;
    if (tid == 0) offs[VN4] = E4;
}

// ---------------------------------------------------------------------------
// FAT2: part_fill (blocks 0..NPB) || gemm_h1+rowdots (blocks NPB..NPB+782).
// gemm_h1: H1h = f16(S @ W1) (bf16 MFMA), fused asf/anb row-dots.
// ---------------------------------------------------------------------------
__global__ __launch_bounds__(256)
void fat_fill_gemm1(const int* __restrict__ eU, const int* __restrict__ eB,
                    const int* __restrict__ pbase, const int* __restrict__ bbase,
                    int* __restrict__ ebuf,
                    const float* __restrict__ Su, const float* __restrict__ Sb,
                    const unsigned short* __restrict__ wspb,
                    const float* __restrict__ aself_u, const float* __restrict__ anbv_u,
                    const float* __restrict__ aself_b, const float* __restrict__ anbv_b,
                    unsigned short* __restrict__ H1h, float* __restrict__ asf,
                    float* __restrict__ anb, int M)
{
    __shared__ unsigned short AhS[BM * BK];
    __shared__ unsigned short BhS[BM * BK];
    __shared__ float dotL[BM][2];
    __shared__ int lbase[NBU];
    __shared__ int lcur[NBU];

    int tid = threadIdx.x;

    if (blockIdx.x < NPB) {
        // ----- part_fill -----
        for (int i = tid; i < NBU; i += 256) {
            lbase[i] = bbase[i] + pbase[i * NPB + blockIdx.x];
            lcur[i] = 0;
        }
        __syncthreads();
        int start = blockIdx.x * PCH;
        int stop  = min(start + PCH, E4);
        for (int i = start + tid; i < stop; i += 256) {
            int side, g, idx;
            edge_decomp(i, side, g, idx);
            const int* base = side ? eB : eU;
            int src = base[(size_t)(2 * g) * NEDGE + idx];
            int d = base[(size_t)(2 * g + 1) * NEDGE + idx];
            int vd = side * (2 * N_NODES) + g * N_NODES + d;
            int b = vd >> 8;
            int p = lbase[b] + atomicAdd(&lcur[b], 1);
            ebuf[p] = ((vd & 255) << 16) | src;
        }
        return;
    }

    // ----- gemm_h1 -----
    int t = blockIdx.x - NPB;             // 0..781
    const int side = t / 391;
    const int rowBase = (t % 391) * BM;
    const float* Ap = side ? Sb : Su;
    const unsigned short* Bp = wspb + (size_t)side * WSP_SIDE;   // W1 slot (bf16)
    const float* avs = side ? aself_b : aself_u;
    const float* avn = side ? anbv_b : anbv_u;
    _Float16* Cout = (_Float16*)(H1h + (size_t)side * HSTRIDE);

    const int wave = tid >> 6, lane = tid & 63;
    const int wr = wave >> 1, wc = wave & 1;
    const int sl = lane & 15, lg = lane >> 4;
    const int K = IN_DIM;

    if (tid < BM) { dotL[tid][0] = 0.f; dotL[tid][1] = 0.f; }

    f32x4 acc[4][4] = {};

    for (int k0 = 0; k0 < K; k0 += BK) {
        __syncthreads();
        #pragma unroll
        for (int p = 0; p < 4; ++p) {
            int q = p * 256 + tid;
            int row = q >> 3;
            int kq = (q & 7) << 3;
            int grow = rowBase + row;
            u16x8 hv = {0, 0, 0, 0, 0, 0, 0, 0};
            if (grow < M) {
                const float* a = Ap + (size_t)grow * K + k0 + kq;
                float4 v0 = *(const float4*)a;
                float4 v1 = *(const float4*)(a + 4);
                hv[0] = f2bf(v0.x); hv[1] = f2bf(v0.y); hv[2] = f2bf(v0.z); hv[3] = f2bf(v0.w);
                hv[4] = f2bf(v1.x); hv[5] = f2bf(v1.y); hv[6] = f2bf(v1.z); hv[7] = f2bf(v1.w);
            }
            *(u16x8*)&AhS[swz(row, kq)] = hv;
        }
        #pragma unroll
        for (int p = 0; p < 4; ++p) {
            int q = p * 256 + tid;
            int n = q >> 3;
            int kq = (q & 7) << 3;
            u16x8 hv = *(const u16x8*)(Bp + (size_t)n * K + k0 + kq);
            *(u16x8*)&BhS[swz(n, kq)] = hv;
        }
        __syncthreads();
        #pragma unroll
        for (int ks = 0; ks < 2; ++ks) {
            int kof = ks * 32 + lg * 8;
            bf16x8 af[4], bf[4];
            #pragma unroll
            for (int f = 0; f < 4; ++f) {
                af[f] = *(const bf16x8*)&AhS[swz(wr * 64 + f * 16 + sl, kof)];
                bf[f] = *(const bf16x8*)&BhS[swz(wc * 64 + f * 16 + sl, kof)];
            }
            #pragma unroll
            for (int fm = 0; fm < 4; ++fm)
                #pragma unroll
                for (int fn = 0; fn < 4; ++fn)
                    acc[fm][fn] = __builtin_amdgcn_mfma_f32_16x16x32_bf16(af[fm], bf[fn], acc[fm][fn], 0, 0, 0);
        }
    }

    // C write (f16)
    #pragma unroll
    for (int fm = 0; fm < 4; ++fm)
        #pragma unroll
        for (int r = 0; r < 4; ++r) {
            int row = rowBase + wr * 64 + fm * 16 + lg * 4 + r;
            if (row >= M) continue;
            #pragma unroll
            for (int fn = 0; fn < 4; ++fn) {
                int col = wc * 64 + fn * 16 + sl;
                Cout[(size_t)row * LATENT + col] = (_Float16)acc[fm][fn][r];
            }
        }

    // fused rowdots
    float as_[4], an_[4];
    #pragma unroll
    for (int fn = 0; fn < 4; ++fn) {
        int col = wc * 64 + fn * 16 + sl;
        as_[fn] = avs[col];
        an_[fn] = avn[col];
    }
    #pragma unroll
    for (int fm = 0; fm < 4; ++fm)
        #pragma unroll
        for (int r = 0; r < 4; ++r) {
            float p1 = 0.f, p2 = 0.f;
            #pragma unroll
            for (int fn = 0; fn < 4; ++fn) {
                float v = acc[fm][fn][r];
                p1 += v * as_[fn];
                p2 += v * an_[fn];
            }
            #pragma unroll
            for (int o = 1; o <= 8; o <<= 1) {
                p1 += __shfl_xor(p1, o);
                p2 += __shfl_xor(p2, o);
            }
            if (sl == 0) {
                int row_l = wr * 64 + fm * 16 + lg * 4 + r;
                atomicAdd(&dotL[row_l][0], p1);
                atomicAdd(&dotL[row_l][1], p2);
            }
        }
    __syncthreads();
    if (tid < BM) {
        int row = rowBase + tid;
        if (row < M) {
            asf[side * M + row] = dotL[tid][0];
            anb[side * M + row] = dotL[tid][1];
        }
    }
}

// ---------------------------------------------------------------------------
__global__ __launch_bounds__(256)
void bucket_csr(const int* __restrict__ ebuf, const int* __restrict__ bbase,
                int* __restrict__ offs, unsigned short* __restrict__ csr)
{
    __shared__ int lds_e[BCAP];
    __shared__ int cnt[256];
    __shared__ int excl[256];
    __shared__ int cur[256];
    __shared__ int wsum[4];
    int tid = threadIdx.x;
    int b = blockIdx.x;
    int lo = bbase[b], hi = bbase[b + 1];
    int sz = hi - lo;

    cnt[tid] = 0; cur[tid] = 0;
    __syncthreads();
    for (int i = tid; i < sz; i += 256) {
        int v = ebuf[lo + i];
        if (i < BCAP) lds_e[i] = v;
        atomicAdd(&cnt[v >> 16], 1);
    }
    __syncthreads();

    int lane = tid & 63, w = tid >> 6;
    int v = cnt[tid];
    int x = v;
    #pragma unroll
    for (int o = 1; o < 64; o <<= 1) {
        int y = __shfl_up(x, o);
        if (lane >= o) x += y;
    }
    if (lane == 63) wsum[w] = x;
    __syncthreads();
    int wb = 0;
    for (int i = 0; i < w; ++i) wb += wsum[i];
    int ex = wb + x - v;
    excl[tid] = ex;
    int vd = b * 256 + tid;
    if (vd < VN4) offs[vd] = lo + ex;
    __syncthreads();

    for (int i = tid; i < sz; i += 256) {
        int e = (i < BCAP) ? lds_e[i] : ebuf[lo + i];
        int dl = e >> 16;
        int p = excl[dl] + atomicAdd(&cur[dl], 1);
        csr[lo + p] = (unsigned short)(e & 0xFFFF);
    }
}

// ---------------------------------------------------------------------------
// GAT aggregation: single pass, deferred normalization, 16-lane groups,
// 2-deep pipeline, inline score recompute, packed-f16 accumulate (v_pk_fma).
// H1/H2 stored f16.
// ---------------------------------------------------------------------------
__global__ __launch_bounds__(256)
void gat_gather(const unsigned short* __restrict__ H1h, const float* __restrict__ asf,
                const float* __restrict__ anb,
                const int* __restrict__ offs, const unsigned short* __restrict__ csr,
                const float* __restrict__ omu, const float* __restrict__ omb,
                unsigned short* __restrict__ H2h, int n)
{
    int side = blockIdx.y;
    int lane = threadIdx.x & 63, wid = threadIdx.x >> 6;
    int d = blockIdx.x * 4 + wid;
    if (d >= n) return;
    const unsigned short* Hbase = H1h + (size_t)side * HSTRIDE;
    const int* offside = offs + side * 2 * N_NODES;
    const float* om_p = side ? omb : omu;
    float ad = asf[side * n + d];
    const float* anb_s = anb + side * n;
    int sub = lane >> 4, sl = lane & 15;
    const unsigned short* Hp = Hbase + (sl << 3);
    float fin[8] = {};

    #pragma unroll
    for (int g = 0; g < NGRAPH; ++g) {
        int beg = offside[g * n + d], end = offside[g * n + d + 1];
        float om = om_p[g];
        f16x8 un8 = splat8(0.f);
        float ss = 0.f;

        int e = beg + sub;
        for (; e + 4 < end; e += 8) {
            int s0 = csr[e], s1 = csr[e + 4];
            float a0 = anb_s[s0], a1 = anb_s[s1];
            f16x8 h0 = *(const f16x8*)(Hp + (size_t)s0 * LATENT);
            f16x8 h1 = *(const f16x8*)(Hp + (size_t)s1 * LATENT);
            float sc0 = ad + a0; sc0 = fmaxf(sc0, 0.2f * sc0);
            float sc1 = ad + a1; sc1 = fmaxf(sc1, 0.2f * sc1);
            float w0 = __expf(sc0), w1 = __expf(sc1);
            ss += w0 + w1;
            un8 += splat8(w0) * h0;
            un8 += splat8(w1) * h1;
        }
        if (e < end) {
            int s0 = csr[e];
            float a0 = anb_s[s0];
            f16x8 h0 = *(const f16x8*)(Hp + (size_t)s0 * LATENT);
            float sc0 = ad + a0; sc0 = fmaxf(sc0, 0.2f * sc0);
            float w0 = __expf(sc0);
            ss += w0;
            un8 += splat8(w0) * h0;
        }

        // cross-group sum of exp (groups hold disjoint edge subsets)
        ss += __shfl_xor(ss, 32);
        ss += __shfl_xor(ss, 16);
        float wsc = om / (ss + 1e-16f);
        #pragma unroll
        for (int j = 0; j < 8; ++j) fin[j] += wsc * (float)un8[j];
    }

    #pragma unroll
    for (int j = 0; j < 8; ++j) {
        fin[j] += __shfl_xor(fin[j], 32);
        fin[j] += __shfl_xor(fin[j], 16);
    }
    if (sub == 0) {
        f16x8 o;
        #pragma unroll
        for (int j = 0; j < 8; ++j) o[j] = (_Float16)fin[j];
        *(f16x8*)(H2h + (size_t)side * HSTRIDE + (size_t)d * LATENT + sl * 8) = o;
    }
}

// ---------------------------------------------------------------------------
// Fused GEMM2+GEMM3: H3 = elu(H2@W2a + S@W2s + b2) in LDS (bf16), then
// OUT = elu(H3@W3) + H4. Pass0 f16 MFMA (H2/W2a f16), pass1 bf16.
// ---------------------------------------------------------------------------
__global__ __launch_bounds__(256)
void gemm_fused23(const unsigned short* __restrict__ H2h,
                  const float* __restrict__ Su, const float* __restrict__ Sb,
                  const unsigned short* __restrict__ wspb,
                  const float* __restrict__ b2u, const float* __restrict__ b2b,
                  const float* __restrict__ H4u, const float* __restrict__ H4b,
                  float* __restrict__ Uo, float* __restrict__ Bo, int M)
{
    __shared__ unsigned short sm[BM * BK * 2];   // AhS/BhS; H3S overlays (32KB)
    __shared__ unsigned short W3S[64 * 128];     // 16KB
    unsigned short* AhS = sm;
    unsigned short* BhS = sm + BM * BK;

    const int side = blockIdx.z;
    const unsigned short* Bside = wspb + (size_t)side * WSP_SIDE;
    const float* bias = side ? b2b : b2u;
    const float* H4 = side ? H4b : H4u;
    float* Cout = side ? Bo : Uo;

    const int tid = threadIdx.x;
    const int rowBase = blockIdx.x * BM;
    const int wave = tid >> 6, lane = tid & 63;
    const int wr = wave >> 1, wc = wave & 1;
    const int sl = lane & 15, lg = lane >> 4;

    // preload W3 [64][128] bf16 k-major (swizzled)
    {
        const unsigned short* w3 = Bside + 81920;
        #pragma unroll
        for (int p = 0; p < 4; ++p) {
            int i = p * 256 + tid;
            int n = i >> 4;
            int kq = (i & 15) << 3;
            u16x8 v = *(const u16x8*)(w3 + (size_t)n * 128 + kq);
            *(u16x8*)&W3S[swz2(n, kq)] = v;
        }
    }

    f32x4 acc[4][4] = {};

    // ---- pass 0: A = H2 (f16), B = W2a (f16), K = 128
    {
        const unsigned short* Ap = H2h + (size_t)side * HSTRIDE;
        const unsigned short* Bp = Bside + 32768;
        const int K = LATENT;
        for (int k0 = 0; k0 < K; k0 += BK) {
            __syncthreads();
            #pragma unroll
            for (int p = 0; p < 4; ++p) {
                int q = p * 256 + tid;
                int row = q >> 3;
                int kq = (q & 7) << 3;
                int grow = rowBase + row;
                u16x8 hv = {0, 0, 0, 0, 0, 0, 0, 0};
                if (grow < M)
                    hv = *(const u16x8*)(Ap + (size_t)grow * K + k0 + kq);
                *(u16x8*)&AhS[swz(row, kq)] = hv;
            }
            #pragma unroll
            for (int p = 0; p < 4; ++p) {
                int q = p * 256 + tid;
                int n = q >> 3;
                int kq = (q & 7) << 3;
                u16x8 hv = *(const u16x8*)(Bp + (size_t)n * K + k0 + kq);
                *(u16x8*)&BhS[swz(n, kq)] = hv;
            }
            __syncthreads();
            #pragma unroll
            for (int ks = 0; ks < 2; ++ks) {
                int kof = ks * 32 + lg * 8;
                f16x8 af[4], bf[4];
                #pragma unroll
                for (int f = 0; f < 4; ++f) {
                    af[f] = *(const f16x8*)&AhS[swz(wr * 64 + f * 16 + sl, kof)];
                    bf[f] = *(const f16x8*)&BhS[swz(wc * 64 + f * 16 + sl, kof)];
                }
                #pragma unroll
                for (int fm = 0; fm < 4; ++fm)
                    #pragma unroll
                    for (int fn = 0; fn < 4; ++fn)
                        acc[fm][fn] = __builtin_amdgcn_mfma_f32_16x16x32_f16(af[fm], bf[fn], acc[fm][fn], 0, 0, 0);
            }
        }
    }

    // ---- pass 1: A = S (f32->bf16), B = W2s (bf16), K = 256
    {
        const float* Ap = side ? Sb : Su;
        const unsigned short* Bp = Bside + 49152;
        const int K = IN_DIM;
        for (int k0 = 0; k0 < K; k0 += BK) {
            __syncthreads();
            #pragma unroll
            for (int p = 0; p < 4; ++p) {
                int q = p * 256 + tid;
                int row = q >> 3;
                int kq = (q & 7) << 3;
                int grow = rowBase + row;
                u16x8 hv = {0, 0, 0, 0, 0, 0, 0, 0};
                if (grow < M) {
                    const float* a = Ap + (size_t)grow * K + k0 + kq;
                    float4 v0 = *(const float4*)a;
                    float4 v1 = *(const float4*)(a + 4);
                    hv[0] = f2bf(v0.x); hv[1] = f2bf(v0.y); hv[2] = f2bf(v0.z); hv[3] = f2bf(v0.w);
                    hv[4] = f2bf(v1.x); hv[5] = f2bf(v1.y); hv[6] = f2bf(v1.z); hv[7] = f2bf(v1.w);
                }
                *(u16x8*)&AhS[swz(row, kq)] = hv;
            }
            #pragma unroll
            for (int p = 0; p < 4; ++p) {
                int q = p * 256 + tid;
                int n = q >> 3;
                int kq = (q & 7) << 3;
                u16x8 hv = *(const u16x8*)(Bp + (size_t)n * K + k0 + kq);
                *(u16x8*)&BhS[swz(n, kq)] = hv;
            }
            __syncthreads();
            #pragma unroll
            for (int ks = 0; ks < 2; ++ks) {
                int kof = ks * 32 + lg * 8;
                bf16x8 af[4], bf[4];
                #pragma unroll
                for (int f = 0; f < 4; ++f) {
                    af[f] = *(const bf16x8*)&AhS[swz(wr * 64 + f * 16 + sl, kof)];
                    bf[f] = *(const bf16x8*)&BhS[swz(wc * 64 + f * 16 + sl, kof)];
                }
                #pragma unroll
                for (int fm = 0; fm < 4; ++fm)
                    #pragma unroll
                    for (int fn = 0; fn < 4; ++fn)
                        acc[fm][fn] = __builtin_amdgcn_mfma_f32_16x16x32_bf16(af[fm], bf[fn], acc[fm][fn], 0, 0, 0);
            }
        }
    }

    __syncthreads();   // main-loop LDS reads done; reuse sm as H3S
    unsigned short* H3S = sm;   // [128][128] bf16, swz2

    // epilogue 1: H3 = elu(acc + b2) -> LDS
    #pragma unroll
    for (int fm = 0; fm < 4; ++fm)
        #pragma unroll
        for (int r = 0; r < 4; ++r) {
            int row_l = wr * 64 + fm * 16 + lg * 4 + r;
            #pragma unroll
            for (int fn = 0; fn < 4; ++fn) {
                int col = wc * 64 + fn * 16 + sl;
                float v = acc[fm][fn][r] + bias[col];
                v = v > 0.f ? v : (__expf(v) - 1.f);
                H3S[swz2(row_l, col)] = f2bf(v);
            }
        }
    __syncthreads();

    // matmul2: OUT[128][64] = H3 @ W3, K=128 (bf16)
    f32x4 acc2[4][2] = {};
    #pragma unroll
    for (int ks = 0; ks < 4; ++ks) {
        int kof = ks * 32 + lg * 8;
        bf16x8 a2[4], b2f[2];
        #pragma unroll
        for (int f = 0; f < 4; ++f)
            a2[f] = *(const bf16x8*)&H3S[swz2(wr * 64 + f * 16 + sl, kof)];
        #pragma unroll
        for (int f = 0; f < 2; ++f)
            b2f[f] = *(const bf16x8*)&W3S[swz2(wc * 32 + f * 16 + sl, kof)];
        #pragma unroll
        for (int fm = 0; fm < 4; ++fm)
            #pragma unroll
            for (int fn = 0; fn < 2; ++fn)
                acc2[fm][fn] = __builtin_amdgcn_mfma_f32_16x16x32_bf16(a2[fm], b2f[fn], acc2[fm][fn], 0, 0, 0);
    }

    // epilogue 2: OUT = elu(acc2) + H4
    #pragma unroll
    for (int fm = 0; fm < 4; ++fm)
        #pragma unroll
        for (int r = 0; r < 4; ++r) {
            int row = rowBase + wr * 64 + fm * 16 + lg * 4 + r;
            if (row >= M) continue;
            #pragma unroll
            for (int fn = 0; fn < 2; ++fn) {
                int col = wc * 32 + fn * 16 + sl;
                float v = acc2[fm][fn][r];
                v = v > 0.f ? v : (__expf(v) - 1.f);
                v += H4[(size_t)row * FINALD + col];
                Cout[(size_t)row * FINALD + col] = v;
            }
        }
}

// ---------------------------------------------------------------------------
__global__ __launch_bounds__(256)
void predict(const int* __restrict__ uid, const int* __restrict__ iid,
             const float* __restrict__ U, const float* __restrict__ B,
             const float* __restrict__ bu, const float* __restrict__ bb,
             const float* __restrict__ bx, float* __restrict__ out, int batch)
{
    int lane = threadIdx.x & 63, wid = threadIdx.x >> 6;
    int b = blockIdx.x * 4 + wid;
    if (b >= batch) return;
    int u = uid[b], it = iid[b];
    float p = U[(size_t)u * FINALD + lane] * B[(size_t)it * FINALD + lane];
    #pragma unroll
    for (int o = 32; o; o >>= 1) p += __shfl_xor(p, o);
    if (lane == 0) {
        float raw = p + bu[u] + bb[it] + bx[0];
        out[b] = 4.f * (1.f / (1.f + __expf(-raw))) + 1.f;
    }
}

// ---------------------------------------------------------------------------
extern "C" void kernel_launch(void* const* d_in, const int* in_sizes, int n_in,
                              void* d_out, int out_size, void* d_ws, size_t ws_size,
                              hipStream_t stream)
{
    const int N = N_NODES;

    float* ws = (float*)d_ws;
    unsigned short* H1h = (unsigned short*)ws;           // 2 sides f16 (12.8e6 ush)
    unsigned short* H2h = (unsigned short*)(ws + 6400000);
    float* U_all = ws + 12800000;
    float* B_all = ws + 16000000;
    float* asf   = ws + 19200000;                        // [2][N]
    float* anb   = asf + 2 * N;                          // [2][N]
    int*   offs  = (int*)(anb + 2 * N);                  // VN4+1
    int*   bbase = offs + VN4 + 1;                       // NBU+1
    unsigned short* csr = (unsigned short*)(bbase + NBU + 1);  // E4 ushorts
    unsigned short* wsp = (unsigned short*)(((uintptr_t)(csr + E4) + 15) & ~(uintptr_t)15);
    int*   ebuf  = (int*)H2h;                            // E4 ints (dead before gather)
    int*   pcnt  = (int*)U_all;                          // NBU*NPB
    int*   pbase = pcnt + NBU * NPB;                     // NBU*NPB

    const int* eU = (const int*)d_in[4];
    const int* eB = (const int*)d_in[5];
    const float* Su = (const float*)d_in[2];
    const float* Sb = (const float*)d_in[3];

    // FAT1: edge histogram || weight prep
    fat_count_prep<<<NPB + PREPB, 256, 0, stream>>>(
        eU, eB, pcnt,
        (const float*)d_in[6],  (const float*)d_in[14], (const float*)d_in[15], (const float*)d_in[20],
        (const float*)d_in[10], (const float*)d_in[17], (const float*)d_in[18], (const float*)d_in[21],
        wsp);

    part_scan<<<1, 1024, 0, stream>>>(pcnt, pbase, bbase, offs);

    // FAT2: edge partition fill || H1 GEMM + rowdots
    fat_fill_gemm1<<<NPB + 782, 256, 0, stream>>>(
        eU, eB, pbase, bbase, ebuf,
        Su, Sb, wsp,
        (const float*)d_in[7], (const float*)d_in[8],
        (const float*)d_in[11], (const float*)d_in[12],
        H1h, asf, anb, N);

    bucket_csr<<<NBU, 256, 0, stream>>>(ebuf, bbase, offs, csr);

    gat_gather<<<dim3(N / 4, 2), 256, 0, stream>>>(
        H1h, asf, anb, offs, csr,
        (const float*)d_in[9], (const float*)d_in[13], H2h, N);

    gemm_fused23<<<dim3(391, 1, 2), 256, 0, stream>>>(
        H2h, Su, Sb, wsp,
        (const float*)d_in[16], (const float*)d_in[19],
        (const float*)d_in[22], (const float*)d_in[23],
        U_all, B_all, N);

    predict<<<BATCHSZ / 4, 256, 0, stream>>>(
        (const int*)d_in[0], (const int*)d_in[1], U_all, B_all,
        (const float*)d_in[24], (const float*)d_in[25], (const float*)d_in[26],
        (float*)d_out, BATCHSZ);
}

// Round 15
// 308.170 us; speedup vs baseline: 3.2022x; 1.0408x over previous
//
#include <hip/hip_runtime.h>
#include <math.h>

#define N_NODES 50000
#define IN_DIM  256
#define LATENT  128
#define FINALD  64
#define NGRAPH  2
#define NEDGE   1000000
#define BATCHSZ 16384

#define VN4     (4 * N_NODES)          // unified virtual dst ids: side*2N + g*N + dst
#define NBU     ((VN4 + 255) >> 8)     // 782 buckets of 256 vds
#define E4      (4 * NEDGE)
#define NPB     256                    // partition blocks
#define PCH     ((E4 + NPB - 1) / NPB) // 15625 edges per partition block
#define BCAP    8192                   // bucket_csr LDS cache entries
#define PREPB   768                    // prep blocks: 2*WSP_SIDE/256

// weights per side: W1[128][256]bf16 W2a[128][128]f16 W2s[128][256]bf16 W3pad[128][128]bf16
#define WSP_SIDE   98304
#define HSTRIDE    (N_NODES * LATENT)  // per-side ushort stride for H1h/H2h

typedef __attribute__((ext_vector_type(8))) short bf16x8;
typedef __attribute__((ext_vector_type(8))) _Float16 f16x8;
typedef __attribute__((ext_vector_type(4))) float f32x4;
typedef __attribute__((ext_vector_type(8))) unsigned short u16x8;

__device__ inline unsigned short f2bf(float x) {
    unsigned int u = __float_as_uint(x);
    u = (u + 0x7fffu + ((u >> 16) & 1u)) >> 16;
    return (unsigned short)u;
}
__device__ inline float bf2f(unsigned short h) {
    return __uint_as_float(((unsigned int)h) << 16);
}
__device__ inline f16x8 splat8(float x) {
    _Float16 h = (_Float16)x;
    f16x8 v = {h, h, h, h, h, h, h, h};
    return v;
}

#define BM 128
#define BK 64

__device__ inline int swz(int r, int k) {      // [*][64] tiles
    return r * BK + ((((k >> 3) ^ (r & 7)) << 3) | (k & 7));
}
__device__ inline int swz2(int r, int c) {     // [*][128] tiles
    return r * 128 + ((((c >> 3) ^ (r & 7)) << 3) | (c & 7));
}

__device__ inline void edge_decomp(int i, int& side, int& g, int& idx) {
    if (i < NEDGE)          { side = 0; g = 0; idx = i; }
    else if (i < 2 * NEDGE) { side = 0; g = 1; idx = i - NEDGE; }
    else if (i < 3 * NEDGE) { side = 1; g = 0; idx = i - 2 * NEDGE; }
    else                    { side = 1; g = 1; idx = i - 3 * NEDGE; }
}

// ---------------------------------------------------------------------------
// FAT1: part_count (blocks 0..NPB) || prep_weights (blocks NPB..NPB+PREPB)
// ---------------------------------------------------------------------------
__global__ __launch_bounds__(256)
void fat_count_prep(const int* __restrict__ eU, const int* __restrict__ eB,
                    int* __restrict__ pcnt,
                    const float* __restrict__ W1u, const float* __restrict__ Wu2,
                    const float* __restrict__ Wus2, const float* __restrict__ Wu3,
                    const float* __restrict__ W1b, const float* __restrict__ Wb2,
                    const float* __restrict__ Wbs2, const float* __restrict__ Wb3,
                    unsigned short* __restrict__ dst)
{
    __shared__ int h[NBU];
    int tid = threadIdx.x;
    if (blockIdx.x < NPB) {
        for (int i = tid; i < NBU; i += 256) h[i] = 0;
        __syncthreads();
        int start = blockIdx.x * PCH;
        int stop  = min(start + PCH, E4);
        for (int i = start + tid; i < stop; i += 256) {
            int side, g, idx;
            edge_decomp(i, side, g, idx);
            const int* base = side ? eB : eU;
            int d = base[(size_t)(2 * g + 1) * NEDGE + idx];
            int vd = side * (2 * N_NODES) + g * N_NODES + d;
            atomicAdd(&h[vd >> 8], 1);
        }
        __syncthreads();
        for (int i = tid; i < NBU; i += 256)
            pcnt[i * NPB + blockIdx.x] = h[i];
    } else {
        int e = (blockIdx.x - NPB) * 256 + tid;
        if (e >= 2 * WSP_SIDE) return;
        int side = e >= WSP_SIDE;
        int r = e - (side ? WSP_SIDE : 0);
        const float* src; int K, hoff; int w3 = 0, fp16 = 0;
        if (r < 32768)      { src = side ? W1b  : W1u;  K = 256; hoff = 0;     }
        else if (r < 49152) { src = side ? Wb2  : Wu2;  K = 128; hoff = 32768; r -= 32768; fp16 = 1; }
        else if (r < 81920) { src = side ? Wbs2 : Wus2; K = 256; hoff = 49152; r -= 49152; }
        else                { src = side ? Wb3  : Wu3;  K = 128; hoff = 81920; r -= 81920; w3 = 1; }
        int n = (K == 256) ? (r >> 8) : (r >> 7);
        int k = (K == 256) ? (r & 255) : (r & 127);
        float x;
        if (w3) x = (n < 64) ? src[k * 64 + n] : 0.f;
        else    x = src[k * 128 + n];
        unsigned short o;
        if (fp16) { _Float16 hx = (_Float16)x; o = *(unsigned short*)&hx; }
        else      o = f2bf(x);
        dst[(size_t)side * WSP_SIDE + hoff + n * K + k] = o;
    }
}

// ---------------------------------------------------------------------------
__global__ __launch_bounds__(1024)
void part_scan(const int* __restrict__ pcnt, int* __restrict__ pbase,
               int* __restrict__ bbase, int* __restrict__ offs)
{
    __shared__ int btot[NBU];
    __shared__ int wsum2[16];
    int tid = threadIdx.x;
    int lane = tid & 63, w = tid >> 6;           // 16 waves
    for (int b = w; b < NBU; b += 16) {
        int4 v = *(const int4*)&pcnt[b * NPB + lane * 4];
        int s = v.x + v.y + v.z + v.w;
        int x = s;
        #pragma unroll
        for (int o = 1; o < 64; o <<= 1) {
            int y = __shfl_up(x, o);
            if (lane >= o) x += y;
        }
        int ex = x - s;
        int* pb = &pbase[b * NPB + lane * 4];
        pb[0] = ex;
        pb[1] = ex + v.x;
        pb[2] = ex + v.x + v.y;
        pb[3] = ex + v.x + v.y + v.z;
        if (lane == 63) btot[b] = x;
    }
    __syncthreads();
    int v = (tid < NBU) ? btot[tid] : 0;
    int x = v;
    #pragma unroll
    for (int o = 1; o < 64; o <<= 1) {
        int y = __shfl_up(x, o);
        if (lane >= o) x += y;
    }
    if (lane == 63) wsum2[w] = x;
    __syncthreads();
    int wb = 0;
    for (int i = 0; i < w; ++i) wb += wsum2[i];
    int ex = wb + x - v;
    if (tid < NBU) bbase[tid] = ex;
    if (tid == NBU - 1) bbase[NBU] = ex + v;
    if (tid == 0) offs[VN4] = E4;
}

// ---------------------------------------------------------------------------
// FAT2: part_fill (blocks 0..NPB) || gemm_h1+rowdots (blocks NPB..NPB+782).
// ---------------------------------------------------------------------------
__global__ __launch_bounds__(256)
void fat_fill_gemm1(const int* __restrict__ eU, const int* __restrict__ eB,
                    const int* __restrict__ pbase, const int* __restrict__ bbase,
                    int* __restrict__ ebuf,
                    const float* __restrict__ Su, const float* __restrict__ Sb,
                    const unsigned short* __restrict__ wspb,
                    const float* __restrict__ aself_u, const float* __restrict__ anbv_u,
                    const float* __restrict__ aself_b, const float* __restrict__ anbv_b,
                    unsigned short* __restrict__ H1h, float* __restrict__ asf,
                    float* __restrict__ anb, int M)
{
    __shared__ unsigned short AhS[BM * BK];
    __shared__ unsigned short BhS[BM * BK];
    __shared__ float dotL[BM][2];
    __shared__ int lbase[NBU];
    __shared__ int lcur[NBU];

    int tid = threadIdx.x;

    if (blockIdx.x < NPB) {
        for (int i = tid; i < NBU; i += 256) {
            lbase[i] = bbase[i] + pbase[i * NPB + blockIdx.x];
            lcur[i] = 0;
        }
        __syncthreads();
        int start = blockIdx.x * PCH;
        int stop  = min(start + PCH, E4);
        for (int i = start + tid; i < stop; i += 256) {
            int side, g, idx;
            edge_decomp(i, side, g, idx);
            const int* base = side ? eB : eU;
            int src = base[(size_t)(2 * g) * NEDGE + idx];
            int d = base[(size_t)(2 * g + 1) * NEDGE + idx];
            int vd = side * (2 * N_NODES) + g * N_NODES + d;
            int b = vd >> 8;
            int p = lbase[b] + atomicAdd(&lcur[b], 1);
            ebuf[p] = ((vd & 255) << 16) | src;
        }
        return;
    }

    // ----- gemm_h1 -----
    int t = blockIdx.x - NPB;             // 0..781
    const int side = t / 391;
    const int rowBase = (t % 391) * BM;
    const float* Ap = side ? Sb : Su;
    const unsigned short* Bp = wspb + (size_t)side * WSP_SIDE;   // W1 slot (bf16)
    const float* avs = side ? aself_b : aself_u;
    const float* avn = side ? anbv_b : anbv_u;
    _Float16* Cout = (_Float16*)(H1h + (size_t)side * HSTRIDE);

    const int wave = tid >> 6, lane = tid & 63;
    const int wr = wave >> 1, wc = wave & 1;
    const int sl = lane & 15, lg = lane >> 4;
    const int K = IN_DIM;

    if (tid < BM) { dotL[tid][0] = 0.f; dotL[tid][1] = 0.f; }

    f32x4 acc[4][4] = {};

    for (int k0 = 0; k0 < K; k0 += BK) {
        __syncthreads();
        #pragma unroll
        for (int p = 0; p < 4; ++p) {
            int q = p * 256 + tid;
            int row = q >> 3;
            int kq = (q & 7) << 3;
            int grow = rowBase + row;
            u16x8 hv = {0, 0, 0, 0, 0, 0, 0, 0};
            if (grow < M) {
                const float* a = Ap + (size_t)grow * K + k0 + kq;
                float4 v0 = *(const float4*)a;
                float4 v1 = *(const float4*)(a + 4);
                hv[0] = f2bf(v0.x); hv[1] = f2bf(v0.y); hv[2] = f2bf(v0.z); hv[3] = f2bf(v0.w);
                hv[4] = f2bf(v1.x); hv[5] = f2bf(v1.y); hv[6] = f2bf(v1.z); hv[7] = f2bf(v1.w);
            }
            *(u16x8*)&AhS[swz(row, kq)] = hv;
        }
        #pragma unroll
        for (int p = 0; p < 4; ++p) {
            int q = p * 256 + tid;
            int n = q >> 3;
            int kq = (q & 7) << 3;
            u16x8 hv = *(const u16x8*)(Bp + (size_t)n * K + k0 + kq);
            *(u16x8*)&BhS[swz(n, kq)] = hv;
        }
        __syncthreads();
        #pragma unroll
        for (int ks = 0; ks < 2; ++ks) {
            int kof = ks * 32 + lg * 8;
            bf16x8 af[4], bf[4];
            #pragma unroll
            for (int f = 0; f < 4; ++f) {
                af[f] = *(const bf16x8*)&AhS[swz(wr * 64 + f * 16 + sl, kof)];
                bf[f] = *(const bf16x8*)&BhS[swz(wc * 64 + f * 16 + sl, kof)];
            }
            #pragma unroll
            for (int fm = 0; fm < 4; ++fm)
                #pragma unroll
                for (int fn = 0; fn < 4; ++fn)
                    acc[fm][fn] = __builtin_amdgcn_mfma_f32_16x16x32_bf16(af[fm], bf[fn], acc[fm][fn], 0, 0, 0);
        }
    }

    // C write (f16)
    #pragma unroll
    for (int fm = 0; fm < 4; ++fm)
        #pragma unroll
        for (int r = 0; r < 4; ++r) {
            int row = rowBase + wr * 64 + fm * 16 + lg * 4 + r;
            if (row >= M) continue;
            #pragma unroll
            for (int fn = 0; fn < 4; ++fn) {
                int col = wc * 64 + fn * 16 + sl;
                Cout[(size_t)row * LATENT + col] = (_Float16)acc[fm][fn][r];
            }
        }

    // fused rowdots
    float as_[4], an_[4];
    #pragma unroll
    for (int fn = 0; fn < 4; ++fn) {
        int col = wc * 64 + fn * 16 + sl;
        as_[fn] = avs[col];
        an_[fn] = avn[col];
    }
    #pragma unroll
    for (int fm = 0; fm < 4; ++fm)
        #pragma unroll
        for (int r = 0; r < 4; ++r) {
            float p1 = 0.f, p2 = 0.f;
            #pragma unroll
            for (int fn = 0; fn < 4; ++fn) {
                float v = acc[fm][fn][r];
                p1 += v * as_[fn];
                p2 += v * an_[fn];
            }
            #pragma unroll
            for (int o = 1; o <= 8; o <<= 1) {
                p1 += __shfl_xor(p1, o);
                p2 += __shfl_xor(p2, o);
            }
            if (sl == 0) {
                int row_l = wr * 64 + fm * 16 + lg * 4 + r;
                atomicAdd(&dotL[row_l][0], p1);
                atomicAdd(&dotL[row_l][1], p2);
            }
        }
    __syncthreads();
    if (tid < BM) {
        int row = rowBase + tid;
        if (row < M) {
            asf[side * M + row] = dotL[tid][0];
            anb[side * M + row] = dotL[tid][1];
        }
    }
}

// ---------------------------------------------------------------------------
__global__ __launch_bounds__(256)
void bucket_csr(const int* __restrict__ ebuf, const int* __restrict__ bbase,
                int* __restrict__ offs, unsigned short* __restrict__ csr)
{
    __shared__ int lds_e[BCAP];
    __shared__ int cnt[256];
    __shared__ int excl[256];
    __shared__ int cur[256];
    __shared__ int wsum[4];
    int tid = threadIdx.x;
    int b = blockIdx.x;
    int lo = bbase[b], hi = bbase[b + 1];
    int sz = hi - lo;

    cnt[tid] = 0; cur[tid] = 0;
    __syncthreads();
    for (int i = tid; i < sz; i += 256) {
        int v = ebuf[lo + i];
        if (i < BCAP) lds_e[i] = v;
        atomicAdd(&cnt[v >> 16], 1);
    }
    __syncthreads();

    int lane = tid & 63, w = tid >> 6;
    int v = cnt[tid];
    int x = v;
    #pragma unroll
    for (int o = 1; o < 64; o <<= 1) {
        int y = __shfl_up(x, o);
        if (lane >= o) x += y;
    }
    if (lane == 63) wsum[w] = x;
    __syncthreads();
    int wb = 0;
    for (int i = 0; i < w; ++i) wb += wsum[i];
    int ex = wb + x - v;
    excl[tid] = ex;
    int vd = b * 256 + tid;
    if (vd < VN4) offs[vd] = lo + ex;
    __syncthreads();

    for (int i = tid; i < sz; i += 256) {
        int e = (i < BCAP) ? lds_e[i] : ebuf[lo + i];
        int dl = e >> 16;
        int p = excl[dl] + atomicAdd(&cur[dl], 1);
        csr[lo + p] = (unsigned short)(e & 0xFFFF);
    }
}

// ---------------------------------------------------------------------------
// GAT aggregation: single pass, deferred normalization, 16-lane groups,
// 4-deep pipeline (16 rows in flight/wave), dual f16 accumulators.
// ---------------------------------------------------------------------------
__global__ __launch_bounds__(256)
void gat_gather(const unsigned short* __restrict__ H1h, const float* __restrict__ asf,
                const float* __restrict__ anb,
                const int* __restrict__ offs, const unsigned short* __restrict__ csr,
                const float* __restrict__ omu, const float* __restrict__ omb,
                unsigned short* __restrict__ H2h, int n)
{
    int side = blockIdx.y;
    int lane = threadIdx.x & 63, wid = threadIdx.x >> 6;
    int d = blockIdx.x * 4 + wid;
    if (d >= n) return;
    const unsigned short* Hbase = H1h + (size_t)side * HSTRIDE;
    const int* offside = offs + side * 2 * N_NODES;
    const float* om_p = side ? omb : omu;
    float ad = asf[side * n + d];
    const float* anb_s = anb + side * n;
    int sub = lane >> 4, sl = lane & 15;
    const unsigned short* Hp = Hbase + (sl << 3);
    float fin[8] = {};

    #pragma unroll
    for (int g = 0; g < NGRAPH; ++g) {
        int beg = offside[g * n + d], end = offside[g * n + d + 1];
        float om = om_p[g];
        f16x8 un8a = splat8(0.f);
        f16x8 un8b = splat8(0.f);
        float ss = 0.f;

        int e = beg + sub;
        // 4-deep: 4 independent row loads per group per iteration
        for (; e + 12 < end; e += 16) {
            int s0 = csr[e], s1 = csr[e + 4], s2 = csr[e + 8], s3 = csr[e + 12];
            float a0 = anb_s[s0], a1 = anb_s[s1], a2 = anb_s[s2], a3 = anb_s[s3];
            f16x8 h0 = *(const f16x8*)(Hp + (size_t)s0 * LATENT);
            f16x8 h1 = *(const f16x8*)(Hp + (size_t)s1 * LATENT);
            f16x8 h2 = *(const f16x8*)(Hp + (size_t)s2 * LATENT);
            f16x8 h3 = *(const f16x8*)(Hp + (size_t)s3 * LATENT);
            float sc0 = ad + a0; sc0 = fmaxf(sc0, 0.2f * sc0);
            float sc1 = ad + a1; sc1 = fmaxf(sc1, 0.2f * sc1);
            float sc2 = ad + a2; sc2 = fmaxf(sc2, 0.2f * sc2);
            float sc3 = ad + a3; sc3 = fmaxf(sc3, 0.2f * sc3);
            float w0 = __expf(sc0), w1 = __expf(sc1);
            float w2 = __expf(sc2), w3 = __expf(sc3);
            ss += (w0 + w1) + (w2 + w3);
            un8a += splat8(w0) * h0;
            un8b += splat8(w1) * h1;
            un8a += splat8(w2) * h2;
            un8b += splat8(w3) * h3;
        }
        for (; e < end; e += 4) {
            int s0 = csr[e];
            float a0 = anb_s[s0];
            f16x8 h0 = *(const f16x8*)(Hp + (size_t)s0 * LATENT);
            float sc0 = ad + a0; sc0 = fmaxf(sc0, 0.2f * sc0);
            float w0 = __expf(sc0);
            ss += w0;
            un8a += splat8(w0) * h0;
        }

        // cross-group sum of exp (groups hold disjoint edge subsets)
        ss += __shfl_xor(ss, 32);
        ss += __shfl_xor(ss, 16);
        float wsc = om / (ss + 1e-16f);
        #pragma unroll
        for (int j = 0; j < 8; ++j) fin[j] += wsc * ((float)un8a[j] + (float)un8b[j]);
    }

    #pragma unroll
    for (int j = 0; j < 8; ++j) {
        fin[j] += __shfl_xor(fin[j], 32);
        fin[j] += __shfl_xor(fin[j], 16);
    }
    if (sub == 0) {
        f16x8 o;
        #pragma unroll
        for (int j = 0; j < 8; ++j) o[j] = (_Float16)fin[j];
        *(f16x8*)(H2h + (size_t)side * HSTRIDE + (size_t)d * LATENT + sl * 8) = o;
    }
}

// ---------------------------------------------------------------------------
// Fused GEMM2+GEMM3: H3 = elu(H2@W2a + S@W2s + b2) in LDS (bf16), then
// OUT = elu(H3@W3) + H4. Pass0 f16 MFMA (H2/W2a f16), pass1 bf16.
// ---------------------------------------------------------------------------
__global__ __launch_bounds__(256)
void gemm_fused23(const unsigned short* __restrict__ H2h,
                  const float* __restrict__ Su, const float* __restrict__ Sb,
                  const unsigned short* __restrict__ wspb,
                  const float* __restrict__ b2u, const float* __restrict__ b2b,
                  const float* __restrict__ H4u, const float* __restrict__ H4b,
                  float* __restrict__ Uo, float* __restrict__ Bo, int M)
{
    __shared__ unsigned short sm[BM * BK * 2];   // AhS/BhS; H3S overlays (32KB)
    __shared__ unsigned short W3S[64 * 128];     // 16KB
    unsigned short* AhS = sm;
    unsigned short* BhS = sm + BM * BK;

    const int side = blockIdx.z;
    const unsigned short* Bside = wspb + (size_t)side * WSP_SIDE;
    const float* bias = side ? b2b : b2u;
    const float* H4 = side ? H4b : H4u;
    float* Cout = side ? Bo : Uo;

    const int tid = threadIdx.x;
    const int rowBase = blockIdx.x * BM;
    const int wave = tid >> 6, lane = tid & 63;
    const int wr = wave >> 1, wc = wave & 1;
    const int sl = lane & 15, lg = lane >> 4;

    // preload W3 [64][128] bf16 k-major (swizzled)
    {
        const unsigned short* w3 = Bside + 81920;
        #pragma unroll
        for (int p = 0; p < 4; ++p) {
            int i = p * 256 + tid;
            int n = i >> 4;
            int kq = (i & 15) << 3;
            u16x8 v = *(const u16x8*)(w3 + (size_t)n * 128 + kq);
            *(u16x8*)&W3S[swz2(n, kq)] = v;
        }
    }

    f32x4 acc[4][4] = {};

    // ---- pass 0: A = H2 (f16), B = W2a (f16), K = 128
    {
        const unsigned short* Ap = H2h + (size_t)side * HSTRIDE;
        const unsigned short* Bp = Bside + 32768;
        const int K = LATENT;
        for (int k0 = 0; k0 < K; k0 += BK) {
            __syncthreads();
            #pragma unroll
            for (int p = 0; p < 4; ++p) {
                int q = p * 256 + tid;
                int row = q >> 3;
                int kq = (q & 7) << 3;
                int grow = rowBase + row;
                u16x8 hv = {0, 0, 0, 0, 0, 0, 0, 0};
                if (grow < M)
                    hv = *(const u16x8*)(Ap + (size_t)grow * K + k0 + kq);
                *(u16x8*)&AhS[swz(row, kq)] = hv;
            }
            #pragma unroll
            for (int p = 0; p < 4; ++p) {
                int q = p * 256 + tid;
                int n = q >> 3;
                int kq = (q & 7) << 3;
                u16x8 hv = *(const u16x8*)(Bp + (size_t)n * K + k0 + kq);
                *(u16x8*)&BhS[swz(n, kq)] = hv;
            }
            __syncthreads();
            #pragma unroll
            for (int ks = 0; ks < 2; ++ks) {
                int kof = ks * 32 + lg * 8;
                f16x8 af[4], bf[4];
                #pragma unroll
                for (int f = 0; f < 4; ++f) {
                    af[f] = *(const f16x8*)&AhS[swz(wr * 64 + f * 16 + sl, kof)];
                    bf[f] = *(const f16x8*)&BhS[swz(wc * 64 + f * 16 + sl, kof)];
                }
                #pragma unroll
                for (int fm = 0; fm < 4; ++fm)
                    #pragma unroll
                    for (int fn = 0; fn < 4; ++fn)
                        acc[fm][fn] = __builtin_amdgcn_mfma_f32_16x16x32_f16(af[fm], bf[fn], acc[fm][fn], 0, 0, 0);
            }
        }
    }

    // ---- pass 1: A = S (f32->bf16), B = W2s (bf16), K = 256
    {
        const float* Ap = side ? Sb : Su;
        const unsigned short* Bp = Bside + 49152;
        const int K = IN_DIM;
        for (int k0 = 0; k0 < K; k0 += BK) {
            __syncthreads();
            #pragma unroll
            for (int p = 0; p < 4; ++p) {
                int q = p * 256 + tid;
                int row = q >> 3;
                int kq = (q & 7) << 3;
                int grow = rowBase + row;
                u16x8 hv = {0, 0, 0, 0, 0, 0, 0, 0};
                if (grow < M) {
                    const float* a = Ap + (size_t)grow * K + k0 + kq;
                    float4 v0 = *(const float4*)a;
                    float4 v1 = *(const float4*)(a + 4);
                    hv[0] = f2bf(v0.x); hv[1] = f2bf(v0.y); hv[2] = f2bf(v0.z); hv[3] = f2bf(v0.w);
                    hv[4] = f2bf(v1.x); hv[5] = f2bf(v1.y); hv[6] = f2bf(v1.z); hv[7] = f2bf(v1.w);
                }
                *(u16x8*)&AhS[swz(row, kq)] = hv;
            }
            #pragma unroll
            for (int p = 0; p < 4; ++p) {
                int q = p * 256 + tid;
                int n = q >> 3;
                int kq = (q & 7) << 3;
                u16x8 hv = *(const u16x8*)(Bp + (size_t)n * K + k0 + kq);
                *(u16x8*)&BhS[swz(n, kq)] = hv;
            }
            __syncthreads();
            #pragma unroll
            for (int ks = 0; ks < 2; ++ks) {
                int kof = ks * 32 + lg * 8;
                bf16x8 af[4], bf[4];
                #pragma unroll
                for (int f = 0; f < 4; ++f) {
                    af[f] = *(const bf16x8*)&AhS[swz(wr * 64 + f * 16 + sl, kof)];
                    bf[f] = *(const bf16x8*)&BhS[swz(wc * 64 + f * 16 + sl, kof)];
                }
                #pragma unroll
                for (int fm = 0; fm < 4; ++fm)
                    #pragma unroll
                    for (int fn = 0; fn < 4; ++fn)
                        acc[fm][fn] = __builtin_amdgcn_mfma_f32_16x16x32_bf16(af[fm], bf[fn], acc[fm][fn], 0, 0, 0);
            }
        }
    }

    __syncthreads();   // main-loop LDS reads done; reuse sm as H3S
    unsigned short* H3S = sm;   // [128][128] bf16, swz2

    // epilogue 1: H3 = elu(acc + b2) -> LDS
    #pragma unroll
    for (int fm = 0; fm < 4; ++fm)
        #pragma unroll
        for (int r = 0; r < 4; ++r) {
            int row_l = wr * 64 + fm * 16 + lg * 4 + r;
            #pragma unroll
            for (int fn = 0; fn < 4; ++fn) {
                int col = wc * 64 + fn * 16 + sl;
                float v = acc[fm][fn][r] + bias[col];
                v = v > 0.f ? v : (__expf(v) - 1.f);
                H3S[swz2(row_l, col)] = f2bf(v);
            }
        }
    __syncthreads();

    // matmul2: OUT[128][64] = H3 @ W3, K=128 (bf16)
    f32x4 acc2[4][2] = {};
    #pragma unroll
    for (int ks = 0; ks < 4; ++ks) {
        int kof = ks * 32 + lg * 8;
        bf16x8 a2[4], b2f[2];
        #pragma unroll
        for (int f = 0; f < 4; ++f)
            a2[f] = *(const bf16x8*)&H3S[swz2(wr * 64 + f * 16 + sl, kof)];
        #pragma unroll
        for (int f = 0; f < 2; ++f)
            b2f[f] = *(const bf16x8*)&W3S[swz2(wc * 32 + f * 16 + sl, kof)];
        #pragma unroll
        for (int fm = 0; fm < 4; ++fm)
            #pragma unroll
            for (int fn = 0; fn < 2; ++fn)
                acc2[fm][fn] = __builtin_amdgcn_mfma_f32_16x16x32_bf16(a2[fm], b2f[fn], acc2[fm][fn], 0, 0, 0);
    }

    // epilogue 2: OUT = elu(acc2) + H4
    #pragma unroll
    for (int fm = 0; fm < 4; ++fm)
        #pragma unroll
        for (int r = 0; r < 4; ++r) {
            int row = rowBase + wr * 64 + fm * 16 + lg * 4 + r;
            if (row >= M) continue;
            #pragma unroll
            for (int fn = 0; fn < 2; ++fn) {
                int col = wc * 32 + fn * 16 + sl;
                float v = acc2[fm][fn][r];
                v = v > 0.f ? v : (__expf(v) - 1.f);
                v += H4[(size_t)row * FINALD + col];
                Cout[(size_t)row * FINALD + col] = v;
            }
        }
}

// ---------------------------------------------------------------------------
__global__ __launch_bounds__(256)
void predict(const int* __restrict__ uid, const int* __restrict__ iid,
             const float* __restrict__ U, const float* __restrict__ B,
             const float* __restrict__ bu, const float* __restrict__ bb,
             const float* __restrict__ bx, float* __restrict__ out, int batch)
{
    int lane = threadIdx.x & 63, wid = threadIdx.x >> 6;
    int b = blockIdx.x * 4 + wid;
    if (b >= batch) return;
    int u = uid[b], it = iid[b];
    float p = U[(size_t)u * FINALD + lane] * B[(size_t)it * FINALD + lane];
    #pragma unroll
    for (int o = 32; o; o >>= 1) p += __shfl_xor(p, o);
    if (lane == 0) {
        float raw = p + bu[u] + bb[it] + bx[0];
        out[b] = 4.f * (1.f / (1.f + __expf(-raw))) + 1.f;
    }
}

// ---------------------------------------------------------------------------
extern "C" void kernel_launch(void* const* d_in, const int* in_sizes, int n_in,
                              void* d_out, int out_size, void* d_ws, size_t ws_size,
                              hipStream_t stream)
{
    const int N = N_NODES;

    float* ws = (float*)d_ws;
    unsigned short* H1h = (unsigned short*)ws;           // 2 sides f16 (12.8e6 ush)
    unsigned short* H2h = (unsigned short*)(ws + 6400000);
    float* U_all = ws + 12800000;
    float* B_all = ws + 16000000;
    float* asf   = ws + 19200000;                        // [2][N]
    float* anb   = asf + 2 * N;                          // [2][N]
    int*   offs  = (int*)(anb + 2 * N);                  // VN4+1
    int*   bbase = offs + VN4 + 1;                       // NBU+1
    unsigned short* csr = (unsigned short*)(bbase + NBU + 1);  // E4 ushorts
    unsigned short* wsp = (unsigned short*)(((uintptr_t)(csr + E4) + 15) & ~(uintptr_t)15);
    int*   ebuf  = (int*)H2h;                            // E4 ints (dead before gather)
    int*   pcnt  = (int*)U_all;                          // NBU*NPB
    int*   pbase = pcnt + NBU * NPB;                     // NBU*NPB

    const int* eU = (const int*)d_in[4];
    const int* eB = (const int*)d_in[5];
    const float* Su = (const float*)d_in[2];
    const float* Sb = (const float*)d_in[3];

    // FAT1: edge histogram || weight prep
    fat_count_prep<<<NPB + PREPB, 256, 0, stream>>>(
        eU, eB, pcnt,
        (const float*)d_in[6],  (const float*)d_in[14], (const float*)d_in[15], (const float*)d_in[20],
        (const float*)d_in[10], (const float*)d_in[17], (const float*)d_in[18], (const float*)d_in[21],
        wsp);

    part_scan<<<1, 1024, 0, stream>>>(pcnt, pbase, bbase, offs);

    // FAT2: edge partition fill || H1 GEMM + rowdots
    fat_fill_gemm1<<<NPB + 782, 256, 0, stream>>>(
        eU, eB, pbase, bbase, ebuf,
        Su, Sb, wsp,
        (const float*)d_in[7], (const float*)d_in[8],
        (const float*)d_in[11], (const float*)d_in[12],
        H1h, asf, anb, N);

    bucket_csr<<<NBU, 256, 0, stream>>>(ebuf, bbase, offs, csr);

    gat_gather<<<dim3(N / 4, 2), 256, 0, stream>>>(
        H1h, asf, anb, offs, csr,
        (const float*)d_in[9], (const float*)d_in[13], H2h, N);

    gemm_fused23<<<dim3(391, 1, 2), 256, 0, stream>>>(
        H2h, Su, Sb, wsp,
        (const float*)d_in[16], (const float*)d_in[19],
        (const float*)d_in[22], (const float*)d_in[23],
        U_all, B_all, N);

    predict<<<BATCHSZ / 4, 256, 0, stream>>>(
        (const int*)d_in[0], (const int*)d_in[1], U_all, B_all,
        (const float*)d_in[24], (const float*)d_in[25], (const float*)d_in[26],
        (float*)d_out, BATCHSZ);
}